// Round 4
// baseline (1030.533 us; speedup 1.0000x reference)
//
#include <hip/hip_runtime.h>
#include <math.h>

// HyenaFilter: y = irfft(rfft(x,2L) * rfft(k,2L))[..., :L] + x*bias
// Register-blocked mixed-radix [16,16,16,2] FFT. Round-4 revision:
//  - 1024-thread blocks processing TWO independent rows (two 64KB LDS arrays +
//    shared twiddle table = 136.7 KB): forces 16 waves/CU inside one workgroup,
//    fixing the observed 1-block/CU residency (Occupancy stuck at 23% whenever
//    VGPR>64). Halves split at a wave boundary; barriers are 16-wave.
//  - k_main: block = channel, halves = batch groups; kf4/tw16 shared by both
//    halves (L1-hot). 4 rows sequential per half with register prefetch.
//  - k_filter: 2 channels per block; halves stream the same H in lockstep.
//  - keeps: LDS twiddle tables, folded XOR-swizzle addressing, wave-local B<->C
//    sync, fused r2+spectral quad stage, pruned first fwd pass, merged k_pre.

#define LSEQ 8192
#define NCH 768
#define NBATCH 8
#define NT 512            // threads per half (per row)
#define BT 1024           // threads per block

// ws layout (float offsets)
#define OFF_TWB  0        // 32 rows x 16 float2 : W16384^{32*q*m}   (pass B; pass-A high = rows 2b)
#define OFF_TW16 1024     // 2049 float2         : W16384^k, k<=2048
#define OFF_TL   5124     // 32 rows x 16 float2 : W16384^{2*a*m}    (pass A low)
#define OFF_TWC  6660     // 2 rows x 16 float2  : W16384^{512*p*m}  (pass C)
#define OFF_H    10240    // 8192 x 16 floats (MLP features, row-major)
#define OFF_KF   141312   // 768 x 4096 float4 (S~, D~ per bin pair)

__device__ __forceinline__ float2 cadd(float2 a, float2 b){ return make_float2(a.x+b.x, a.y+b.y); }
__device__ __forceinline__ float2 csub(float2 a, float2 b){ return make_float2(a.x-b.x, a.y-b.y); }
__device__ __forceinline__ float2 cmul(float2 a, float2 b){ return make_float2(a.x*b.x - a.y*b.y, a.x*b.y + a.y*b.x); }
__device__ __forceinline__ float2 mni(float2 a){ return make_float2(a.y, -a.x); }  // * -i

// wave-local LDS producer->consumer sync (exchange confined to one wave)
__device__ __forceinline__ void wave_sync(){
    asm volatile("s_waitcnt lgkmcnt(0)" ::: "memory");
}

// generic swizzle (used only in the spectral stage)
__device__ __forceinline__ int IDX(int i){ return i ^ (((i>>4) ^ (i>>8)) & 15); }
// digit-reversal: bin k -> slot after DIF passes [16(512),16(32),16(2)] (pre-r2, slot even)
__device__ __forceinline__ int drev(int k){
    return ((k & 15) << 9) | (((k >> 4) & 15) << 5) | (((k >> 8) & 15) << 1) | (k >> 12);
}

#define C1 0.923879532511286756f
#define S1 0.382683432365089772f
#define R2 0.707106781186547524f

// natural-in DFT-16; output bin m in q[rv[m]]. FULL=false: inputs 8..15 are
// pre-duplicated copies of 0..7 (zero upper half), stage-1 add/sub skipped.
template<bool FULL>
__device__ __forceinline__ void dft16(float2 q[16]) {
    if constexpr (FULL) {
#pragma unroll
        for (int j = 0; j < 8; ++j) { float2 u=q[j], v=q[j+8]; q[j]=cadd(u,v); q[j+8]=csub(u,v); }
    }
    q[9]  = cmul(q[9],  make_float2( C1,-S1));
    q[10] = cmul(q[10], make_float2( R2,-R2));
    q[11] = cmul(q[11], make_float2( S1,-C1));
    q[12] = mni(q[12]);
    q[13] = cmul(q[13], make_float2(-S1,-C1));
    q[14] = cmul(q[14], make_float2(-R2,-R2));
    q[15] = cmul(q[15], make_float2(-C1,-S1));
#pragma unroll
    for (int b = 0; b < 16; b += 8) {
#pragma unroll
        for (int j = 0; j < 4; ++j) { float2 u=q[b+j], v=q[b+j+4]; q[b+j]=cadd(u,v); q[b+j+4]=csub(u,v); }
        q[b+5] = cmul(q[b+5], make_float2( R2,-R2));
        q[b+6] = mni(q[b+6]);
        q[b+7] = cmul(q[b+7], make_float2(-R2,-R2));
    }
#pragma unroll
    for (int b = 0; b < 16; b += 4) {
        float2 u0=q[b], v0=q[b+2], u1=q[b+1], v1=q[b+3];
        q[b]=cadd(u0,v0); q[b+2]=csub(u0,v0);
        q[b+1]=cadd(u1,v1); q[b+3]=mni(csub(u1,v1));
    }
#pragma unroll
    for (int b = 0; b < 16; b += 2) { float2 u=q[b], v=q[b+1]; q[b]=cadd(u,v); q[b+1]=csub(u,v); }
}

// Hand-folded swizzled addressing: IDX(base+p+r*L) == (sb ^ C_r) + (r*L).
template<int PASS>
__device__ __forceinline__ int psb(int t) {
    if constexpr (PASS == 0) {               // L=512, p=t
        return t ^ (((t>>4) ^ (t>>8)) & 15);
    } else if constexpr (PASS == 1) {        // L=32, base=(t>>5)<<9, p=t&31
        int p = t & 31, hb = t >> 5;
        return ((hb<<9) | p) ^ (((p>>4) ^ (hb<<1)) & 15);
    } else {                                 // L=2, base=(t>>1)<<5, p=t&1
        int h = t >> 1;
        return ((h<<5) | (t&1)) ^ (((h<<1) ^ (h>>3)) & 15);
    }
}
template<int PASS>
__device__ __forceinline__ int paddr(int sb, int r) {
    if constexpr (PASS == 0)      return (sb ^ (2*(r&7))) + (r<<9);
    else if constexpr (PASS == 1) return (sb ^ ((2*(r&7)) ^ (r>>3))) + (r<<5);
    else                          return sb ^ ((r<<1) ^ (r>>3));
}

// One radix-16 pass, twiddles from LDS table twT[m][row]:
//   row<32: TWB[q][m]=W16384^{32qm}; row=32+a: TL[a][m]=W16384^{2am}; row=64+c: TWC[c][m].
// Pass A twiddle W8192^{pm} = TL[p&31][m] * TWB[2*(p>>5)][m].
template<int PASS, bool DIT, bool PRUNED>
__device__ __forceinline__ void r16p(float2* lds, const float2 (*twT)[68], int t) {
    static constexpr int RV[16] = {0,8,4,12,2,10,6,14,1,9,5,13,3,11,7,15};
    const int sb = psb<PASS>(t);
    int rL, rH = 0;
    if constexpr (PASS == 0) { rL = 32 + (t & 31); rH = (t >> 5) << 1; }
    else if constexpr (PASS == 1) { rL = t & 31; }
    else { rL = 64 + (t & 1); }
    float2 q[16];
    if constexpr (PRUNED) {
#pragma unroll
        for (int r = 0; r < 8; ++r) { q[r] = lds[paddr<PASS>(sb, r)]; q[r+8] = q[r]; }
    } else {
#pragma unroll
        for (int r = 0; r < 16; ++r) q[r] = lds[paddr<PASS>(sb, r)];
    }
    if constexpr (DIT) {
#pragma unroll
        for (int m = 1; m < 16; ++m) {
            float2 w = twT[m][rL];
            if constexpr (PASS == 0) w = cmul(w, twT[m][rH]);
            q[m] = cmul(q[m], w);
        }
        dft16<true>(q);
    } else {
        dft16<!PRUNED>(q);
#pragma unroll
        for (int m = 1; m < 16; ++m) {
            float2 w = twT[m][rL];
            if constexpr (PASS == 0) w = cmul(w, twT[m][rH]);
            q[RV[m]] = cmul(q[RV[m]], w);
        }
    }
#pragma unroll
    for (int m = 0; m < 16; ++m) lds[paddr<PASS>(sb, m)] = q[RV[m]];
}

// copy twiddle tables global -> LDS (transposed): 66 rows x 16 elems
__device__ __forceinline__ void load_twT(float2 (*twT)[68], const float* __restrict__ ws, int tid) {
    const float2* gTWB = (const float2*)(ws + OFF_TWB);
    const float2* gTL  = (const float2*)(ws + OFF_TL);
    const float2* gTWC = (const float2*)(ws + OFF_TWC);
    for (int idx = tid; idx < 16*66; idx += BT) {
        int r = idx >> 4, m = idx & 15;
        float2 v;
        if (r < 32)      v = gTWB[(r << 4) + m];
        else if (r < 64) v = gTL[((r - 32) << 4) + m];
        else             v = gTWC[((r - 64) << 4) + m];
        twT[m][r] = v;
    }
}

// spectral multiply for bin pair (k, 8192-k): o1/o2 are swapped v'[k], v'[8192-k]
__device__ __forceinline__ void specpair(float2 V1, float2 V2, float4 kv, float2 W,
                                         float2& o1, float2& o2) {
    float2 Eh = make_float2(V1.x + V2.x, V1.y - V2.y);
    float2 Oh = make_float2(V1.y + V2.y, V2.x - V1.x);
    float2 S = make_float2(kv.x, kv.y);
    float a = W.x*kv.z, b = W.y*kv.w, cc = W.x*kv.w, dd = W.y*kv.z;
    float2 T  = make_float2(a - b, cc + dd);
    float2 T2 = make_float2(a + b, cc - dd);
    float2 Ep = cadd(cmul(Eh, S), cmul(Oh, T));
    float2 Op = cadd(cmul(Eh, T2), cmul(Oh, S));
    o1 = make_float2(Ep.y + Op.x, Ep.x - Op.y);
    o2 = make_float2(Op.x - Ep.y, Ep.x + Op.y);
}

// merged init (block 0: twiddle tables via double-precision factor tables) + MLP (blocks 1..16)
__global__ __launch_bounds__(512) void k_pre(const float* __restrict__ z, const float* __restrict__ freq,
        const float* __restrict__ W0, const float* __restrict__ b0,
        const float* __restrict__ W1, const float* __restrict__ b1,
        const float* __restrict__ W2, const float* __restrict__ b2,
        float* __restrict__ ws, float* __restrict__ H) {
    __shared__ double2 lA[128], lB[128];
    const int t = threadIdx.x;
    if (blockIdx.x == 0) {
        const double K = -2.0 * 3.14159265358979323846 / 16384.0;
        if (t < 128)      { double a = K * (double)(t << 7); lA[t] = make_double2(cos(a), sin(a)); }
        else if (t < 256) { int b = t - 128; double a = K * (double)b; lB[b] = make_double2(cos(a), sin(a)); }
        __syncthreads();
        auto wf = [&](int e) -> float2 {
            e &= 16383;
            double2 A = lA[e >> 7], B = lB[e & 127];
            return make_float2((float)(A.x*B.x - A.y*B.y), (float)(A.x*B.y + A.y*B.x));
        };
        float2* tw16 = (float2*)(ws + OFF_TW16);
        for (int k = t; k <= 2048; k += 512) tw16[k] = wf(k);
        if (t < 32) {
            float2* rowL = (float2*)(ws + OFF_TL)  + (t << 4);
            float2* rowB = (float2*)(ws + OFF_TWB) + (t << 4);
#pragma unroll
            for (int m = 0; m < 16; ++m) { rowL[m] = wf(2*t*m); rowB[m] = wf(32*t*m); }
        } else if (t < 34) {
            int c2 = t - 32;
            float2* rowC = (float2*)(ws + OFF_TWC) + (c2 << 4);
#pragma unroll
            for (int m = 0; m < 16; ++m) rowC[m] = wf(512*c2*m);
        }
    } else {
        const int j = ((blockIdx.x - 1) << 9) + t;
        const float z0 = z[j*3+0], z1 = z[j*3+1], z2 = z[j*3+2];
        float h[16], g[16];
#pragma unroll
        for (int m = 0; m < 16; ++m)
            h[m] = sinf(freq[m] * (z0*W0[m] + z1*W0[16+m] + z2*W0[32+m] + b0[m]));
#pragma unroll
        for (int m = 0; m < 16; ++m) {
            float a = b1[m];
#pragma unroll
            for (int p = 0; p < 16; ++p) a += h[p] * W1[p*16+m];
            g[m] = sinf(freq[m] * a);
        }
#pragma unroll
        for (int m = 0; m < 16; ++m) {
            float a = b2[m];
#pragma unroll
            for (int p = 0; p < 16; ++p) a += g[p] * W2[p*16+m];
            h[m] = sinf(freq[m] * a);
        }
        float4* hp = (float4*)(H + (j << 4));   // row-major [8192][16]
        hp[0] = make_float4(h[0],  h[1],  h[2],  h[3]);
        hp[1] = make_float4(h[4],  h[5],  h[6],  h[7]);
        hp[2] = make_float4(h[8],  h[9],  h[10], h[11]);
        hp[3] = make_float4(h[12], h[13], h[14], h[15]);
    }
}

// Two channels per block (one per 512-thread half): filter -> pruned fwd FFT
// -> fused(r2+unpack) -> store (S~,D~)
__global__ __launch_bounds__(BT) void k_filter(const float* __restrict__ H, const float* __restrict__ t,
        const float* __restrict__ deltas, const float* __restrict__ W3,
        const float* __restrict__ b3, const float* __restrict__ ws,
        float* __restrict__ KfF) {
    __shared__ float2 lds2[2][LSEQ];
    __shared__ float2 twT[16][68];
    const int tid = threadIdx.x;
    const int half = tid >> 9, tt = tid & (NT-1);
    const int c = (blockIdx.x << 1) + half;
    float2* lds = lds2[half];
    load_twT(twT, ws, tid);
    float4 w3a = make_float4(W3[0*NCH+c],  W3[1*NCH+c],  W3[2*NCH+c],  W3[3*NCH+c]);
    float4 w3b = make_float4(W3[4*NCH+c],  W3[5*NCH+c],  W3[6*NCH+c],  W3[7*NCH+c]);
    float4 w3c = make_float4(W3[8*NCH+c],  W3[9*NCH+c],  W3[10*NCH+c], W3[11*NCH+c]);
    float4 w3d = make_float4(W3[12*NCH+c], W3[13*NCH+c], W3[14*NCH+c], W3[15*NCH+c]);
    const float b3c = b3[c];
    const float ad = fabsf(deltas[c]);
    const int sbA = psb<0>(tt);
#pragma unroll 2
    for (int j = 0; j < 8; ++j) {
        int n = tt + (j << 9);
        const float4* hp = (const float4*)(H + (n << 5));
        float4 p0 = hp[0], p1 = hp[1], p2 = hp[2], p3 = hp[3];
        float4 q0 = hp[4], q1 = hp[5], q2 = hp[6], q3 = hp[7];
        float s0 = b3c + p0.x*w3a.x + p0.y*w3a.y + p0.z*w3a.z + p0.w*w3a.w
                       + p1.x*w3b.x + p1.y*w3b.y + p1.z*w3b.z + p1.w*w3b.w
                       + p2.x*w3c.x + p2.y*w3c.y + p2.z*w3c.z + p2.w*w3c.w
                       + p3.x*w3d.x + p3.y*w3d.y + p3.z*w3d.z + p3.w*w3d.w;
        float s1 = b3c + q0.x*w3a.x + q0.y*w3a.y + q0.z*w3a.z + q0.w*w3a.w
                       + q1.x*w3b.x + q1.y*w3b.y + q1.z*w3b.z + q1.w*w3b.w
                       + q2.x*w3c.x + q2.y*w3c.y + q2.z*w3c.z + q2.w*w3c.w
                       + q3.x*w3d.x + q3.y*w3d.y + q3.z*w3d.z + q3.w*w3d.w;
        float2 tv = ((const float2*)t)[n];
        lds[(sbA ^ (2*j)) + (j<<9)] = make_float2(s0 * expf(-tv.x*ad), s1 * expf(-tv.y*ad));
    }
    __syncthreads();
    r16p<0,false,true >(lds, twT, tt); __syncthreads();
    r16p<1,false,false>(lds, twT, tt); wave_sync();
    r16p<2,false,false>(lds, twT, tt); __syncthreads();

    float4* kf4 = (float4*)KfF + (size_t)c * 4096;
    const float2* tw16 = (const float2*)(ws + OFF_TW16);
    const float sc = 1.0f / 32768.0f;
#pragma unroll 2
    for (int it = 0; it < 4; ++it) {
        int k  = tt + 1 + (it << 9);   // 1..2048
        int jj = 4096 - k;             // 2048..4095 (k=2048: idempotent dup)
        int pA = IDX(drev(k)), pB = IDX(drev(jj));
        float2 uA = lds[pA], vA = lds[pA^1];
        float2 uB = lds[pB], vB = lds[pB^1];
        float2 Vk = cadd(uA, vA), Vk4 = csub(uA, vA);   // bins k, k+4096
        float2 Vj = cadd(uB, vB), Vj4 = csub(uB, vB);   // bins jj, jj+4096 (=8192-k)
        float2 W  = tw16[k];
        float2 Wj = make_float2(-W.y, -W.x);            // tw16[4096-k]
        {
            float2 E = make_float2(Vk.x + Vj4.x, Vk.y - Vj4.y);
            float2 O = make_float2(Vk.y + Vj4.y, Vj4.x - Vk.x);
            float2 D = cmul(W, O);
            kf4[k] = make_float4(E.x*sc, E.y*sc, D.x*sc, D.y*sc);
        }
        {
            float2 E = make_float2(Vj.x + Vk4.x, Vj.y - Vk4.y);
            float2 O = make_float2(Vj.y + Vk4.y, Vk4.x - Vj.x);
            float2 D = cmul(Wj, O);
            kf4[jj] = make_float4(E.x*sc, E.y*sc, D.x*sc, D.y*sc);
        }
    }
    if (tt == 0) {
        float2 u = lds[0], v = lds[1];          // IDX(0)=0, IDX(1)=1
        float2 V0 = cadd(u, v), VN = csub(u, v);
        kf4[0] = make_float4((V0.x + V0.y)/16384.f, (V0.x - V0.y)/16384.f,
                             VN.x/8192.f, -VN.y/8192.f);
    }
}

// Block = channel c; half h = batches 4h..4h+3 (4 rows sequential, prefetched).
// Both halves share kf4[c]/tw16 (L1-hot). pack x -> pruned fwd FFT ->
// fused(r2+spectral+inv-r2) -> DIT net -> out.
__global__ __launch_bounds__(BT) void k_main(const float* __restrict__ x, const float* __restrict__ ws,
        const float* __restrict__ KfF, const float* __restrict__ bias,
        float* __restrict__ out) {
    __shared__ float2 lds2[2][LSEQ];
    __shared__ float2 twT[16][68];
    const int c = blockIdx.x;                   // 0..767
    const int tid = threadIdx.x;
    const int half = tid >> 9, tt = tid & (NT-1);
    float2* lds = lds2[half];
    const float4* kf4 = (const float4*)KfF + (size_t)c * 4096;
    const float2* tw16 = (const float2*)(ws + OFF_TW16);
    const size_t rowstride = (size_t)NCH * LSEQ;
    const float* xbase = x + (size_t)(half*4) * rowstride + (size_t)c * LSEQ;
    float* obase = out + (size_t)(half*4) * rowstride + (size_t)c * LSEQ;
    const float bc = bias[c];

    // staging addresses: IDX(2i) = (EB ^ (j<<2)) + (j<<10), IDX(2i+1) = that ^ 1
    const int EB = (tt << 1) ^ (((tt>>3) ^ (tt>>7)) & 15);

    float4 pf[4];
#pragma unroll
    for (int j = 0; j < 4; ++j) pf[j] = ((const float4*)xbase)[tt + (j<<9)];
    load_twT(twT, ws, tid);

    for (int rr = 0; rr < 4; ++rr) {
        float4 xs[4];
#pragma unroll
        for (int j = 0; j < 4; ++j) {
            xs[j] = pf[j];
            int a0 = (EB ^ (j<<2)) + (j<<10);
            lds[a0]   = make_float2(xs[j].x, xs[j].y);
            lds[a0^1] = make_float2(xs[j].z, xs[j].w);
        }
        if (rr < 3) {   // prefetch next row's x; hidden under this row's FFT
            const float4* xn = (const float4*)(xbase + (size_t)(rr+1) * rowstride);
#pragma unroll
            for (int j = 0; j < 4; ++j) pf[j] = xn[tt + (j<<9)];
        }
        __syncthreads();                              // also covers twT copy (rr==0)
        r16p<0,false,true >(lds, twT, tt); __syncthreads();
        r16p<1,false,false>(lds, twT, tt); wave_sync();
        r16p<2,false,false>(lds, twT, tt); __syncthreads();

        // fused fwd-r2 + spectral multiply + inverse-r2, per closed quad of bins
#pragma unroll 2
        for (int it = 0; it < 4; ++it) {
            int k  = tt + 1 + (it << 9);   // 1..2048
            int jj = 4096 - k;
            int pA = IDX(drev(k)), pB = IDX(drev(jj));
            float2 uA = lds[pA], vA = lds[pA^1];
            float2 uB = lds[pB], vB = lds[pB^1];
            float2 Vk = cadd(uA, vA), Vk4 = csub(uA, vA);   // bins k, k+4096
            float2 Vj = cadd(uB, vB), Vj4 = csub(uB, vB);   // bins jj, 8192-k
            float4 kvk = kf4[k], kvj = kf4[jj];
            float2 W  = tw16[k];
            float2 Wj = make_float2(-W.y, -W.x);
            float2 r1, r2, r1j, r2j;
            specpair(Vk, Vj4, kvk, W,  r1,  r2);   // v'[k],  v'[8192-k]
            specpair(Vj, Vk4, kvj, Wj, r1j, r2j);  // v'[jj], v'[4096+k]
            lds[pA]   = cadd(r1, r2j);  lds[pA^1] = csub(r1, r2j);
            lds[pB]   = cadd(r1j, r2);  lds[pB^1] = csub(r1j, r2);
        }
        if (tt == 0) {
            float2 u = lds[0], v = lds[1];
            float2 V0 = cadd(u, v), VN = csub(u, v);        // bins 0, 4096
            float4 kv = kf4[0];
            float U0 = V0.x + V0.y, UL = V0.x - V0.y;
            float re = U0*kv.x + UL*kv.y;
            float im = U0*kv.x - UL*kv.y;
            float2 s0 = make_float2(im, re);
            float2 P = make_float2(VN.x*kv.z + VN.y*kv.w, VN.x*kv.w - VN.y*kv.z);
            float2 s1 = make_float2(-P.y, P.x);
            lds[0] = cadd(s0, s1);
            lds[1] = csub(s0, s1);
        }
        __syncthreads();

        r16p<2,true,false>(lds, twT, tt); wave_sync();
        r16p<1,true,false>(lds, twT, tt); __syncthreads();
        r16p<0,true,false>(lds, twT, tt); __syncthreads();

        float4* orow4 = (float4*)(obase + (size_t)rr * rowstride);
#pragma unroll
        for (int j = 0; j < 4; ++j) {
            int a0 = (EB ^ (j<<2)) + (j<<10);
            float2 wA = lds[a0], wB = lds[a0^1];
            float4 xv = xs[j];
            orow4[tt + (j<<9)] = make_float4(wA.y + xv.x*bc, wA.x + xv.y*bc,
                                             wB.y + xv.z*bc, wB.x + xv.w*bc);
        }
        if (rr < 3) __syncthreads();   // protect lds before next row's staging
    }
}

extern "C" void kernel_launch(void* const* d_in, const int* in_sizes, int n_in,
                              void* d_out, int out_size, void* d_ws, size_t ws_size,
                              hipStream_t stream) {
    const float* x      = (const float*)d_in[0];
    const float* z      = (const float*)d_in[2];
    const float* t      = (const float*)d_in[3];
    const float* deltas = (const float*)d_in[4];
    const float* freq   = (const float*)d_in[5];
    const float* W0     = (const float*)d_in[6];
    const float* b0     = (const float*)d_in[7];
    const float* W1     = (const float*)d_in[8];
    const float* b1     = (const float*)d_in[9];
    const float* W2     = (const float*)d_in[10];
    const float* b2     = (const float*)d_in[11];
    const float* W3     = (const float*)d_in[12];
    const float* b3     = (const float*)d_in[13];
    const float* bias   = (const float*)d_in[14];
    float* out = (float*)d_out;
    float* ws  = (float*)d_ws;
    float* H   = ws + OFF_H;
    float* Kf  = ws + OFF_KF;

    hipLaunchKernelGGL(k_pre, dim3(17), dim3(512), 0, stream, z, freq, W0, b0, W1, b1, W2, b2, ws, H);
    hipLaunchKernelGGL(k_filter, dim3(NCH/2), dim3(BT), 0, stream, H, t, deltas, W3, b3, ws, Kf);
    hipLaunchKernelGGL(k_main, dim3(NCH), dim3(BT), 0, stream, x, ws, Kf, bias, out);
}

// Round 5
// 1015.307 us; speedup vs baseline: 1.0150x; 1.0150x over previous
//
#include <hip/hip_runtime.h>
#include <math.h>

// HyenaFilter: y = irfft(rfft(x,2L) * rfft(k,2L))[..., :L] + x*bias
// Register-blocked mixed-radix [16,16,16,2] FFT. Round-5 revision:
//  - R4 structure (1024-thread blocks, two independent rows, 136.7 KB LDS,
//    16 waves/CU in one workgroup) PLUS __launch_bounds__(BT, 1): min-blocks=1
//    tells the allocator the truth (1 block/CU, 4 waves/SIMD) and raises the
//    VGPR budget to 128. R4's default heuristic clamped to 64 VGPR and spilled
//    ~1.9 GB of scratch (FETCH 1.12GB/WRITE 1.08GB, VALUBusy 27%).
//  - everything else identical to R4: LDS twiddle tables, folded XOR-swizzle,
//    wave-local B<->C sync, fused r2+spectral quad, pruned first fwd pass.

#define LSEQ 8192
#define NCH 768
#define NBATCH 8
#define NT 512            // threads per half (per row)
#define BT 1024           // threads per block

// ws layout (float offsets)
#define OFF_TWB  0        // 32 rows x 16 float2 : W16384^{32*q*m}   (pass B; pass-A high = rows 2b)
#define OFF_TW16 1024     // 2049 float2         : W16384^k, k<=2048
#define OFF_TL   5124     // 32 rows x 16 float2 : W16384^{2*a*m}    (pass A low)
#define OFF_TWC  6660     // 2 rows x 16 float2  : W16384^{512*p*m}  (pass C)
#define OFF_H    10240    // 8192 x 16 floats (MLP features, row-major)
#define OFF_KF   141312   // 768 x 4096 float4 (S~, D~ per bin pair)

__device__ __forceinline__ float2 cadd(float2 a, float2 b){ return make_float2(a.x+b.x, a.y+b.y); }
__device__ __forceinline__ float2 csub(float2 a, float2 b){ return make_float2(a.x-b.x, a.y-b.y); }
__device__ __forceinline__ float2 cmul(float2 a, float2 b){ return make_float2(a.x*b.x - a.y*b.y, a.x*b.y + a.y*b.x); }
__device__ __forceinline__ float2 mni(float2 a){ return make_float2(a.y, -a.x); }  // * -i

// wave-local LDS producer->consumer sync (exchange confined to one wave)
__device__ __forceinline__ void wave_sync(){
    asm volatile("s_waitcnt lgkmcnt(0)" ::: "memory");
}

// generic swizzle (used only in the spectral stage)
__device__ __forceinline__ int IDX(int i){ return i ^ (((i>>4) ^ (i>>8)) & 15); }
// digit-reversal: bin k -> slot after DIF passes [16(512),16(32),16(2)] (pre-r2, slot even)
__device__ __forceinline__ int drev(int k){
    return ((k & 15) << 9) | (((k >> 4) & 15) << 5) | (((k >> 8) & 15) << 1) | (k >> 12);
}

#define C1 0.923879532511286756f
#define S1 0.382683432365089772f
#define R2 0.707106781186547524f

// natural-in DFT-16; output bin m in q[rv[m]]. FULL=false: inputs 8..15 are
// pre-duplicated copies of 0..7 (zero upper half), stage-1 add/sub skipped.
template<bool FULL>
__device__ __forceinline__ void dft16(float2 q[16]) {
    if constexpr (FULL) {
#pragma unroll
        for (int j = 0; j < 8; ++j) { float2 u=q[j], v=q[j+8]; q[j]=cadd(u,v); q[j+8]=csub(u,v); }
    }
    q[9]  = cmul(q[9],  make_float2( C1,-S1));
    q[10] = cmul(q[10], make_float2( R2,-R2));
    q[11] = cmul(q[11], make_float2( S1,-C1));
    q[12] = mni(q[12]);
    q[13] = cmul(q[13], make_float2(-S1,-C1));
    q[14] = cmul(q[14], make_float2(-R2,-R2));
    q[15] = cmul(q[15], make_float2(-C1,-S1));
#pragma unroll
    for (int b = 0; b < 16; b += 8) {
#pragma unroll
        for (int j = 0; j < 4; ++j) { float2 u=q[b+j], v=q[b+j+4]; q[b+j]=cadd(u,v); q[b+j+4]=csub(u,v); }
        q[b+5] = cmul(q[b+5], make_float2( R2,-R2));
        q[b+6] = mni(q[b+6]);
        q[b+7] = cmul(q[b+7], make_float2(-R2,-R2));
    }
#pragma unroll
    for (int b = 0; b < 16; b += 4) {
        float2 u0=q[b], v0=q[b+2], u1=q[b+1], v1=q[b+3];
        q[b]=cadd(u0,v0); q[b+2]=csub(u0,v0);
        q[b+1]=cadd(u1,v1); q[b+3]=mni(csub(u1,v1));
    }
#pragma unroll
    for (int b = 0; b < 16; b += 2) { float2 u=q[b], v=q[b+1]; q[b]=cadd(u,v); q[b+1]=csub(u,v); }
}

// Hand-folded swizzled addressing: IDX(base+p+r*L) == (sb ^ C_r) + (r*L).
template<int PASS>
__device__ __forceinline__ int psb(int t) {
    if constexpr (PASS == 0) {               // L=512, p=t
        return t ^ (((t>>4) ^ (t>>8)) & 15);
    } else if constexpr (PASS == 1) {        // L=32, base=(t>>5)<<9, p=t&31
        int p = t & 31, hb = t >> 5;
        return ((hb<<9) | p) ^ (((p>>4) ^ (hb<<1)) & 15);
    } else {                                 // L=2, base=(t>>1)<<5, p=t&1
        int h = t >> 1;
        return ((h<<5) | (t&1)) ^ (((h<<1) ^ (h>>3)) & 15);
    }
}
template<int PASS>
__device__ __forceinline__ int paddr(int sb, int r) {
    if constexpr (PASS == 0)      return (sb ^ (2*(r&7))) + (r<<9);
    else if constexpr (PASS == 1) return (sb ^ ((2*(r&7)) ^ (r>>3))) + (r<<5);
    else                          return sb ^ ((r<<1) ^ (r>>3));
}

// One radix-16 pass, twiddles from LDS table twT[m][row]:
//   row<32: TWB[q][m]=W16384^{32qm}; row=32+a: TL[a][m]=W16384^{2am}; row=64+c: TWC[c][m].
// Pass A twiddle W8192^{pm} = TL[p&31][m] * TWB[2*(p>>5)][m].
template<int PASS, bool DIT, bool PRUNED>
__device__ __forceinline__ void r16p(float2* lds, const float2 (*twT)[68], int t) {
    static constexpr int RV[16] = {0,8,4,12,2,10,6,14,1,9,5,13,3,11,7,15};
    const int sb = psb<PASS>(t);
    int rL, rH = 0;
    if constexpr (PASS == 0) { rL = 32 + (t & 31); rH = (t >> 5) << 1; }
    else if constexpr (PASS == 1) { rL = t & 31; }
    else { rL = 64 + (t & 1); }
    float2 q[16];
    if constexpr (PRUNED) {
#pragma unroll
        for (int r = 0; r < 8; ++r) { q[r] = lds[paddr<PASS>(sb, r)]; q[r+8] = q[r]; }
    } else {
#pragma unroll
        for (int r = 0; r < 16; ++r) q[r] = lds[paddr<PASS>(sb, r)];
    }
    if constexpr (DIT) {
#pragma unroll
        for (int m = 1; m < 16; ++m) {
            float2 w = twT[m][rL];
            if constexpr (PASS == 0) w = cmul(w, twT[m][rH]);
            q[m] = cmul(q[m], w);
        }
        dft16<true>(q);
    } else {
        dft16<!PRUNED>(q);
#pragma unroll
        for (int m = 1; m < 16; ++m) {
            float2 w = twT[m][rL];
            if constexpr (PASS == 0) w = cmul(w, twT[m][rH]);
            q[RV[m]] = cmul(q[RV[m]], w);
        }
    }
#pragma unroll
    for (int m = 0; m < 16; ++m) lds[paddr<PASS>(sb, m)] = q[RV[m]];
}

// copy twiddle tables global -> LDS (transposed): 66 rows x 16 elems
__device__ __forceinline__ void load_twT(float2 (*twT)[68], const float* __restrict__ ws, int tid) {
    const float2* gTWB = (const float2*)(ws + OFF_TWB);
    const float2* gTL  = (const float2*)(ws + OFF_TL);
    const float2* gTWC = (const float2*)(ws + OFF_TWC);
    for (int idx = tid; idx < 16*66; idx += BT) {
        int r = idx >> 4, m = idx & 15;
        float2 v;
        if (r < 32)      v = gTWB[(r << 4) + m];
        else if (r < 64) v = gTL[((r - 32) << 4) + m];
        else             v = gTWC[((r - 64) << 4) + m];
        twT[m][r] = v;
    }
}

// spectral multiply for bin pair (k, 8192-k): o1/o2 are swapped v'[k], v'[8192-k]
__device__ __forceinline__ void specpair(float2 V1, float2 V2, float4 kv, float2 W,
                                         float2& o1, float2& o2) {
    float2 Eh = make_float2(V1.x + V2.x, V1.y - V2.y);
    float2 Oh = make_float2(V1.y + V2.y, V2.x - V1.x);
    float2 S = make_float2(kv.x, kv.y);
    float a = W.x*kv.z, b = W.y*kv.w, cc = W.x*kv.w, dd = W.y*kv.z;
    float2 T  = make_float2(a - b, cc + dd);
    float2 T2 = make_float2(a + b, cc - dd);
    float2 Ep = cadd(cmul(Eh, S), cmul(Oh, T));
    float2 Op = cadd(cmul(Eh, T2), cmul(Oh, S));
    o1 = make_float2(Ep.y + Op.x, Ep.x - Op.y);
    o2 = make_float2(Op.x - Ep.y, Ep.x + Op.y);
}

// merged init (block 0: twiddle tables via double-precision factor tables) + MLP (blocks 1..16)
__global__ __launch_bounds__(512) void k_pre(const float* __restrict__ z, const float* __restrict__ freq,
        const float* __restrict__ W0, const float* __restrict__ b0,
        const float* __restrict__ W1, const float* __restrict__ b1,
        const float* __restrict__ W2, const float* __restrict__ b2,
        float* __restrict__ ws, float* __restrict__ H) {
    __shared__ double2 lA[128], lB[128];
    const int t = threadIdx.x;
    if (blockIdx.x == 0) {
        const double K = -2.0 * 3.14159265358979323846 / 16384.0;
        if (t < 128)      { double a = K * (double)(t << 7); lA[t] = make_double2(cos(a), sin(a)); }
        else if (t < 256) { int b = t - 128; double a = K * (double)b; lB[b] = make_double2(cos(a), sin(a)); }
        __syncthreads();
        auto wf = [&](int e) -> float2 {
            e &= 16383;
            double2 A = lA[e >> 7], B = lB[e & 127];
            return make_float2((float)(A.x*B.x - A.y*B.y), (float)(A.x*B.y + A.y*B.x));
        };
        float2* tw16 = (float2*)(ws + OFF_TW16);
        for (int k = t; k <= 2048; k += 512) tw16[k] = wf(k);
        if (t < 32) {
            float2* rowL = (float2*)(ws + OFF_TL)  + (t << 4);
            float2* rowB = (float2*)(ws + OFF_TWB) + (t << 4);
#pragma unroll
            for (int m = 0; m < 16; ++m) { rowL[m] = wf(2*t*m); rowB[m] = wf(32*t*m); }
        } else if (t < 34) {
            int c2 = t - 32;
            float2* rowC = (float2*)(ws + OFF_TWC) + (c2 << 4);
#pragma unroll
            for (int m = 0; m < 16; ++m) rowC[m] = wf(512*c2*m);
        }
    } else {
        const int j = ((blockIdx.x - 1) << 9) + t;
        const float z0 = z[j*3+0], z1 = z[j*3+1], z2 = z[j*3+2];
        float h[16], g[16];
#pragma unroll
        for (int m = 0; m < 16; ++m)
            h[m] = sinf(freq[m] * (z0*W0[m] + z1*W0[16+m] + z2*W0[32+m] + b0[m]));
#pragma unroll
        for (int m = 0; m < 16; ++m) {
            float a = b1[m];
#pragma unroll
            for (int p = 0; p < 16; ++p) a += h[p] * W1[p*16+m];
            g[m] = sinf(freq[m] * a);
        }
#pragma unroll
        for (int m = 0; m < 16; ++m) {
            float a = b2[m];
#pragma unroll
            for (int p = 0; p < 16; ++p) a += g[p] * W2[p*16+m];
            h[m] = sinf(freq[m] * a);
        }
        float4* hp = (float4*)(H + (j << 4));   // row-major [8192][16]
        hp[0] = make_float4(h[0],  h[1],  h[2],  h[3]);
        hp[1] = make_float4(h[4],  h[5],  h[6],  h[7]);
        hp[2] = make_float4(h[8],  h[9],  h[10], h[11]);
        hp[3] = make_float4(h[12], h[13], h[14], h[15]);
    }
}

// Two channels per block (one per 512-thread half): filter -> pruned fwd FFT
// -> fused(r2+unpack) -> store (S~,D~)
__global__ __launch_bounds__(BT, 1) void k_filter(const float* __restrict__ H, const float* __restrict__ t,
        const float* __restrict__ deltas, const float* __restrict__ W3,
        const float* __restrict__ b3, const float* __restrict__ ws,
        float* __restrict__ KfF) {
    __shared__ float2 lds2[2][LSEQ];
    __shared__ float2 twT[16][68];
    const int tid = threadIdx.x;
    const int half = tid >> 9, tt = tid & (NT-1);
    const int c = (blockIdx.x << 1) + half;
    float2* lds = lds2[half];
    load_twT(twT, ws, tid);
    float4 w3a = make_float4(W3[0*NCH+c],  W3[1*NCH+c],  W3[2*NCH+c],  W3[3*NCH+c]);
    float4 w3b = make_float4(W3[4*NCH+c],  W3[5*NCH+c],  W3[6*NCH+c],  W3[7*NCH+c]);
    float4 w3c = make_float4(W3[8*NCH+c],  W3[9*NCH+c],  W3[10*NCH+c], W3[11*NCH+c]);
    float4 w3d = make_float4(W3[12*NCH+c], W3[13*NCH+c], W3[14*NCH+c], W3[15*NCH+c]);
    const float b3c = b3[c];
    const float ad = fabsf(deltas[c]);
    const int sbA = psb<0>(tt);
#pragma unroll 2
    for (int j = 0; j < 8; ++j) {
        int n = tt + (j << 9);
        const float4* hp = (const float4*)(H + (n << 5));
        float4 p0 = hp[0], p1 = hp[1], p2 = hp[2], p3 = hp[3];
        float4 q0 = hp[4], q1 = hp[5], q2 = hp[6], q3 = hp[7];
        float s0 = b3c + p0.x*w3a.x + p0.y*w3a.y + p0.z*w3a.z + p0.w*w3a.w
                       + p1.x*w3b.x + p1.y*w3b.y + p1.z*w3b.z + p1.w*w3b.w
                       + p2.x*w3c.x + p2.y*w3c.y + p2.z*w3c.z + p2.w*w3c.w
                       + p3.x*w3d.x + p3.y*w3d.y + p3.z*w3d.z + p3.w*w3d.w;
        float s1 = b3c + q0.x*w3a.x + q0.y*w3a.y + q0.z*w3a.z + q0.w*w3a.w
                       + q1.x*w3b.x + q1.y*w3b.y + q1.z*w3b.z + q1.w*w3b.w
                       + q2.x*w3c.x + q2.y*w3c.y + q2.z*w3c.z + q2.w*w3c.w
                       + q3.x*w3d.x + q3.y*w3d.y + q3.z*w3d.z + q3.w*w3d.w;
        float2 tv = ((const float2*)t)[n];
        lds[(sbA ^ (2*j)) + (j<<9)] = make_float2(s0 * expf(-tv.x*ad), s1 * expf(-tv.y*ad));
    }
    __syncthreads();
    r16p<0,false,true >(lds, twT, tt); __syncthreads();
    r16p<1,false,false>(lds, twT, tt); wave_sync();
    r16p<2,false,false>(lds, twT, tt); __syncthreads();

    float4* kf4 = (float4*)KfF + (size_t)c * 4096;
    const float2* tw16 = (const float2*)(ws + OFF_TW16);
    const float sc = 1.0f / 32768.0f;
#pragma unroll 2
    for (int it = 0; it < 4; ++it) {
        int k  = tt + 1 + (it << 9);   // 1..2048
        int jj = 4096 - k;             // 2048..4095 (k=2048: idempotent dup)
        int pA = IDX(drev(k)), pB = IDX(drev(jj));
        float2 uA = lds[pA], vA = lds[pA^1];
        float2 uB = lds[pB], vB = lds[pB^1];
        float2 Vk = cadd(uA, vA), Vk4 = csub(uA, vA);   // bins k, k+4096
        float2 Vj = cadd(uB, vB), Vj4 = csub(uB, vB);   // bins jj, jj+4096 (=8192-k)
        float2 W  = tw16[k];
        float2 Wj = make_float2(-W.y, -W.x);            // tw16[4096-k]
        {
            float2 E = make_float2(Vk.x + Vj4.x, Vk.y - Vj4.y);
            float2 O = make_float2(Vk.y + Vj4.y, Vj4.x - Vk.x);
            float2 D = cmul(W, O);
            kf4[k] = make_float4(E.x*sc, E.y*sc, D.x*sc, D.y*sc);
        }
        {
            float2 E = make_float2(Vj.x + Vk4.x, Vj.y - Vk4.y);
            float2 O = make_float2(Vj.y + Vk4.y, Vk4.x - Vj.x);
            float2 D = cmul(Wj, O);
            kf4[jj] = make_float4(E.x*sc, E.y*sc, D.x*sc, D.y*sc);
        }
    }
    if (tt == 0) {
        float2 u = lds[0], v = lds[1];          // IDX(0)=0, IDX(1)=1
        float2 V0 = cadd(u, v), VN = csub(u, v);
        kf4[0] = make_float4((V0.x + V0.y)/16384.f, (V0.x - V0.y)/16384.f,
                             VN.x/8192.f, -VN.y/8192.f);
    }
}

// Block = channel c; half h = batches 4h..4h+3 (4 rows sequential, prefetched).
// Both halves share kf4[c]/tw16 (L1-hot). pack x -> pruned fwd FFT ->
// fused(r2+spectral+inv-r2) -> DIT net -> out.
__global__ __launch_bounds__(BT, 1) void k_main(const float* __restrict__ x, const float* __restrict__ ws,
        const float* __restrict__ KfF, const float* __restrict__ bias,
        float* __restrict__ out) {
    __shared__ float2 lds2[2][LSEQ];
    __shared__ float2 twT[16][68];
    const int c = blockIdx.x;                   // 0..767
    const int tid = threadIdx.x;
    const int half = tid >> 9, tt = tid & (NT-1);
    float2* lds = lds2[half];
    const float4* kf4 = (const float4*)KfF + (size_t)c * 4096;
    const float2* tw16 = (const float2*)(ws + OFF_TW16);
    const size_t rowstride = (size_t)NCH * LSEQ;
    const float* xbase = x + (size_t)(half*4) * rowstride + (size_t)c * LSEQ;
    float* obase = out + (size_t)(half*4) * rowstride + (size_t)c * LSEQ;
    const float bc = bias[c];

    // staging addresses: IDX(2i) = (EB ^ (j<<2)) + (j<<10), IDX(2i+1) = that ^ 1
    const int EB = (tt << 1) ^ (((tt>>3) ^ (tt>>7)) & 15);

    float4 pf[4];
#pragma unroll
    for (int j = 0; j < 4; ++j) pf[j] = ((const float4*)xbase)[tt + (j<<9)];
    load_twT(twT, ws, tid);

    for (int rr = 0; rr < 4; ++rr) {
        float4 xs[4];
#pragma unroll
        for (int j = 0; j < 4; ++j) {
            xs[j] = pf[j];
            int a0 = (EB ^ (j<<2)) + (j<<10);
            lds[a0]   = make_float2(xs[j].x, xs[j].y);
            lds[a0^1] = make_float2(xs[j].z, xs[j].w);
        }
        if (rr < 3) {   // prefetch next row's x; hidden under this row's FFT
            const float4* xn = (const float4*)(xbase + (size_t)(rr+1) * rowstride);
#pragma unroll
            for (int j = 0; j < 4; ++j) pf[j] = xn[tt + (j<<9)];
        }
        __syncthreads();                              // also covers twT copy (rr==0)
        r16p<0,false,true >(lds, twT, tt); __syncthreads();
        r16p<1,false,false>(lds, twT, tt); wave_sync();
        r16p<2,false,false>(lds, twT, tt); __syncthreads();

        // fused fwd-r2 + spectral multiply + inverse-r2, per closed quad of bins
#pragma unroll 2
        for (int it = 0; it < 4; ++it) {
            int k  = tt + 1 + (it << 9);   // 1..2048
            int jj = 4096 - k;
            int pA = IDX(drev(k)), pB = IDX(drev(jj));
            float2 uA = lds[pA], vA = lds[pA^1];
            float2 uB = lds[pB], vB = lds[pB^1];
            float2 Vk = cadd(uA, vA), Vk4 = csub(uA, vA);   // bins k, k+4096
            float2 Vj = cadd(uB, vB), Vj4 = csub(uB, vB);   // bins jj, 8192-k
            float4 kvk = kf4[k], kvj = kf4[jj];
            float2 W  = tw16[k];
            float2 Wj = make_float2(-W.y, -W.x);
            float2 r1, r2, r1j, r2j;
            specpair(Vk, Vj4, kvk, W,  r1,  r2);   // v'[k],  v'[8192-k]
            specpair(Vj, Vk4, kvj, Wj, r1j, r2j);  // v'[jj], v'[4096+k]
            lds[pA]   = cadd(r1, r2j);  lds[pA^1] = csub(r1, r2j);
            lds[pB]   = cadd(r1j, r2);  lds[pB^1] = csub(r1j, r2);
        }
        if (tt == 0) {
            float2 u = lds[0], v = lds[1];
            float2 V0 = cadd(u, v), VN = csub(u, v);        // bins 0, 4096
            float4 kv = kf4[0];
            float U0 = V0.x + V0.y, UL = V0.x - V0.y;
            float re = U0*kv.x + UL*kv.y;
            float im = U0*kv.x - UL*kv.y;
            float2 s0 = make_float2(im, re);
            float2 P = make_float2(VN.x*kv.z + VN.y*kv.w, VN.x*kv.w - VN.y*kv.z);
            float2 s1 = make_float2(-P.y, P.x);
            lds[0] = cadd(s0, s1);
            lds[1] = csub(s0, s1);
        }
        __syncthreads();

        r16p<2,true,false>(lds, twT, tt); wave_sync();
        r16p<1,true,false>(lds, twT, tt); __syncthreads();
        r16p<0,true,false>(lds, twT, tt); __syncthreads();

        float4* orow4 = (float4*)(obase + (size_t)rr * rowstride);
#pragma unroll
        for (int j = 0; j < 4; ++j) {
            int a0 = (EB ^ (j<<2)) + (j<<10);
            float2 wA = lds[a0], wB = lds[a0^1];
            float4 xv = xs[j];
            orow4[tt + (j<<9)] = make_float4(wA.y + xv.x*bc, wA.x + xv.y*bc,
                                             wB.y + xv.z*bc, wB.x + xv.w*bc);
        }
        if (rr < 3) __syncthreads();   // protect lds before next row's staging
    }
}

extern "C" void kernel_launch(void* const* d_in, const int* in_sizes, int n_in,
                              void* d_out, int out_size, void* d_ws, size_t ws_size,
                              hipStream_t stream) {
    const float* x      = (const float*)d_in[0];
    const float* z      = (const float*)d_in[2];
    const float* t      = (const float*)d_in[3];
    const float* deltas = (const float*)d_in[4];
    const float* freq   = (const float*)d_in[5];
    const float* W0     = (const float*)d_in[6];
    const float* b0     = (const float*)d_in[7];
    const float* W1     = (const float*)d_in[8];
    const float* b1     = (const float*)d_in[9];
    const float* W2     = (const float*)d_in[10];
    const float* b2     = (const float*)d_in[11];
    const float* W3     = (const float*)d_in[12];
    const float* b3     = (const float*)d_in[13];
    const float* bias   = (const float*)d_in[14];
    float* out = (float*)d_out;
    float* ws  = (float*)d_ws;
    float* H   = ws + OFF_H;
    float* Kf  = ws + OFF_KF;

    hipLaunchKernelGGL(k_pre, dim3(17), dim3(512), 0, stream, z, freq, W0, b0, W1, b1, W2, b2, ws, H);
    hipLaunchKernelGGL(k_filter, dim3(NCH/2), dim3(BT), 0, stream, H, t, deltas, W3, b3, ws, Kf);
    hipLaunchKernelGGL(k_main, dim3(NCH), dim3(BT), 0, stream, x, ws, Kf, bias, out);
}

// Round 6
// 926.789 us; speedup vs baseline: 1.1119x; 1.0955x over previous
//
#include <hip/hip_runtime.h>
#include <math.h>

// HyenaFilter: y = irfft(rfft(x,2L) * rfft(k,2L))[..., :L] + x*bias
// Register-blocked mixed-radix [16,16,16,2] FFT. Round-6 revision:
//  - R4/R5 structure (1024-thread blocks, two independent rows, 136.7 KB LDS,
//    16 waves/CU in one workgroup) with the register budget forced via direct
//    backend attributes: amdgpu_flat_work_group_size(1024,1024) +
//    amdgpu_waves_per_eu(4,4). __launch_bounds__(BT,1) was ignored (VGPR stayed
//    64, ~1.9 GB scratch spill); the max=4 here removes the allocator's
//    8-waves/EU occupancy target (unreachable anyway: LDS pins 1 block/CU)
//    and min=4 sets the budget to 512/4 = 128 VGPR, which this code fits (~124).
//  - everything else identical to R5: LDS twiddle tables, folded XOR-swizzle,
//    wave-local B<->C sync, fused r2+spectral quad, pruned first fwd pass.

#define LSEQ 8192
#define NCH 768
#define NBATCH 8
#define NT 512            // threads per half (per row)
#define BT 1024           // threads per block

// ws layout (float offsets)
#define OFF_TWB  0        // 32 rows x 16 float2 : W16384^{32*q*m}   (pass B; pass-A high = rows 2b)
#define OFF_TW16 1024     // 2049 float2         : W16384^k, k<=2048
#define OFF_TL   5124     // 32 rows x 16 float2 : W16384^{2*a*m}    (pass A low)
#define OFF_TWC  6660     // 2 rows x 16 float2  : W16384^{512*p*m}  (pass C)
#define OFF_H    10240    // 8192 x 16 floats (MLP features, row-major)
#define OFF_KF   141312   // 768 x 4096 float4 (S~, D~ per bin pair)

__device__ __forceinline__ float2 cadd(float2 a, float2 b){ return make_float2(a.x+b.x, a.y+b.y); }
__device__ __forceinline__ float2 csub(float2 a, float2 b){ return make_float2(a.x-b.x, a.y-b.y); }
__device__ __forceinline__ float2 cmul(float2 a, float2 b){ return make_float2(a.x*b.x - a.y*b.y, a.x*b.y + a.y*b.x); }
__device__ __forceinline__ float2 mni(float2 a){ return make_float2(a.y, -a.x); }  // * -i

// wave-local LDS producer->consumer sync (exchange confined to one wave)
__device__ __forceinline__ void wave_sync(){
    asm volatile("s_waitcnt lgkmcnt(0)" ::: "memory");
}

// generic swizzle (used only in the spectral stage)
__device__ __forceinline__ int IDX(int i){ return i ^ (((i>>4) ^ (i>>8)) & 15); }
// digit-reversal: bin k -> slot after DIF passes [16(512),16(32),16(2)] (pre-r2, slot even)
__device__ __forceinline__ int drev(int k){
    return ((k & 15) << 9) | (((k >> 4) & 15) << 5) | (((k >> 8) & 15) << 1) | (k >> 12);
}

#define C1 0.923879532511286756f
#define S1 0.382683432365089772f
#define R2 0.707106781186547524f

// natural-in DFT-16; output bin m in q[rv[m]]. FULL=false: inputs 8..15 are
// pre-duplicated copies of 0..7 (zero upper half), stage-1 add/sub skipped.
template<bool FULL>
__device__ __forceinline__ void dft16(float2 q[16]) {
    if constexpr (FULL) {
#pragma unroll
        for (int j = 0; j < 8; ++j) { float2 u=q[j], v=q[j+8]; q[j]=cadd(u,v); q[j+8]=csub(u,v); }
    }
    q[9]  = cmul(q[9],  make_float2( C1,-S1));
    q[10] = cmul(q[10], make_float2( R2,-R2));
    q[11] = cmul(q[11], make_float2( S1,-C1));
    q[12] = mni(q[12]);
    q[13] = cmul(q[13], make_float2(-S1,-C1));
    q[14] = cmul(q[14], make_float2(-R2,-R2));
    q[15] = cmul(q[15], make_float2(-C1,-S1));
#pragma unroll
    for (int b = 0; b < 16; b += 8) {
#pragma unroll
        for (int j = 0; j < 4; ++j) { float2 u=q[b+j], v=q[b+j+4]; q[b+j]=cadd(u,v); q[b+j+4]=csub(u,v); }
        q[b+5] = cmul(q[b+5], make_float2( R2,-R2));
        q[b+6] = mni(q[b+6]);
        q[b+7] = cmul(q[b+7], make_float2(-R2,-R2));
    }
#pragma unroll
    for (int b = 0; b < 16; b += 4) {
        float2 u0=q[b], v0=q[b+2], u1=q[b+1], v1=q[b+3];
        q[b]=cadd(u0,v0); q[b+2]=csub(u0,v0);
        q[b+1]=cadd(u1,v1); q[b+3]=mni(csub(u1,v1));
    }
#pragma unroll
    for (int b = 0; b < 16; b += 2) { float2 u=q[b], v=q[b+1]; q[b]=cadd(u,v); q[b+1]=csub(u,v); }
}

// Hand-folded swizzled addressing: IDX(base+p+r*L) == (sb ^ C_r) + (r*L).
template<int PASS>
__device__ __forceinline__ int psb(int t) {
    if constexpr (PASS == 0) {               // L=512, p=t
        return t ^ (((t>>4) ^ (t>>8)) & 15);
    } else if constexpr (PASS == 1) {        // L=32, base=(t>>5)<<9, p=t&31
        int p = t & 31, hb = t >> 5;
        return ((hb<<9) | p) ^ (((p>>4) ^ (hb<<1)) & 15);
    } else {                                 // L=2, base=(t>>1)<<5, p=t&1
        int h = t >> 1;
        return ((h<<5) | (t&1)) ^ (((h<<1) ^ (h>>3)) & 15);
    }
}
template<int PASS>
__device__ __forceinline__ int paddr(int sb, int r) {
    if constexpr (PASS == 0)      return (sb ^ (2*(r&7))) + (r<<9);
    else if constexpr (PASS == 1) return (sb ^ ((2*(r&7)) ^ (r>>3))) + (r<<5);
    else                          return sb ^ ((r<<1) ^ (r>>3));
}

// One radix-16 pass, twiddles from LDS table twT[m][row]:
//   row<32: TWB[q][m]=W16384^{32qm}; row=32+a: TL[a][m]=W16384^{2am}; row=64+c: TWC[c][m].
// Pass A twiddle W8192^{pm} = TL[p&31][m] * TWB[2*(p>>5)][m].
template<int PASS, bool DIT, bool PRUNED>
__device__ __forceinline__ void r16p(float2* lds, const float2 (*twT)[68], int t) {
    static constexpr int RV[16] = {0,8,4,12,2,10,6,14,1,9,5,13,3,11,7,15};
    const int sb = psb<PASS>(t);
    int rL, rH = 0;
    if constexpr (PASS == 0) { rL = 32 + (t & 31); rH = (t >> 5) << 1; }
    else if constexpr (PASS == 1) { rL = t & 31; }
    else { rL = 64 + (t & 1); }
    float2 q[16];
    if constexpr (PRUNED) {
#pragma unroll
        for (int r = 0; r < 8; ++r) { q[r] = lds[paddr<PASS>(sb, r)]; q[r+8] = q[r]; }
    } else {
#pragma unroll
        for (int r = 0; r < 16; ++r) q[r] = lds[paddr<PASS>(sb, r)];
    }
    if constexpr (DIT) {
#pragma unroll
        for (int m = 1; m < 16; ++m) {
            float2 w = twT[m][rL];
            if constexpr (PASS == 0) w = cmul(w, twT[m][rH]);
            q[m] = cmul(q[m], w);
        }
        dft16<true>(q);
    } else {
        dft16<!PRUNED>(q);
#pragma unroll
        for (int m = 1; m < 16; ++m) {
            float2 w = twT[m][rL];
            if constexpr (PASS == 0) w = cmul(w, twT[m][rH]);
            q[RV[m]] = cmul(q[RV[m]], w);
        }
    }
#pragma unroll
    for (int m = 0; m < 16; ++m) lds[paddr<PASS>(sb, m)] = q[RV[m]];
}

// copy twiddle tables global -> LDS (transposed): 66 rows x 16 elems
__device__ __forceinline__ void load_twT(float2 (*twT)[68], const float* __restrict__ ws, int tid) {
    const float2* gTWB = (const float2*)(ws + OFF_TWB);
    const float2* gTL  = (const float2*)(ws + OFF_TL);
    const float2* gTWC = (const float2*)(ws + OFF_TWC);
    for (int idx = tid; idx < 16*66; idx += BT) {
        int r = idx >> 4, m = idx & 15;
        float2 v;
        if (r < 32)      v = gTWB[(r << 4) + m];
        else if (r < 64) v = gTL[((r - 32) << 4) + m];
        else             v = gTWC[((r - 64) << 4) + m];
        twT[m][r] = v;
    }
}

// spectral multiply for bin pair (k, 8192-k): o1/o2 are swapped v'[k], v'[8192-k]
__device__ __forceinline__ void specpair(float2 V1, float2 V2, float4 kv, float2 W,
                                         float2& o1, float2& o2) {
    float2 Eh = make_float2(V1.x + V2.x, V1.y - V2.y);
    float2 Oh = make_float2(V1.y + V2.y, V2.x - V1.x);
    float2 S = make_float2(kv.x, kv.y);
    float a = W.x*kv.z, b = W.y*kv.w, cc = W.x*kv.w, dd = W.y*kv.z;
    float2 T  = make_float2(a - b, cc + dd);
    float2 T2 = make_float2(a + b, cc - dd);
    float2 Ep = cadd(cmul(Eh, S), cmul(Oh, T));
    float2 Op = cadd(cmul(Eh, T2), cmul(Oh, S));
    o1 = make_float2(Ep.y + Op.x, Ep.x - Op.y);
    o2 = make_float2(Op.x - Ep.y, Ep.x + Op.y);
}

// merged init (block 0: twiddle tables via double-precision factor tables) + MLP (blocks 1..16)
__global__ __launch_bounds__(512) void k_pre(const float* __restrict__ z, const float* __restrict__ freq,
        const float* __restrict__ W0, const float* __restrict__ b0,
        const float* __restrict__ W1, const float* __restrict__ b1,
        const float* __restrict__ W2, const float* __restrict__ b2,
        float* __restrict__ ws, float* __restrict__ H) {
    __shared__ double2 lA[128], lB[128];
    const int t = threadIdx.x;
    if (blockIdx.x == 0) {
        const double K = -2.0 * 3.14159265358979323846 / 16384.0;
        if (t < 128)      { double a = K * (double)(t << 7); lA[t] = make_double2(cos(a), sin(a)); }
        else if (t < 256) { int b = t - 128; double a = K * (double)b; lB[b] = make_double2(cos(a), sin(a)); }
        __syncthreads();
        auto wf = [&](int e) -> float2 {
            e &= 16383;
            double2 A = lA[e >> 7], B = lB[e & 127];
            return make_float2((float)(A.x*B.x - A.y*B.y), (float)(A.x*B.y + A.y*B.x));
        };
        float2* tw16 = (float2*)(ws + OFF_TW16);
        for (int k = t; k <= 2048; k += 512) tw16[k] = wf(k);
        if (t < 32) {
            float2* rowL = (float2*)(ws + OFF_TL)  + (t << 4);
            float2* rowB = (float2*)(ws + OFF_TWB) + (t << 4);
#pragma unroll
            for (int m = 0; m < 16; ++m) { rowL[m] = wf(2*t*m); rowB[m] = wf(32*t*m); }
        } else if (t < 34) {
            int c2 = t - 32;
            float2* rowC = (float2*)(ws + OFF_TWC) + (c2 << 4);
#pragma unroll
            for (int m = 0; m < 16; ++m) rowC[m] = wf(512*c2*m);
        }
    } else {
        const int j = ((blockIdx.x - 1) << 9) + t;
        const float z0 = z[j*3+0], z1 = z[j*3+1], z2 = z[j*3+2];
        float h[16], g[16];
#pragma unroll
        for (int m = 0; m < 16; ++m)
            h[m] = sinf(freq[m] * (z0*W0[m] + z1*W0[16+m] + z2*W0[32+m] + b0[m]));
#pragma unroll
        for (int m = 0; m < 16; ++m) {
            float a = b1[m];
#pragma unroll
            for (int p = 0; p < 16; ++p) a += h[p] * W1[p*16+m];
            g[m] = sinf(freq[m] * a);
        }
#pragma unroll
        for (int m = 0; m < 16; ++m) {
            float a = b2[m];
#pragma unroll
            for (int p = 0; p < 16; ++p) a += g[p] * W2[p*16+m];
            h[m] = sinf(freq[m] * a);
        }
        float4* hp = (float4*)(H + (j << 4));   // row-major [8192][16]
        hp[0] = make_float4(h[0],  h[1],  h[2],  h[3]);
        hp[1] = make_float4(h[4],  h[5],  h[6],  h[7]);
        hp[2] = make_float4(h[8],  h[9],  h[10], h[11]);
        hp[3] = make_float4(h[12], h[13], h[14], h[15]);
    }
}

// Two channels per block (one per 512-thread half): filter -> pruned fwd FFT
// -> fused(r2+unpack) -> store (S~,D~)
__global__ __attribute__((amdgpu_flat_work_group_size(BT, BT), amdgpu_waves_per_eu(4, 4)))
void k_filter(const float* __restrict__ H, const float* __restrict__ t,
        const float* __restrict__ deltas, const float* __restrict__ W3,
        const float* __restrict__ b3, const float* __restrict__ ws,
        float* __restrict__ KfF) {
    __shared__ float2 lds2[2][LSEQ];
    __shared__ float2 twT[16][68];
    const int tid = threadIdx.x;
    const int half = tid >> 9, tt = tid & (NT-1);
    const int c = (blockIdx.x << 1) + half;
    float2* lds = lds2[half];
    load_twT(twT, ws, tid);
    float4 w3a = make_float4(W3[0*NCH+c],  W3[1*NCH+c],  W3[2*NCH+c],  W3[3*NCH+c]);
    float4 w3b = make_float4(W3[4*NCH+c],  W3[5*NCH+c],  W3[6*NCH+c],  W3[7*NCH+c]);
    float4 w3c = make_float4(W3[8*NCH+c],  W3[9*NCH+c],  W3[10*NCH+c], W3[11*NCH+c]);
    float4 w3d = make_float4(W3[12*NCH+c], W3[13*NCH+c], W3[14*NCH+c], W3[15*NCH+c]);
    const float b3c = b3[c];
    const float ad = fabsf(deltas[c]);
    const int sbA = psb<0>(tt);
#pragma unroll 2
    for (int j = 0; j < 8; ++j) {
        int n = tt + (j << 9);
        const float4* hp = (const float4*)(H + (n << 5));
        float4 p0 = hp[0], p1 = hp[1], p2 = hp[2], p3 = hp[3];
        float4 q0 = hp[4], q1 = hp[5], q2 = hp[6], q3 = hp[7];
        float s0 = b3c + p0.x*w3a.x + p0.y*w3a.y + p0.z*w3a.z + p0.w*w3a.w
                       + p1.x*w3b.x + p1.y*w3b.y + p1.z*w3b.z + p1.w*w3b.w
                       + p2.x*w3c.x + p2.y*w3c.y + p2.z*w3c.z + p2.w*w3c.w
                       + p3.x*w3d.x + p3.y*w3d.y + p3.z*w3d.z + p3.w*w3d.w;
        float s1 = b3c + q0.x*w3a.x + q0.y*w3a.y + q0.z*w3a.z + q0.w*w3a.w
                       + q1.x*w3b.x + q1.y*w3b.y + q1.z*w3b.z + q1.w*w3b.w
                       + q2.x*w3c.x + q2.y*w3c.y + q2.z*w3c.z + q2.w*w3c.w
                       + q3.x*w3d.x + q3.y*w3d.y + q3.z*w3d.z + q3.w*w3d.w;
        float2 tv = ((const float2*)t)[n];
        lds[(sbA ^ (2*j)) + (j<<9)] = make_float2(s0 * expf(-tv.x*ad), s1 * expf(-tv.y*ad));
    }
    __syncthreads();
    r16p<0,false,true >(lds, twT, tt); __syncthreads();
    r16p<1,false,false>(lds, twT, tt); wave_sync();
    r16p<2,false,false>(lds, twT, tt); __syncthreads();

    float4* kf4 = (float4*)KfF + (size_t)c * 4096;
    const float2* tw16 = (const float2*)(ws + OFF_TW16);
    const float sc = 1.0f / 32768.0f;
#pragma unroll 2
    for (int it = 0; it < 4; ++it) {
        int k  = tt + 1 + (it << 9);   // 1..2048
        int jj = 4096 - k;             // 2048..4095 (k=2048: idempotent dup)
        int pA = IDX(drev(k)), pB = IDX(drev(jj));
        float2 uA = lds[pA], vA = lds[pA^1];
        float2 uB = lds[pB], vB = lds[pB^1];
        float2 Vk = cadd(uA, vA), Vk4 = csub(uA, vA);   // bins k, k+4096
        float2 Vj = cadd(uB, vB), Vj4 = csub(uB, vB);   // bins jj, jj+4096 (=8192-k)
        float2 W  = tw16[k];
        float2 Wj = make_float2(-W.y, -W.x);            // tw16[4096-k]
        {
            float2 E = make_float2(Vk.x + Vj4.x, Vk.y - Vj4.y);
            float2 O = make_float2(Vk.y + Vj4.y, Vj4.x - Vk.x);
            float2 D = cmul(W, O);
            kf4[k] = make_float4(E.x*sc, E.y*sc, D.x*sc, D.y*sc);
        }
        {
            float2 E = make_float2(Vj.x + Vk4.x, Vj.y - Vk4.y);
            float2 O = make_float2(Vj.y + Vk4.y, Vk4.x - Vj.x);
            float2 D = cmul(Wj, O);
            kf4[jj] = make_float4(E.x*sc, E.y*sc, D.x*sc, D.y*sc);
        }
    }
    if (tt == 0) {
        float2 u = lds[0], v = lds[1];          // IDX(0)=0, IDX(1)=1
        float2 V0 = cadd(u, v), VN = csub(u, v);
        kf4[0] = make_float4((V0.x + V0.y)/16384.f, (V0.x - V0.y)/16384.f,
                             VN.x/8192.f, -VN.y/8192.f);
    }
}

// Block = channel c; half h = batches 4h..4h+3 (4 rows sequential, prefetched).
// Both halves share kf4[c]/tw16 (L1-hot). pack x -> pruned fwd FFT ->
// fused(r2+spectral+inv-r2) -> DIT net -> out.
__global__ __attribute__((amdgpu_flat_work_group_size(BT, BT), amdgpu_waves_per_eu(4, 4)))
void k_main(const float* __restrict__ x, const float* __restrict__ ws,
        const float* __restrict__ KfF, const float* __restrict__ bias,
        float* __restrict__ out) {
    __shared__ float2 lds2[2][LSEQ];
    __shared__ float2 twT[16][68];
    const int c = blockIdx.x;                   // 0..767
    const int tid = threadIdx.x;
    const int half = tid >> 9, tt = tid & (NT-1);
    float2* lds = lds2[half];
    const float4* kf4 = (const float4*)KfF + (size_t)c * 4096;
    const float2* tw16 = (const float2*)(ws + OFF_TW16);
    const size_t rowstride = (size_t)NCH * LSEQ;
    const float* xbase = x + (size_t)(half*4) * rowstride + (size_t)c * LSEQ;
    float* obase = out + (size_t)(half*4) * rowstride + (size_t)c * LSEQ;
    const float bc = bias[c];

    // staging addresses: IDX(2i) = (EB ^ (j<<2)) + (j<<10), IDX(2i+1) = that ^ 1
    const int EB = (tt << 1) ^ (((tt>>3) ^ (tt>>7)) & 15);

    float4 pf[4];
#pragma unroll
    for (int j = 0; j < 4; ++j) pf[j] = ((const float4*)xbase)[tt + (j<<9)];
    load_twT(twT, ws, tid);

    for (int rr = 0; rr < 4; ++rr) {
        float4 xs[4];
#pragma unroll
        for (int j = 0; j < 4; ++j) {
            xs[j] = pf[j];
            int a0 = (EB ^ (j<<2)) + (j<<10);
            lds[a0]   = make_float2(xs[j].x, xs[j].y);
            lds[a0^1] = make_float2(xs[j].z, xs[j].w);
        }
        if (rr < 3) {   // prefetch next row's x; hidden under this row's FFT
            const float4* xn = (const float4*)(xbase + (size_t)(rr+1) * rowstride);
#pragma unroll
            for (int j = 0; j < 4; ++j) pf[j] = xn[tt + (j<<9)];
        }
        __syncthreads();                              // also covers twT copy (rr==0)
        r16p<0,false,true >(lds, twT, tt); __syncthreads();
        r16p<1,false,false>(lds, twT, tt); wave_sync();
        r16p<2,false,false>(lds, twT, tt); __syncthreads();

        // fused fwd-r2 + spectral multiply + inverse-r2, per closed quad of bins
#pragma unroll 2
        for (int it = 0; it < 4; ++it) {
            int k  = tt + 1 + (it << 9);   // 1..2048
            int jj = 4096 - k;
            int pA = IDX(drev(k)), pB = IDX(drev(jj));
            float2 uA = lds[pA], vA = lds[pA^1];
            float2 uB = lds[pB], vB = lds[pB^1];
            float2 Vk = cadd(uA, vA), Vk4 = csub(uA, vA);   // bins k, k+4096
            float2 Vj = cadd(uB, vB), Vj4 = csub(uB, vB);   // bins jj, 8192-k
            float4 kvk = kf4[k], kvj = kf4[jj];
            float2 W  = tw16[k];
            float2 Wj = make_float2(-W.y, -W.x);
            float2 r1, r2, r1j, r2j;
            specpair(Vk, Vj4, kvk, W,  r1,  r2);   // v'[k],  v'[8192-k]
            specpair(Vj, Vk4, kvj, Wj, r1j, r2j);  // v'[jj], v'[4096+k]
            lds[pA]   = cadd(r1, r2j);  lds[pA^1] = csub(r1, r2j);
            lds[pB]   = cadd(r1j, r2);  lds[pB^1] = csub(r1j, r2);
        }
        if (tt == 0) {
            float2 u = lds[0], v = lds[1];
            float2 V0 = cadd(u, v), VN = csub(u, v);        // bins 0, 4096
            float4 kv = kf4[0];
            float U0 = V0.x + V0.y, UL = V0.x - V0.y;
            float re = U0*kv.x + UL*kv.y;
            float im = U0*kv.x - UL*kv.y;
            float2 s0 = make_float2(im, re);
            float2 P = make_float2(VN.x*kv.z + VN.y*kv.w, VN.x*kv.w - VN.y*kv.z);
            float2 s1 = make_float2(-P.y, P.x);
            lds[0] = cadd(s0, s1);
            lds[1] = csub(s0, s1);
        }
        __syncthreads();

        r16p<2,true,false>(lds, twT, tt); wave_sync();
        r16p<1,true,false>(lds, twT, tt); __syncthreads();
        r16p<0,true,false>(lds, twT, tt); __syncthreads();

        float4* orow4 = (float4*)(obase + (size_t)rr * rowstride);
#pragma unroll
        for (int j = 0; j < 4; ++j) {
            int a0 = (EB ^ (j<<2)) + (j<<10);
            float2 wA = lds[a0], wB = lds[a0^1];
            float4 xv = xs[j];
            orow4[tt + (j<<9)] = make_float4(wA.y + xv.x*bc, wA.x + xv.y*bc,
                                             wB.y + xv.z*bc, wB.x + xv.w*bc);
        }
        if (rr < 3) __syncthreads();   // protect lds before next row's staging
    }
}

extern "C" void kernel_launch(void* const* d_in, const int* in_sizes, int n_in,
                              void* d_out, int out_size, void* d_ws, size_t ws_size,
                              hipStream_t stream) {
    const float* x      = (const float*)d_in[0];
    const float* z      = (const float*)d_in[2];
    const float* t      = (const float*)d_in[3];
    const float* deltas = (const float*)d_in[4];
    const float* freq   = (const float*)d_in[5];
    const float* W0     = (const float*)d_in[6];
    const float* b0     = (const float*)d_in[7];
    const float* W1     = (const float*)d_in[8];
    const float* b1     = (const float*)d_in[9];
    const float* W2     = (const float*)d_in[10];
    const float* b2     = (const float*)d_in[11];
    const float* W3     = (const float*)d_in[12];
    const float* b3     = (const float*)d_in[13];
    const float* bias   = (const float*)d_in[14];
    float* out = (float*)d_out;
    float* ws  = (float*)d_ws;
    float* H   = ws + OFF_H;
    float* Kf  = ws + OFF_KF;

    hipLaunchKernelGGL(k_pre, dim3(17), dim3(512), 0, stream, z, freq, W0, b0, W1, b1, W2, b2, ws, H);
    hipLaunchKernelGGL(k_filter, dim3(NCH/2), dim3(BT), 0, stream, H, t, deltas, W3, b3, ws, Kf);
    hipLaunchKernelGGL(k_main, dim3(NCH), dim3(BT), 0, stream, x, ws, Kf, bias, out);
}

// Round 7
// 844.793 us; speedup vs baseline: 1.2199x; 1.0971x over previous
//
#include <hip/hip_runtime.h>
#include <math.h>

// HyenaFilter: y = irfft(rfft(x,2L) * rfft(k,2L))[..., :L] + x*bias
// Register-blocked mixed-radix [16,16,16,2] FFT. Round-7 revision:
//  - Accept the toolchain's hard 64-VGPR cap for 1024-thread blocks (3 knobs
//    failed: launch_bounds(NT,4)/(BT,1), amdgpu_waves_per_eu(4,4)); instead
//    make k_main FIT in 64 VGPRs: drop persistent xs[]/pf[] (re-read x from
//    global at the output step), spectral unroll 2->1, no row-loop unroll.
//    Peak live set ~50 VGPR -> no spill at 16 waves/CU.
//  - k_filter reverted to the known-good 512-thread R3 form (88 VGPR, no
//    spill); it gains nothing from 1024 threads.
//  - keeps: 2-row 1024t k_main (136.7 KB LDS, 16 waves/CU structural), LDS
//    twiddle tables, folded XOR-swizzle, wave-local B<->C sync, fused
//    r2+spectral quad, pruned first fwd pass, merged k_pre.

#define LSEQ 8192
#define NCH 768
#define NBATCH 8
#define NT 512            // threads per half (per row)
#define BT 1024           // threads per block (k_main)

// ws layout (float offsets)
#define OFF_TWB  0        // 32 rows x 16 float2 : W16384^{32*q*m}   (pass B; pass-A high = rows 2b)
#define OFF_TW16 1024     // 2049 float2         : W16384^k, k<=2048
#define OFF_TL   5124     // 32 rows x 16 float2 : W16384^{2*a*m}    (pass A low)
#define OFF_TWC  6660     // 2 rows x 16 float2  : W16384^{512*p*m}  (pass C)
#define OFF_H    10240    // 8192 x 16 floats (MLP features, row-major)
#define OFF_KF   141312   // 768 x 4096 float4 (S~, D~ per bin pair)

__device__ __forceinline__ float2 cadd(float2 a, float2 b){ return make_float2(a.x+b.x, a.y+b.y); }
__device__ __forceinline__ float2 csub(float2 a, float2 b){ return make_float2(a.x-b.x, a.y-b.y); }
__device__ __forceinline__ float2 cmul(float2 a, float2 b){ return make_float2(a.x*b.x - a.y*b.y, a.x*b.y + a.y*b.x); }
__device__ __forceinline__ float2 mni(float2 a){ return make_float2(a.y, -a.x); }  // * -i

// wave-local LDS producer->consumer sync (exchange confined to one wave)
__device__ __forceinline__ void wave_sync(){
    asm volatile("s_waitcnt lgkmcnt(0)" ::: "memory");
}

// generic swizzle (used only in the spectral stage)
__device__ __forceinline__ int IDX(int i){ return i ^ (((i>>4) ^ (i>>8)) & 15); }
// digit-reversal: bin k -> slot after DIF passes [16(512),16(32),16(2)] (pre-r2, slot even)
__device__ __forceinline__ int drev(int k){
    return ((k & 15) << 9) | (((k >> 4) & 15) << 5) | (((k >> 8) & 15) << 1) | (k >> 12);
}

#define C1 0.923879532511286756f
#define S1 0.382683432365089772f
#define R2 0.707106781186547524f

// natural-in DFT-16; output bin m in q[rv[m]]. FULL=false: inputs 8..15 are
// pre-duplicated copies of 0..7 (zero upper half), stage-1 add/sub skipped.
template<bool FULL>
__device__ __forceinline__ void dft16(float2 q[16]) {
    if constexpr (FULL) {
#pragma unroll
        for (int j = 0; j < 8; ++j) { float2 u=q[j], v=q[j+8]; q[j]=cadd(u,v); q[j+8]=csub(u,v); }
    }
    q[9]  = cmul(q[9],  make_float2( C1,-S1));
    q[10] = cmul(q[10], make_float2( R2,-R2));
    q[11] = cmul(q[11], make_float2( S1,-C1));
    q[12] = mni(q[12]);
    q[13] = cmul(q[13], make_float2(-S1,-C1));
    q[14] = cmul(q[14], make_float2(-R2,-R2));
    q[15] = cmul(q[15], make_float2(-C1,-S1));
#pragma unroll
    for (int b = 0; b < 16; b += 8) {
#pragma unroll
        for (int j = 0; j < 4; ++j) { float2 u=q[b+j], v=q[b+j+4]; q[b+j]=cadd(u,v); q[b+j+4]=csub(u,v); }
        q[b+5] = cmul(q[b+5], make_float2( R2,-R2));
        q[b+6] = mni(q[b+6]);
        q[b+7] = cmul(q[b+7], make_float2(-R2,-R2));
    }
#pragma unroll
    for (int b = 0; b < 16; b += 4) {
        float2 u0=q[b], v0=q[b+2], u1=q[b+1], v1=q[b+3];
        q[b]=cadd(u0,v0); q[b+2]=csub(u0,v0);
        q[b+1]=cadd(u1,v1); q[b+3]=mni(csub(u1,v1));
    }
#pragma unroll
    for (int b = 0; b < 16; b += 2) { float2 u=q[b], v=q[b+1]; q[b]=cadd(u,v); q[b+1]=csub(u,v); }
}

// Hand-folded swizzled addressing: IDX(base+p+r*L) == (sb ^ C_r) + (r*L).
template<int PASS>
__device__ __forceinline__ int psb(int t) {
    if constexpr (PASS == 0) {               // L=512, p=t
        return t ^ (((t>>4) ^ (t>>8)) & 15);
    } else if constexpr (PASS == 1) {        // L=32, base=(t>>5)<<9, p=t&31
        int p = t & 31, hb = t >> 5;
        return ((hb<<9) | p) ^ (((p>>4) ^ (hb<<1)) & 15);
    } else {                                 // L=2, base=(t>>1)<<5, p=t&1
        int h = t >> 1;
        return ((h<<5) | (t&1)) ^ (((h<<1) ^ (h>>3)) & 15);
    }
}
template<int PASS>
__device__ __forceinline__ int paddr(int sb, int r) {
    if constexpr (PASS == 0)      return (sb ^ (2*(r&7))) + (r<<9);
    else if constexpr (PASS == 1) return (sb ^ ((2*(r&7)) ^ (r>>3))) + (r<<5);
    else                          return sb ^ ((r<<1) ^ (r>>3));
}

// One radix-16 pass, twiddles from LDS table twT[m][row]:
//   row<32: TWB[q][m]=W16384^{32qm}; row=32+a: TL[a][m]=W16384^{2am}; row=64+c: TWC[c][m].
// Pass A twiddle W8192^{pm} = TL[p&31][m] * TWB[2*(p>>5)][m].
template<int PASS, bool DIT, bool PRUNED>
__device__ __forceinline__ void r16p(float2* lds, const float2 (*twT)[68], int t) {
    static constexpr int RV[16] = {0,8,4,12,2,10,6,14,1,9,5,13,3,11,7,15};
    const int sb = psb<PASS>(t);
    int rL, rH = 0;
    if constexpr (PASS == 0) { rL = 32 + (t & 31); rH = (t >> 5) << 1; }
    else if constexpr (PASS == 1) { rL = t & 31; }
    else { rL = 64 + (t & 1); }
    float2 q[16];
    if constexpr (PRUNED) {
#pragma unroll
        for (int r = 0; r < 8; ++r) { q[r] = lds[paddr<PASS>(sb, r)]; q[r+8] = q[r]; }
    } else {
#pragma unroll
        for (int r = 0; r < 16; ++r) q[r] = lds[paddr<PASS>(sb, r)];
    }
    if constexpr (DIT) {
#pragma unroll
        for (int m = 1; m < 16; ++m) {
            float2 w = twT[m][rL];
            if constexpr (PASS == 0) w = cmul(w, twT[m][rH]);
            q[m] = cmul(q[m], w);
        }
        dft16<true>(q);
    } else {
        dft16<!PRUNED>(q);
#pragma unroll
        for (int m = 1; m < 16; ++m) {
            float2 w = twT[m][rL];
            if constexpr (PASS == 0) w = cmul(w, twT[m][rH]);
            q[RV[m]] = cmul(q[RV[m]], w);
        }
    }
#pragma unroll
    for (int m = 0; m < 16; ++m) lds[paddr<PASS>(sb, m)] = q[RV[m]];
}

// copy twiddle tables global -> LDS (transposed): 66 rows x 16 elems
__device__ __forceinline__ void load_twT(float2 (*twT)[68], const float* __restrict__ ws,
                                         int tid, int step) {
    const float2* gTWB = (const float2*)(ws + OFF_TWB);
    const float2* gTL  = (const float2*)(ws + OFF_TL);
    const float2* gTWC = (const float2*)(ws + OFF_TWC);
    for (int idx = tid; idx < 16*66; idx += step) {
        int r = idx >> 4, m = idx & 15;
        float2 v;
        if (r < 32)      v = gTWB[(r << 4) + m];
        else if (r < 64) v = gTL[((r - 32) << 4) + m];
        else             v = gTWC[((r - 64) << 4) + m];
        twT[m][r] = v;
    }
}

// spectral multiply for bin pair (k, 8192-k): o1/o2 are swapped v'[k], v'[8192-k]
__device__ __forceinline__ void specpair(float2 V1, float2 V2, float4 kv, float2 W,
                                         float2& o1, float2& o2) {
    float2 Eh = make_float2(V1.x + V2.x, V1.y - V2.y);
    float2 Oh = make_float2(V1.y + V2.y, V2.x - V1.x);
    float2 S = make_float2(kv.x, kv.y);
    float a = W.x*kv.z, b = W.y*kv.w, cc = W.x*kv.w, dd = W.y*kv.z;
    float2 T  = make_float2(a - b, cc + dd);
    float2 T2 = make_float2(a + b, cc - dd);
    float2 Ep = cadd(cmul(Eh, S), cmul(Oh, T));
    float2 Op = cadd(cmul(Eh, T2), cmul(Oh, S));
    o1 = make_float2(Ep.y + Op.x, Ep.x - Op.y);
    o2 = make_float2(Op.x - Ep.y, Ep.x + Op.y);
}

// merged init (block 0: twiddle tables via double-precision factor tables) + MLP (blocks 1..16)
__global__ __launch_bounds__(512) void k_pre(const float* __restrict__ z, const float* __restrict__ freq,
        const float* __restrict__ W0, const float* __restrict__ b0,
        const float* __restrict__ W1, const float* __restrict__ b1,
        const float* __restrict__ W2, const float* __restrict__ b2,
        float* __restrict__ ws, float* __restrict__ H) {
    __shared__ double2 lA[128], lB[128];
    const int t = threadIdx.x;
    if (blockIdx.x == 0) {
        const double K = -2.0 * 3.14159265358979323846 / 16384.0;
        if (t < 128)      { double a = K * (double)(t << 7); lA[t] = make_double2(cos(a), sin(a)); }
        else if (t < 256) { int b = t - 128; double a = K * (double)b; lB[b] = make_double2(cos(a), sin(a)); }
        __syncthreads();
        auto wf = [&](int e) -> float2 {
            e &= 16383;
            double2 A = lA[e >> 7], B = lB[e & 127];
            return make_float2((float)(A.x*B.x - A.y*B.y), (float)(A.x*B.y + A.y*B.x));
        };
        float2* tw16 = (float2*)(ws + OFF_TW16);
        for (int k = t; k <= 2048; k += 512) tw16[k] = wf(k);
        if (t < 32) {
            float2* rowL = (float2*)(ws + OFF_TL)  + (t << 4);
            float2* rowB = (float2*)(ws + OFF_TWB) + (t << 4);
#pragma unroll
            for (int m = 0; m < 16; ++m) { rowL[m] = wf(2*t*m); rowB[m] = wf(32*t*m); }
        } else if (t < 34) {
            int c2 = t - 32;
            float2* rowC = (float2*)(ws + OFF_TWC) + (c2 << 4);
#pragma unroll
            for (int m = 0; m < 16; ++m) rowC[m] = wf(512*c2*m);
        }
    } else {
        const int j = ((blockIdx.x - 1) << 9) + t;
        const float z0 = z[j*3+0], z1 = z[j*3+1], z2 = z[j*3+2];
        float h[16], g[16];
#pragma unroll
        for (int m = 0; m < 16; ++m)
            h[m] = sinf(freq[m] * (z0*W0[m] + z1*W0[16+m] + z2*W0[32+m] + b0[m]));
#pragma unroll
        for (int m = 0; m < 16; ++m) {
            float a = b1[m];
#pragma unroll
            for (int p = 0; p < 16; ++p) a += h[p] * W1[p*16+m];
            g[m] = sinf(freq[m] * a);
        }
#pragma unroll
        for (int m = 0; m < 16; ++m) {
            float a = b2[m];
#pragma unroll
            for (int p = 0; p < 16; ++p) a += g[p] * W2[p*16+m];
            h[m] = sinf(freq[m] * a);
        }
        float4* hp = (float4*)(H + (j << 4));   // row-major [8192][16]
        hp[0] = make_float4(h[0],  h[1],  h[2],  h[3]);
        hp[1] = make_float4(h[4],  h[5],  h[6],  h[7]);
        hp[2] = make_float4(h[8],  h[9],  h[10], h[11]);
        hp[3] = make_float4(h[12], h[13], h[14], h[15]);
    }
}

// Per channel (512 threads, R3 form): filter -> pruned fwd FFT -> fused(r2+unpack)
// -> store (S~,D~)
__global__ __launch_bounds__(NT) void k_filter(const float* __restrict__ H, const float* __restrict__ t,
        const float* __restrict__ deltas, const float* __restrict__ W3,
        const float* __restrict__ b3, const float* __restrict__ ws,
        float* __restrict__ KfF) {
    __shared__ float2 lds[LSEQ];
    __shared__ float2 twT[16][68];
    const int c = blockIdx.x;
    const int tid = threadIdx.x;
    load_twT(twT, ws, tid, NT);
    float4 w3a = make_float4(W3[0*NCH+c],  W3[1*NCH+c],  W3[2*NCH+c],  W3[3*NCH+c]);
    float4 w3b = make_float4(W3[4*NCH+c],  W3[5*NCH+c],  W3[6*NCH+c],  W3[7*NCH+c]);
    float4 w3c = make_float4(W3[8*NCH+c],  W3[9*NCH+c],  W3[10*NCH+c], W3[11*NCH+c]);
    float4 w3d = make_float4(W3[12*NCH+c], W3[13*NCH+c], W3[14*NCH+c], W3[15*NCH+c]);
    const float b3c = b3[c];
    const float ad = fabsf(deltas[c]);
    const int sbA = psb<0>(tid);
#pragma unroll 2
    for (int j = 0; j < 8; ++j) {
        int n = tid + (j << 9);
        const float4* hp = (const float4*)(H + (n << 5));
        float4 p0 = hp[0], p1 = hp[1], p2 = hp[2], p3 = hp[3];
        float4 q0 = hp[4], q1 = hp[5], q2 = hp[6], q3 = hp[7];
        float s0 = b3c + p0.x*w3a.x + p0.y*w3a.y + p0.z*w3a.z + p0.w*w3a.w
                       + p1.x*w3b.x + p1.y*w3b.y + p1.z*w3b.z + p1.w*w3b.w
                       + p2.x*w3c.x + p2.y*w3c.y + p2.z*w3c.z + p2.w*w3c.w
                       + p3.x*w3d.x + p3.y*w3d.y + p3.z*w3d.z + p3.w*w3d.w;
        float s1 = b3c + q0.x*w3a.x + q0.y*w3a.y + q0.z*w3a.z + q0.w*w3a.w
                       + q1.x*w3b.x + q1.y*w3b.y + q1.z*w3b.z + q1.w*w3b.w
                       + q2.x*w3c.x + q2.y*w3c.y + q2.z*w3c.z + q2.w*w3c.w
                       + q3.x*w3d.x + q3.y*w3d.y + q3.z*w3d.z + q3.w*w3d.w;
        float2 tv = ((const float2*)t)[n];
        lds[(sbA ^ (2*j)) + (j<<9)] = make_float2(s0 * expf(-tv.x*ad), s1 * expf(-tv.y*ad));
    }
    __syncthreads();
    r16p<0,false,true >(lds, twT, tid); __syncthreads();
    r16p<1,false,false>(lds, twT, tid); wave_sync();
    r16p<2,false,false>(lds, twT, tid); __syncthreads();

    float4* kf4 = (float4*)KfF + (size_t)c * 4096;
    const float2* tw16 = (const float2*)(ws + OFF_TW16);
    const float sc = 1.0f / 32768.0f;
#pragma unroll 2
    for (int it = 0; it < 4; ++it) {
        int k  = tid + 1 + (it << 9);   // 1..2048
        int jj = 4096 - k;              // 2048..4095 (k=2048: idempotent dup)
        int pA = IDX(drev(k)), pB = IDX(drev(jj));
        float2 uA = lds[pA], vA = lds[pA^1];
        float2 uB = lds[pB], vB = lds[pB^1];
        float2 Vk = cadd(uA, vA), Vk4 = csub(uA, vA);   // bins k, k+4096
        float2 Vj = cadd(uB, vB), Vj4 = csub(uB, vB);   // bins jj, jj+4096 (=8192-k)
        float2 W  = tw16[k];
        float2 Wj = make_float2(-W.y, -W.x);            // tw16[4096-k]
        {
            float2 E = make_float2(Vk.x + Vj4.x, Vk.y - Vj4.y);
            float2 O = make_float2(Vk.y + Vj4.y, Vj4.x - Vk.x);
            float2 D = cmul(W, O);
            kf4[k] = make_float4(E.x*sc, E.y*sc, D.x*sc, D.y*sc);
        }
        {
            float2 E = make_float2(Vj.x + Vk4.x, Vj.y - Vk4.y);
            float2 O = make_float2(Vj.y + Vk4.y, Vk4.x - Vj.x);
            float2 D = cmul(Wj, O);
            kf4[jj] = make_float4(E.x*sc, E.y*sc, D.x*sc, D.y*sc);
        }
    }
    if (tid == 0) {
        float2 u = lds[0], v = lds[1];          // IDX(0)=0, IDX(1)=1
        float2 V0 = cadd(u, v), VN = csub(u, v);
        kf4[0] = make_float4((V0.x + V0.y)/16384.f, (V0.x - V0.y)/16384.f,
                             VN.x/8192.f, -VN.y/8192.f);
    }
}

// Block = channel c; half h = batches 4h..4h+3 (4 rows sequential). 1024 threads,
// 16 waves/CU. Built to fit the 64-VGPR cap: no persistent xs/pf (x re-read from
// global at the output step; sequential + L2-resident), spectral unroll 1.
__global__ __attribute__((amdgpu_flat_work_group_size(BT, BT), amdgpu_waves_per_eu(4, 4)))
void k_main(const float* __restrict__ x, const float* __restrict__ ws,
        const float* __restrict__ KfF, const float* __restrict__ bias,
        float* __restrict__ out) {
    __shared__ float2 lds2[2][LSEQ];
    __shared__ float2 twT[16][68];
    const int c = blockIdx.x;                   // 0..767
    const int tid = threadIdx.x;
    const int half = tid >> 9, tt = tid & (NT-1);
    float2* lds = lds2[half];
    const float4* kf4 = (const float4*)KfF + (size_t)c * 4096;
    const float2* tw16 = (const float2*)(ws + OFF_TW16);
    const size_t rowstride = (size_t)NCH * LSEQ;
    const float* xbase = x + (size_t)(half*4) * rowstride + (size_t)c * LSEQ;
    float* obase = out + (size_t)(half*4) * rowstride + (size_t)c * LSEQ;
    const float bc = bias[c];

    // staging addresses: IDX(2i) = (EB ^ (j<<2)) + (j<<10), IDX(2i+1) = that ^ 1
    const int EB = (tt << 1) ^ (((tt>>3) ^ (tt>>7)) & 15);

    load_twT(twT, ws, tid, BT);

#pragma unroll 1
    for (int rr = 0; rr < 4; ++rr) {
        const float4* xr4 = (const float4*)(xbase + (size_t)rr * rowstride);
#pragma unroll
        for (int j = 0; j < 4; ++j) {
            float4 v = xr4[tt + (j<<9)];
            int a0 = (EB ^ (j<<2)) + (j<<10);
            lds[a0]   = make_float2(v.x, v.y);
            lds[a0^1] = make_float2(v.z, v.w);
        }
        __syncthreads();                              // also covers twT copy (rr==0)
        r16p<0,false,true >(lds, twT, tt); __syncthreads();
        r16p<1,false,false>(lds, twT, tt); wave_sync();
        r16p<2,false,false>(lds, twT, tt); __syncthreads();

        // fused fwd-r2 + spectral multiply + inverse-r2, per closed quad of bins
#pragma unroll 1
        for (int it = 0; it < 4; ++it) {
            int k  = tt + 1 + (it << 9);   // 1..2048
            int jj = 4096 - k;
            int pA = IDX(drev(k)), pB = IDX(drev(jj));
            float2 uA = lds[pA], vA = lds[pA^1];
            float2 uB = lds[pB], vB = lds[pB^1];
            float2 Vk = cadd(uA, vA), Vk4 = csub(uA, vA);   // bins k, k+4096
            float2 Vj = cadd(uB, vB), Vj4 = csub(uB, vB);   // bins jj, 8192-k
            float4 kvk = kf4[k], kvj = kf4[jj];
            float2 W  = tw16[k];
            float2 Wj = make_float2(-W.y, -W.x);
            float2 r1, r2, r1j, r2j;
            specpair(Vk, Vj4, kvk, W,  r1,  r2);   // v'[k],  v'[8192-k]
            specpair(Vj, Vk4, kvj, Wj, r1j, r2j);  // v'[jj], v'[4096+k]
            lds[pA]   = cadd(r1, r2j);  lds[pA^1] = csub(r1, r2j);
            lds[pB]   = cadd(r1j, r2);  lds[pB^1] = csub(r1j, r2);
        }
        if (tt == 0) {
            float2 u = lds[0], v = lds[1];
            float2 V0 = cadd(u, v), VN = csub(u, v);        // bins 0, 4096
            float4 kv = kf4[0];
            float U0 = V0.x + V0.y, UL = V0.x - V0.y;
            float re = U0*kv.x + UL*kv.y;
            float im = U0*kv.x - UL*kv.y;
            float2 s0 = make_float2(im, re);
            float2 P = make_float2(VN.x*kv.z + VN.y*kv.w, VN.x*kv.w - VN.y*kv.z);
            float2 s1 = make_float2(-P.y, P.x);
            lds[0] = cadd(s0, s1);
            lds[1] = csub(s0, s1);
        }
        __syncthreads();

        r16p<2,true,false>(lds, twT, tt); wave_sync();
        r16p<1,true,false>(lds, twT, tt); __syncthreads();
        r16p<0,true,false>(lds, twT, tt); __syncthreads();

        float4* orow4 = (float4*)(obase + (size_t)rr * rowstride);
#pragma unroll
        for (int j = 0; j < 4; ++j) {
            int a0 = (EB ^ (j<<2)) + (j<<10);
            float2 wA = lds[a0], wB = lds[a0^1];
            float4 xv = xr4[tt + (j<<9)];               // re-read (L2-resident)
            orow4[tt + (j<<9)] = make_float4(wA.y + xv.x*bc, wA.x + xv.y*bc,
                                             wB.y + xv.z*bc, wB.x + xv.w*bc);
        }
        if (rr < 3) __syncthreads();   // protect lds before next row's staging
    }
}

extern "C" void kernel_launch(void* const* d_in, const int* in_sizes, int n_in,
                              void* d_out, int out_size, void* d_ws, size_t ws_size,
                              hipStream_t stream) {
    const float* x      = (const float*)d_in[0];
    const float* z      = (const float*)d_in[2];
    const float* t      = (const float*)d_in[3];
    const float* deltas = (const float*)d_in[4];
    const float* freq   = (const float*)d_in[5];
    const float* W0     = (const float*)d_in[6];
    const float* b0     = (const float*)d_in[7];
    const float* W1     = (const float*)d_in[8];
    const float* b1     = (const float*)d_in[9];
    const float* W2     = (const float*)d_in[10];
    const float* b2     = (const float*)d_in[11];
    const float* W3     = (const float*)d_in[12];
    const float* b3     = (const float*)d_in[13];
    const float* bias   = (const float*)d_in[14];
    float* out = (float*)d_out;
    float* ws  = (float*)d_ws;
    float* H   = ws + OFF_H;
    float* Kf  = ws + OFF_KF;

    hipLaunchKernelGGL(k_pre, dim3(17), dim3(512), 0, stream, z, freq, W0, b0, W1, b1, W2, b2, ws, H);
    hipLaunchKernelGGL(k_filter, dim3(NCH), dim3(NT), 0, stream, H, t, deltas, W3, b3, ws, Kf);
    hipLaunchKernelGGL(k_main, dim3(NCH), dim3(BT), 0, stream, x, ws, Kf, bias, out);
}

// Round 8
// 678.525 us; speedup vs baseline: 1.5188x; 1.2450x over previous
//
#include <hip/hip_runtime.h>
#include <math.h>

// HyenaFilter: y = irfft(rfft(x,2L) * rfft(k,2L))[..., :L] + x*bias
// Register-blocked mixed-radix [16,16,16,2] FFT. Round-8 revision:
//  - Abandon 1024-thread blocks (hard 64-VGPR cap on this toolchain, 3 knobs
//    tried; r16 pass needs ~90 regs -> unavoidable spill). Back to 512-thread
//    blocks where the allocator is sane (88-124 observed), and get the SAME
//    16 waves/CU via TWO co-resident blocks: R3 missed it by a few VGPRs
//    (124 -> granule 128; 16 waves x 128 = 2048 = whole pool, no slack).
//    R7's diet (no persistent xs[]/pf[], spectral unroll 1, row unroll 1)
//    drops ~32 persistent regs -> ~92-104 VGPR -> 2 blocks fit with slack.
//  - keeps: LDS twiddle tables (8.7 KB; block total 72.7 KB, x2 = 145 < 160),
//    folded XOR-swizzle, wave-local B<->C sync, fused r2+spectral quad,
//    pruned first fwd pass, x re-read at epilogue (L2-resident), merged k_pre.

#define LSEQ 8192
#define NCH 768
#define NBATCH 8
#define NT 512            // threads per block

// ws layout (float offsets)
#define OFF_TWB  0        // 32 rows x 16 float2 : W16384^{32*q*m}   (pass B; pass-A high = rows 2b)
#define OFF_TW16 1024     // 2049 float2         : W16384^k, k<=2048
#define OFF_TL   5124     // 32 rows x 16 float2 : W16384^{2*a*m}    (pass A low)
#define OFF_TWC  6660     // 2 rows x 16 float2  : W16384^{512*p*m}  (pass C)
#define OFF_H    10240    // 8192 x 16 floats (MLP features, row-major)
#define OFF_KF   141312   // 768 x 4096 float4 (S~, D~ per bin pair)

__device__ __forceinline__ float2 cadd(float2 a, float2 b){ return make_float2(a.x+b.x, a.y+b.y); }
__device__ __forceinline__ float2 csub(float2 a, float2 b){ return make_float2(a.x-b.x, a.y-b.y); }
__device__ __forceinline__ float2 cmul(float2 a, float2 b){ return make_float2(a.x*b.x - a.y*b.y, a.x*b.y + a.y*b.x); }
__device__ __forceinline__ float2 mni(float2 a){ return make_float2(a.y, -a.x); }  // * -i

// wave-local LDS producer->consumer sync (exchange confined to one wave)
__device__ __forceinline__ void wave_sync(){
    asm volatile("s_waitcnt lgkmcnt(0)" ::: "memory");
}

// generic swizzle (used only in the spectral stage)
__device__ __forceinline__ int IDX(int i){ return i ^ (((i>>4) ^ (i>>8)) & 15); }
// digit-reversal: bin k -> slot after DIF passes [16(512),16(32),16(2)] (pre-r2, slot even)
__device__ __forceinline__ int drev(int k){
    return ((k & 15) << 9) | (((k >> 4) & 15) << 5) | (((k >> 8) & 15) << 1) | (k >> 12);
}

#define C1 0.923879532511286756f
#define S1 0.382683432365089772f
#define R2 0.707106781186547524f

// natural-in DFT-16; output bin m in q[rv[m]]. FULL=false: inputs 8..15 are
// pre-duplicated copies of 0..7 (zero upper half), stage-1 add/sub skipped.
template<bool FULL>
__device__ __forceinline__ void dft16(float2 q[16]) {
    if constexpr (FULL) {
#pragma unroll
        for (int j = 0; j < 8; ++j) { float2 u=q[j], v=q[j+8]; q[j]=cadd(u,v); q[j+8]=csub(u,v); }
    }
    q[9]  = cmul(q[9],  make_float2( C1,-S1));
    q[10] = cmul(q[10], make_float2( R2,-R2));
    q[11] = cmul(q[11], make_float2( S1,-C1));
    q[12] = mni(q[12]);
    q[13] = cmul(q[13], make_float2(-S1,-C1));
    q[14] = cmul(q[14], make_float2(-R2,-R2));
    q[15] = cmul(q[15], make_float2(-C1,-S1));
#pragma unroll
    for (int b = 0; b < 16; b += 8) {
#pragma unroll
        for (int j = 0; j < 4; ++j) { float2 u=q[b+j], v=q[b+j+4]; q[b+j]=cadd(u,v); q[b+j+4]=csub(u,v); }
        q[b+5] = cmul(q[b+5], make_float2( R2,-R2));
        q[b+6] = mni(q[b+6]);
        q[b+7] = cmul(q[b+7], make_float2(-R2,-R2));
    }
#pragma unroll
    for (int b = 0; b < 16; b += 4) {
        float2 u0=q[b], v0=q[b+2], u1=q[b+1], v1=q[b+3];
        q[b]=cadd(u0,v0); q[b+2]=csub(u0,v0);
        q[b+1]=cadd(u1,v1); q[b+3]=mni(csub(u1,v1));
    }
#pragma unroll
    for (int b = 0; b < 16; b += 2) { float2 u=q[b], v=q[b+1]; q[b]=cadd(u,v); q[b+1]=csub(u,v); }
}

// Hand-folded swizzled addressing: IDX(base+p+r*L) == (sb ^ C_r) + (r*L).
template<int PASS>
__device__ __forceinline__ int psb(int t) {
    if constexpr (PASS == 0) {               // L=512, p=t
        return t ^ (((t>>4) ^ (t>>8)) & 15);
    } else if constexpr (PASS == 1) {        // L=32, base=(t>>5)<<9, p=t&31
        int p = t & 31, hb = t >> 5;
        return ((hb<<9) | p) ^ (((p>>4) ^ (hb<<1)) & 15);
    } else {                                 // L=2, base=(t>>1)<<5, p=t&1
        int h = t >> 1;
        return ((h<<5) | (t&1)) ^ (((h<<1) ^ (h>>3)) & 15);
    }
}
template<int PASS>
__device__ __forceinline__ int paddr(int sb, int r) {
    if constexpr (PASS == 0)      return (sb ^ (2*(r&7))) + (r<<9);
    else if constexpr (PASS == 1) return (sb ^ ((2*(r&7)) ^ (r>>3))) + (r<<5);
    else                          return sb ^ ((r<<1) ^ (r>>3));
}

// One radix-16 pass, twiddles from LDS table twT[m][row]:
//   row<32: TWB[q][m]=W16384^{32qm}; row=32+a: TL[a][m]=W16384^{2am}; row=64+c: TWC[c][m].
// Pass A twiddle W8192^{pm} = TL[p&31][m] * TWB[2*(p>>5)][m].
template<int PASS, bool DIT, bool PRUNED>
__device__ __forceinline__ void r16p(float2* lds, const float2 (*twT)[68], int t) {
    static constexpr int RV[16] = {0,8,4,12,2,10,6,14,1,9,5,13,3,11,7,15};
    const int sb = psb<PASS>(t);
    int rL, rH = 0;
    if constexpr (PASS == 0) { rL = 32 + (t & 31); rH = (t >> 5) << 1; }
    else if constexpr (PASS == 1) { rL = t & 31; }
    else { rL = 64 + (t & 1); }
    float2 q[16];
    if constexpr (PRUNED) {
#pragma unroll
        for (int r = 0; r < 8; ++r) { q[r] = lds[paddr<PASS>(sb, r)]; q[r+8] = q[r]; }
    } else {
#pragma unroll
        for (int r = 0; r < 16; ++r) q[r] = lds[paddr<PASS>(sb, r)];
    }
    if constexpr (DIT) {
#pragma unroll
        for (int m = 1; m < 16; ++m) {
            float2 w = twT[m][rL];
            if constexpr (PASS == 0) w = cmul(w, twT[m][rH]);
            q[m] = cmul(q[m], w);
        }
        dft16<true>(q);
    } else {
        dft16<!PRUNED>(q);
#pragma unroll
        for (int m = 1; m < 16; ++m) {
            float2 w = twT[m][rL];
            if constexpr (PASS == 0) w = cmul(w, twT[m][rH]);
            q[RV[m]] = cmul(q[RV[m]], w);
        }
    }
#pragma unroll
    for (int m = 0; m < 16; ++m) lds[paddr<PASS>(sb, m)] = q[RV[m]];
}

// copy twiddle tables global -> LDS (transposed): 66 rows x 16 elems
__device__ __forceinline__ void load_twT(float2 (*twT)[68], const float* __restrict__ ws, int tid) {
    const float2* gTWB = (const float2*)(ws + OFF_TWB);
    const float2* gTL  = (const float2*)(ws + OFF_TL);
    const float2* gTWC = (const float2*)(ws + OFF_TWC);
    for (int idx = tid; idx < 16*66; idx += NT) {
        int r = idx >> 4, m = idx & 15;
        float2 v;
        if (r < 32)      v = gTWB[(r << 4) + m];
        else if (r < 64) v = gTL[((r - 32) << 4) + m];
        else             v = gTWC[((r - 64) << 4) + m];
        twT[m][r] = v;
    }
}

// spectral multiply for bin pair (k, 8192-k): o1/o2 are swapped v'[k], v'[8192-k]
__device__ __forceinline__ void specpair(float2 V1, float2 V2, float4 kv, float2 W,
                                         float2& o1, float2& o2) {
    float2 Eh = make_float2(V1.x + V2.x, V1.y - V2.y);
    float2 Oh = make_float2(V1.y + V2.y, V2.x - V1.x);
    float2 S = make_float2(kv.x, kv.y);
    float a = W.x*kv.z, b = W.y*kv.w, cc = W.x*kv.w, dd = W.y*kv.z;
    float2 T  = make_float2(a - b, cc + dd);
    float2 T2 = make_float2(a + b, cc - dd);
    float2 Ep = cadd(cmul(Eh, S), cmul(Oh, T));
    float2 Op = cadd(cmul(Eh, T2), cmul(Oh, S));
    o1 = make_float2(Ep.y + Op.x, Ep.x - Op.y);
    o2 = make_float2(Op.x - Ep.y, Ep.x + Op.y);
}

// merged init (block 0: twiddle tables via double-precision factor tables) + MLP (blocks 1..16)
__global__ __launch_bounds__(512) void k_pre(const float* __restrict__ z, const float* __restrict__ freq,
        const float* __restrict__ W0, const float* __restrict__ b0,
        const float* __restrict__ W1, const float* __restrict__ b1,
        const float* __restrict__ W2, const float* __restrict__ b2,
        float* __restrict__ ws, float* __restrict__ H) {
    __shared__ double2 lA[128], lB[128];
    const int t = threadIdx.x;
    if (blockIdx.x == 0) {
        const double K = -2.0 * 3.14159265358979323846 / 16384.0;
        if (t < 128)      { double a = K * (double)(t << 7); lA[t] = make_double2(cos(a), sin(a)); }
        else if (t < 256) { int b = t - 128; double a = K * (double)b; lB[b] = make_double2(cos(a), sin(a)); }
        __syncthreads();
        auto wf = [&](int e) -> float2 {
            e &= 16383;
            double2 A = lA[e >> 7], B = lB[e & 127];
            return make_float2((float)(A.x*B.x - A.y*B.y), (float)(A.x*B.y + A.y*B.x));
        };
        float2* tw16 = (float2*)(ws + OFF_TW16);
        for (int k = t; k <= 2048; k += 512) tw16[k] = wf(k);
        if (t < 32) {
            float2* rowL = (float2*)(ws + OFF_TL)  + (t << 4);
            float2* rowB = (float2*)(ws + OFF_TWB) + (t << 4);
#pragma unroll
            for (int m = 0; m < 16; ++m) { rowL[m] = wf(2*t*m); rowB[m] = wf(32*t*m); }
        } else if (t < 34) {
            int c2 = t - 32;
            float2* rowC = (float2*)(ws + OFF_TWC) + (c2 << 4);
#pragma unroll
            for (int m = 0; m < 16; ++m) rowC[m] = wf(512*c2*m);
        }
    } else {
        const int j = ((blockIdx.x - 1) << 9) + t;
        const float z0 = z[j*3+0], z1 = z[j*3+1], z2 = z[j*3+2];
        float h[16], g[16];
#pragma unroll
        for (int m = 0; m < 16; ++m)
            h[m] = sinf(freq[m] * (z0*W0[m] + z1*W0[16+m] + z2*W0[32+m] + b0[m]));
#pragma unroll
        for (int m = 0; m < 16; ++m) {
            float a = b1[m];
#pragma unroll
            for (int p = 0; p < 16; ++p) a += h[p] * W1[p*16+m];
            g[m] = sinf(freq[m] * a);
        }
#pragma unroll
        for (int m = 0; m < 16; ++m) {
            float a = b2[m];
#pragma unroll
            for (int p = 0; p < 16; ++p) a += g[p] * W2[p*16+m];
            h[m] = sinf(freq[m] * a);
        }
        float4* hp = (float4*)(H + (j << 4));   // row-major [8192][16]
        hp[0] = make_float4(h[0],  h[1],  h[2],  h[3]);
        hp[1] = make_float4(h[4],  h[5],  h[6],  h[7]);
        hp[2] = make_float4(h[8],  h[9],  h[10], h[11]);
        hp[3] = make_float4(h[12], h[13], h[14], h[15]);
    }
}

// Per channel (512 threads): filter -> pruned fwd FFT -> fused(r2+unpack)
// -> store (S~,D~)
__global__ __launch_bounds__(NT) void k_filter(const float* __restrict__ H, const float* __restrict__ t,
        const float* __restrict__ deltas, const float* __restrict__ W3,
        const float* __restrict__ b3, const float* __restrict__ ws,
        float* __restrict__ KfF) {
    __shared__ float2 lds[LSEQ];
    __shared__ float2 twT[16][68];
    const int c = blockIdx.x;
    const int tid = threadIdx.x;
    load_twT(twT, ws, tid);
    float4 w3a = make_float4(W3[0*NCH+c],  W3[1*NCH+c],  W3[2*NCH+c],  W3[3*NCH+c]);
    float4 w3b = make_float4(W3[4*NCH+c],  W3[5*NCH+c],  W3[6*NCH+c],  W3[7*NCH+c]);
    float4 w3c = make_float4(W3[8*NCH+c],  W3[9*NCH+c],  W3[10*NCH+c], W3[11*NCH+c]);
    float4 w3d = make_float4(W3[12*NCH+c], W3[13*NCH+c], W3[14*NCH+c], W3[15*NCH+c]);
    const float b3c = b3[c];
    const float ad = fabsf(deltas[c]);
    const int sbA = psb<0>(tid);
#pragma unroll 2
    for (int j = 0; j < 8; ++j) {
        int n = tid + (j << 9);
        const float4* hp = (const float4*)(H + (n << 5));
        float4 p0 = hp[0], p1 = hp[1], p2 = hp[2], p3 = hp[3];
        float4 q0 = hp[4], q1 = hp[5], q2 = hp[6], q3 = hp[7];
        float s0 = b3c + p0.x*w3a.x + p0.y*w3a.y + p0.z*w3a.z + p0.w*w3a.w
                       + p1.x*w3b.x + p1.y*w3b.y + p1.z*w3b.z + p1.w*w3b.w
                       + p2.x*w3c.x + p2.y*w3c.y + p2.z*w3c.z + p2.w*w3c.w
                       + p3.x*w3d.x + p3.y*w3d.y + p3.z*w3d.z + p3.w*w3d.w;
        float s1 = b3c + q0.x*w3a.x + q0.y*w3a.y + q0.z*w3a.z + q0.w*w3a.w
                       + q1.x*w3b.x + q1.y*w3b.y + q1.z*w3b.z + q1.w*w3b.w
                       + q2.x*w3c.x + q2.y*w3c.y + q2.z*w3c.z + q2.w*w3c.w
                       + q3.x*w3d.x + q3.y*w3d.y + q3.z*w3d.z + q3.w*w3d.w;
        float2 tv = ((const float2*)t)[n];
        lds[(sbA ^ (2*j)) + (j<<9)] = make_float2(s0 * expf(-tv.x*ad), s1 * expf(-tv.y*ad));
    }
    __syncthreads();
    r16p<0,false,true >(lds, twT, tid); __syncthreads();
    r16p<1,false,false>(lds, twT, tid); wave_sync();
    r16p<2,false,false>(lds, twT, tid); __syncthreads();

    float4* kf4 = (float4*)KfF + (size_t)c * 4096;
    const float2* tw16 = (const float2*)(ws + OFF_TW16);
    const float sc = 1.0f / 32768.0f;
#pragma unroll 2
    for (int it = 0; it < 4; ++it) {
        int k  = tid + 1 + (it << 9);   // 1..2048
        int jj = 4096 - k;              // 2048..4095 (k=2048: idempotent dup)
        int pA = IDX(drev(k)), pB = IDX(drev(jj));
        float2 uA = lds[pA], vA = lds[pA^1];
        float2 uB = lds[pB], vB = lds[pB^1];
        float2 Vk = cadd(uA, vA), Vk4 = csub(uA, vA);   // bins k, k+4096
        float2 Vj = cadd(uB, vB), Vj4 = csub(uB, vB);   // bins jj, jj+4096 (=8192-k)
        float2 W  = tw16[k];
        float2 Wj = make_float2(-W.y, -W.x);            // tw16[4096-k]
        {
            float2 E = make_float2(Vk.x + Vj4.x, Vk.y - Vj4.y);
            float2 O = make_float2(Vk.y + Vj4.y, Vj4.x - Vk.x);
            float2 D = cmul(W, O);
            kf4[k] = make_float4(E.x*sc, E.y*sc, D.x*sc, D.y*sc);
        }
        {
            float2 E = make_float2(Vj.x + Vk4.x, Vj.y - Vk4.y);
            float2 O = make_float2(Vj.y + Vk4.y, Vk4.x - Vj.x);
            float2 D = cmul(Wj, O);
            kf4[jj] = make_float4(E.x*sc, E.y*sc, D.x*sc, D.y*sc);
        }
    }
    if (tid == 0) {
        float2 u = lds[0], v = lds[1];          // IDX(0)=0, IDX(1)=1
        float2 V0 = cadd(u, v), VN = csub(u, v);
        kf4[0] = make_float4((V0.x + V0.y)/16384.f, (V0.x - V0.y)/16384.f,
                             VN.x/8192.f, -VN.y/8192.f);
    }
}

// Block (512 threads) = (channel c, batch-half): 4 rows sequential. Register
// diet for 2-blocks/CU co-residency (16 waves/CU): no persistent xs/pf
// (x re-read at epilogue, L2-resident), spectral unroll 1, row unroll 1.
__global__ __launch_bounds__(NT) void k_main(const float* __restrict__ x, const float* __restrict__ ws,
        const float* __restrict__ KfF, const float* __restrict__ bias,
        float* __restrict__ out) {
    __shared__ float2 lds[LSEQ];
    __shared__ float2 twT[16][68];
    const int bid = blockIdx.x;                 // 0..1535
    const int c = bid >> 1, half = bid & 1;     // 4 batches per block, same channel
    const int tt = threadIdx.x;
    const float4* kf4 = (const float4*)KfF + (size_t)c * 4096;
    const float2* tw16 = (const float2*)(ws + OFF_TW16);
    const size_t rowstride = (size_t)NCH * LSEQ;
    const float* xbase = x + (size_t)(half*4) * rowstride + (size_t)c * LSEQ;
    float* obase = out + (size_t)(half*4) * rowstride + (size_t)c * LSEQ;
    const float bc = bias[c];

    // staging addresses: IDX(2i) = (EB ^ (j<<2)) + (j<<10), IDX(2i+1) = that ^ 1
    const int EB = (tt << 1) ^ (((tt>>3) ^ (tt>>7)) & 15);

    load_twT(twT, ws, tt);

#pragma unroll 1
    for (int rr = 0; rr < 4; ++rr) {
        const float4* xr4 = (const float4*)(xbase + (size_t)rr * rowstride);
#pragma unroll
        for (int j = 0; j < 4; ++j) {
            float4 v = xr4[tt + (j<<9)];
            int a0 = (EB ^ (j<<2)) + (j<<10);
            lds[a0]   = make_float2(v.x, v.y);
            lds[a0^1] = make_float2(v.z, v.w);
        }
        __syncthreads();                              // also covers twT copy (rr==0)
        r16p<0,false,true >(lds, twT, tt); __syncthreads();
        r16p<1,false,false>(lds, twT, tt); wave_sync();
        r16p<2,false,false>(lds, twT, tt); __syncthreads();

        // fused fwd-r2 + spectral multiply + inverse-r2, per closed quad of bins
#pragma unroll 1
        for (int it = 0; it < 4; ++it) {
            int k  = tt + 1 + (it << 9);   // 1..2048
            int jj = 4096 - k;
            int pA = IDX(drev(k)), pB = IDX(drev(jj));
            float2 uA = lds[pA], vA = lds[pA^1];
            float2 uB = lds[pB], vB = lds[pB^1];
            float2 Vk = cadd(uA, vA), Vk4 = csub(uA, vA);   // bins k, k+4096
            float2 Vj = cadd(uB, vB), Vj4 = csub(uB, vB);   // bins jj, 8192-k
            float4 kvk = kf4[k], kvj = kf4[jj];
            float2 W  = tw16[k];
            float2 Wj = make_float2(-W.y, -W.x);
            float2 r1, r2, r1j, r2j;
            specpair(Vk, Vj4, kvk, W,  r1,  r2);   // v'[k],  v'[8192-k]
            specpair(Vj, Vk4, kvj, Wj, r1j, r2j);  // v'[jj], v'[4096+k]
            lds[pA]   = cadd(r1, r2j);  lds[pA^1] = csub(r1, r2j);
            lds[pB]   = cadd(r1j, r2);  lds[pB^1] = csub(r1j, r2);
        }
        if (tt == 0) {
            float2 u = lds[0], v = lds[1];
            float2 V0 = cadd(u, v), VN = csub(u, v);        // bins 0, 4096
            float4 kv = kf4[0];
            float U0 = V0.x + V0.y, UL = V0.x - V0.y;
            float re = U0*kv.x + UL*kv.y;
            float im = U0*kv.x - UL*kv.y;
            float2 s0 = make_float2(im, re);
            float2 P = make_float2(VN.x*kv.z + VN.y*kv.w, VN.x*kv.w - VN.y*kv.z);
            float2 s1 = make_float2(-P.y, P.x);
            lds[0] = cadd(s0, s1);
            lds[1] = csub(s0, s1);
        }
        __syncthreads();

        r16p<2,true,false>(lds, twT, tt); wave_sync();
        r16p<1,true,false>(lds, twT, tt); __syncthreads();
        r16p<0,true,false>(lds, twT, tt); __syncthreads();

        float4* orow4 = (float4*)(obase + (size_t)rr * rowstride);
#pragma unroll
        for (int j = 0; j < 4; ++j) {
            int a0 = (EB ^ (j<<2)) + (j<<10);
            float2 wA = lds[a0], wB = lds[a0^1];
            float4 xv = xr4[tt + (j<<9)];               // re-read (L2-resident)
            orow4[tt + (j<<9)] = make_float4(wA.y + xv.x*bc, wA.x + xv.y*bc,
                                             wB.y + xv.z*bc, wB.x + xv.w*bc);
        }
        if (rr < 3) __syncthreads();   // protect lds before next row's staging
    }
}

extern "C" void kernel_launch(void* const* d_in, const int* in_sizes, int n_in,
                              void* d_out, int out_size, void* d_ws, size_t ws_size,
                              hipStream_t stream) {
    const float* x      = (const float*)d_in[0];
    const float* z      = (const float*)d_in[2];
    const float* t      = (const float*)d_in[3];
    const float* deltas = (const float*)d_in[4];
    const float* freq   = (const float*)d_in[5];
    const float* W0     = (const float*)d_in[6];
    const float* b0     = (const float*)d_in[7];
    const float* W1     = (const float*)d_in[8];
    const float* b1     = (const float*)d_in[9];
    const float* W2     = (const float*)d_in[10];
    const float* b2     = (const float*)d_in[11];
    const float* W3     = (const float*)d_in[12];
    const float* b3     = (const float*)d_in[13];
    const float* bias   = (const float*)d_in[14];
    float* out = (float*)d_out;
    float* ws  = (float*)d_ws;
    float* H   = ws + OFF_H;
    float* Kf  = ws + OFF_KF;

    hipLaunchKernelGGL(k_pre, dim3(17), dim3(512), 0, stream, z, freq, W0, b0, W1, b1, W2, b2, ws, H);
    hipLaunchKernelGGL(k_filter, dim3(NCH), dim3(NT), 0, stream, H, t, deltas, W3, b3, ws, Kf);
    hipLaunchKernelGGL(k_main, dim3(NBATCH * NCH / 4), dim3(NT), 0, stream, x, ws, Kf, bias, out);
}

// Round 9
// 672.044 us; speedup vs baseline: 1.5334x; 1.0096x over previous
//
#include <hip/hip_runtime.h>
#include <math.h>

// HyenaFilter: y = irfft(rfft(x,2L) * rfft(k,2L))[..., :L] + x*bias
// Register-blocked mixed-radix [16,16,16,2] FFT. Round-9 revision:
//  - Occupancy ceiling accepted (8 waves/CU: 2-block residency needs <=64 VGPR,
//    impossible for q[16] passes; VGPR quantum 64/128 per m69). Attack stalls
//    at fixed occupancy: TWO-ROW PING-PONG per 512-thread block. lds2[2][8192]
//    (+twT = 139.8 KB, still 1 block/CU) holds two rows; every pass runs on
//    both buffers between barriers -> barriers per row halved, buffer-1 ds_reads
//    land under buffer-0's dft16 chain, twiddle/kf loads shared across rows.
//  - k_filter: same trick with 2 CHANNELS per block; H loads are channel-
//    independent -> staging loads shared (per-channel staging cost halves).
//  - keeps: LDS twiddle tables, folded XOR-swizzle, wave-local B<->C sync,
//    fused r2+spectral quad, pruned first fwd pass, x re-read epilogue,
//    merged k_pre. Plain __launch_bounds__(512) (min-waves arg harms: R1/R5/R6).

#define LSEQ 8192
#define NCH 768
#define NBATCH 8
#define NT 512            // threads per block

// ws layout (float offsets)
#define OFF_TWB  0        // 32 rows x 16 float2 : W16384^{32*q*m}   (pass B; pass-A high = rows 2b)
#define OFF_TW16 1024     // 2049 float2         : W16384^k, k<=2048
#define OFF_TL   5124     // 32 rows x 16 float2 : W16384^{2*a*m}    (pass A low)
#define OFF_TWC  6660     // 2 rows x 16 float2  : W16384^{512*p*m}  (pass C)
#define OFF_H    10240    // 8192 x 16 floats (MLP features, row-major)
#define OFF_KF   141312   // 768 x 4096 float4 (S~, D~ per bin pair)

__device__ __forceinline__ float2 cadd(float2 a, float2 b){ return make_float2(a.x+b.x, a.y+b.y); }
__device__ __forceinline__ float2 csub(float2 a, float2 b){ return make_float2(a.x-b.x, a.y-b.y); }
__device__ __forceinline__ float2 cmul(float2 a, float2 b){ return make_float2(a.x*b.x - a.y*b.y, a.x*b.y + a.y*b.x); }
__device__ __forceinline__ float2 mni(float2 a){ return make_float2(a.y, -a.x); }  // * -i

// wave-local LDS producer->consumer sync (exchange confined to one wave)
__device__ __forceinline__ void wave_sync(){
    asm volatile("s_waitcnt lgkmcnt(0)" ::: "memory");
}

// generic swizzle (used only in the spectral stage)
__device__ __forceinline__ int IDX(int i){ return i ^ (((i>>4) ^ (i>>8)) & 15); }
// digit-reversal: bin k -> slot after DIF passes [16(512),16(32),16(2)] (pre-r2, slot even)
__device__ __forceinline__ int drev(int k){
    return ((k & 15) << 9) | (((k >> 4) & 15) << 5) | (((k >> 8) & 15) << 1) | (k >> 12);
}

#define C1 0.923879532511286756f
#define S1 0.382683432365089772f
#define R2 0.707106781186547524f

// natural-in DFT-16; output bin m in q[rv[m]]. FULL=false: inputs 8..15 are
// pre-duplicated copies of 0..7 (zero upper half), stage-1 add/sub skipped.
template<bool FULL>
__device__ __forceinline__ void dft16(float2 q[16]) {
    if constexpr (FULL) {
#pragma unroll
        for (int j = 0; j < 8; ++j) { float2 u=q[j], v=q[j+8]; q[j]=cadd(u,v); q[j+8]=csub(u,v); }
    }
    q[9]  = cmul(q[9],  make_float2( C1,-S1));
    q[10] = cmul(q[10], make_float2( R2,-R2));
    q[11] = cmul(q[11], make_float2( S1,-C1));
    q[12] = mni(q[12]);
    q[13] = cmul(q[13], make_float2(-S1,-C1));
    q[14] = cmul(q[14], make_float2(-R2,-R2));
    q[15] = cmul(q[15], make_float2(-C1,-S1));
#pragma unroll
    for (int b = 0; b < 16; b += 8) {
#pragma unroll
        for (int j = 0; j < 4; ++j) { float2 u=q[b+j], v=q[b+j+4]; q[b+j]=cadd(u,v); q[b+j+4]=csub(u,v); }
        q[b+5] = cmul(q[b+5], make_float2( R2,-R2));
        q[b+6] = mni(q[b+6]);
        q[b+7] = cmul(q[b+7], make_float2(-R2,-R2));
    }
#pragma unroll
    for (int b = 0; b < 16; b += 4) {
        float2 u0=q[b], v0=q[b+2], u1=q[b+1], v1=q[b+3];
        q[b]=cadd(u0,v0); q[b+2]=csub(u0,v0);
        q[b+1]=cadd(u1,v1); q[b+3]=mni(csub(u1,v1));
    }
#pragma unroll
    for (int b = 0; b < 16; b += 2) { float2 u=q[b], v=q[b+1]; q[b]=cadd(u,v); q[b+1]=csub(u,v); }
}

// Hand-folded swizzled addressing: IDX(base+p+r*L) == (sb ^ C_r) + (r*L).
template<int PASS>
__device__ __forceinline__ int psb(int t) {
    if constexpr (PASS == 0) {               // L=512, p=t
        return t ^ (((t>>4) ^ (t>>8)) & 15);
    } else if constexpr (PASS == 1) {        // L=32, base=(t>>5)<<9, p=t&31
        int p = t & 31, hb = t >> 5;
        return ((hb<<9) | p) ^ (((p>>4) ^ (hb<<1)) & 15);
    } else {                                 // L=2, base=(t>>1)<<5, p=t&1
        int h = t >> 1;
        return ((h<<5) | (t&1)) ^ (((h<<1) ^ (h>>3)) & 15);
    }
}
template<int PASS>
__device__ __forceinline__ int paddr(int sb, int r) {
    if constexpr (PASS == 0)      return (sb ^ (2*(r&7))) + (r<<9);
    else if constexpr (PASS == 1) return (sb ^ ((2*(r&7)) ^ (r>>3))) + (r<<5);
    else                          return sb ^ ((r<<1) ^ (r>>3));
}

// One radix-16 pass over TWO buffers (ping-pong): all reads issued first
// (buffer-1 latency hides under buffer-0 compute), twiddles loaded once and
// applied to both. twT[m][row]: row<32 TWB, 32+a TL, 64+c TWC.
// Pass A twiddle W8192^{pm} = TL[p&31][m] * TWB[2*(p>>5)][m].
template<int PASS, bool DIT, bool PRUNED>
__device__ __forceinline__ void r16p2(float2* l0, float2* l1, const float2 (*twT)[68], int t) {
    static constexpr int RV[16] = {0,8,4,12,2,10,6,14,1,9,5,13,3,11,7,15};
    const int sb = psb<PASS>(t);
    int rL, rH = 0;
    if constexpr (PASS == 0) { rL = 32 + (t & 31); rH = (t >> 5) << 1; }
    else if constexpr (PASS == 1) { rL = t & 31; }
    else { rL = 64 + (t & 1); }
    float2 q0[16], q1[16];
    if constexpr (PRUNED) {
#pragma unroll
        for (int r = 0; r < 8; ++r) { q0[r] = l0[paddr<PASS>(sb, r)]; q1[r] = l1[paddr<PASS>(sb, r)]; }
#pragma unroll
        for (int r = 0; r < 8; ++r) { q0[r+8] = q0[r]; q1[r+8] = q1[r]; }
    } else {
#pragma unroll
        for (int r = 0; r < 16; ++r) { q0[r] = l0[paddr<PASS>(sb, r)]; q1[r] = l1[paddr<PASS>(sb, r)]; }
    }
    if constexpr (DIT) {
#pragma unroll
        for (int m = 1; m < 16; ++m) {
            float2 w = twT[m][rL];
            if constexpr (PASS == 0) w = cmul(w, twT[m][rH]);
            q0[m] = cmul(q0[m], w);
            q1[m] = cmul(q1[m], w);
        }
        dft16<true>(q0);
        dft16<true>(q1);
    } else {
        dft16<!PRUNED>(q0);
        dft16<!PRUNED>(q1);
#pragma unroll
        for (int m = 1; m < 16; ++m) {
            float2 w = twT[m][rL];
            if constexpr (PASS == 0) w = cmul(w, twT[m][rH]);
            q0[RV[m]] = cmul(q0[RV[m]], w);
            q1[RV[m]] = cmul(q1[RV[m]], w);
        }
    }
#pragma unroll
    for (int m = 0; m < 16; ++m) {
        l0[paddr<PASS>(sb, m)] = q0[RV[m]];
        l1[paddr<PASS>(sb, m)] = q1[RV[m]];
    }
}

// copy twiddle tables global -> LDS (transposed): 66 rows x 16 elems
__device__ __forceinline__ void load_twT(float2 (*twT)[68], const float* __restrict__ ws, int tid) {
    const float2* gTWB = (const float2*)(ws + OFF_TWB);
    const float2* gTL  = (const float2*)(ws + OFF_TL);
    const float2* gTWC = (const float2*)(ws + OFF_TWC);
    for (int idx = tid; idx < 16*66; idx += NT) {
        int r = idx >> 4, m = idx & 15;
        float2 v;
        if (r < 32)      v = gTWB[(r << 4) + m];
        else if (r < 64) v = gTL[((r - 32) << 4) + m];
        else             v = gTWC[((r - 64) << 4) + m];
        twT[m][r] = v;
    }
}

// spectral multiply for bin pair (k, 8192-k): o1/o2 are swapped v'[k], v'[8192-k]
__device__ __forceinline__ void specpair(float2 V1, float2 V2, float4 kv, float2 W,
                                         float2& o1, float2& o2) {
    float2 Eh = make_float2(V1.x + V2.x, V1.y - V2.y);
    float2 Oh = make_float2(V1.y + V2.y, V2.x - V1.x);
    float2 S = make_float2(kv.x, kv.y);
    float a = W.x*kv.z, b = W.y*kv.w, cc = W.x*kv.w, dd = W.y*kv.z;
    float2 T  = make_float2(a - b, cc + dd);
    float2 T2 = make_float2(a + b, cc - dd);
    float2 Ep = cadd(cmul(Eh, S), cmul(Oh, T));
    float2 Op = cadd(cmul(Eh, T2), cmul(Oh, S));
    o1 = make_float2(Ep.y + Op.x, Ep.x - Op.y);
    o2 = make_float2(Op.x - Ep.y, Ep.x + Op.y);
}

// fused fwd-r2 + spectral multiply + inverse-r2 for one buffer at quad (k,jj)
__device__ __forceinline__ void spec_rows(float2* l, int pA, int pB,
                                          float4 kvk, float4 kvj, float2 W, float2 Wj) {
    float2 uA = l[pA], vA = l[pA^1];
    float2 uB = l[pB], vB = l[pB^1];
    float2 Vk = cadd(uA, vA), Vk4 = csub(uA, vA);   // bins k, k+4096
    float2 Vj = cadd(uB, vB), Vj4 = csub(uB, vB);   // bins jj, 8192-k
    float2 r1, r2, r1j, r2j;
    specpair(Vk, Vj4, kvk, W,  r1,  r2);   // v'[k],  v'[8192-k]
    specpair(Vj, Vk4, kvj, Wj, r1j, r2j);  // v'[jj], v'[4096+k]
    l[pA]   = cadd(r1, r2j);  l[pA^1] = csub(r1, r2j);
    l[pB]   = cadd(r1j, r2);  l[pB^1] = csub(r1j, r2);
}

// bins 0 / 4096 special (tt==0)
__device__ __forceinline__ void spec_dc(float2* l, float4 kv) {
    float2 u = l[0], v = l[1];
    float2 V0 = cadd(u, v), VN = csub(u, v);
    float U0 = V0.x + V0.y, UL = V0.x - V0.y;
    float re = U0*kv.x + UL*kv.y;
    float im = U0*kv.x - UL*kv.y;
    float2 s0 = make_float2(im, re);
    float2 P = make_float2(VN.x*kv.z + VN.y*kv.w, VN.x*kv.w - VN.y*kv.z);
    float2 s1 = make_float2(-P.y, P.x);
    l[0] = cadd(s0, s1);
    l[1] = csub(s0, s1);
}

// filter spectral store for one channel at quad (k,jj)
__device__ __forceinline__ void filt_store(float2* l, float4* kf, int k, int jj,
                                           int pA, int pB, float2 W, float2 Wj, float sc) {
    float2 uA = l[pA], vA = l[pA^1];
    float2 uB = l[pB], vB = l[pB^1];
    float2 Vk = cadd(uA, vA), Vk4 = csub(uA, vA);
    float2 Vj = cadd(uB, vB), Vj4 = csub(uB, vB);
    {
        float2 E = make_float2(Vk.x + Vj4.x, Vk.y - Vj4.y);
        float2 O = make_float2(Vk.y + Vj4.y, Vj4.x - Vk.x);
        float2 D = cmul(W, O);
        kf[k] = make_float4(E.x*sc, E.y*sc, D.x*sc, D.y*sc);
    }
    {
        float2 E = make_float2(Vj.x + Vk4.x, Vj.y - Vk4.y);
        float2 O = make_float2(Vj.y + Vk4.y, Vk4.x - Vj.x);
        float2 D = cmul(Wj, O);
        kf[jj] = make_float4(E.x*sc, E.y*sc, D.x*sc, D.y*sc);
    }
}
__device__ __forceinline__ void filt_dc(float2* l, float4* kf) {
    float2 u = l[0], v = l[1];
    float2 V0 = cadd(u, v), VN = csub(u, v);
    kf[0] = make_float4((V0.x + V0.y)/16384.f, (V0.x - V0.y)/16384.f,
                        VN.x/8192.f, -VN.y/8192.f);
}

// merged init (block 0: twiddle tables via double-precision factor tables) + MLP (blocks 1..16)
__global__ __launch_bounds__(512) void k_pre(const float* __restrict__ z, const float* __restrict__ freq,
        const float* __restrict__ W0, const float* __restrict__ b0,
        const float* __restrict__ W1, const float* __restrict__ b1,
        const float* __restrict__ W2, const float* __restrict__ b2,
        float* __restrict__ ws, float* __restrict__ H) {
    __shared__ double2 lA[128], lB[128];
    const int t = threadIdx.x;
    if (blockIdx.x == 0) {
        const double K = -2.0 * 3.14159265358979323846 / 16384.0;
        if (t < 128)      { double a = K * (double)(t << 7); lA[t] = make_double2(cos(a), sin(a)); }
        else if (t < 256) { int b = t - 128; double a = K * (double)b; lB[b] = make_double2(cos(a), sin(a)); }
        __syncthreads();
        auto wf = [&](int e) -> float2 {
            e &= 16383;
            double2 A = lA[e >> 7], B = lB[e & 127];
            return make_float2((float)(A.x*B.x - A.y*B.y), (float)(A.x*B.y + A.y*B.x));
        };
        float2* tw16 = (float2*)(ws + OFF_TW16);
        for (int k = t; k <= 2048; k += 512) tw16[k] = wf(k);
        if (t < 32) {
            float2* rowL = (float2*)(ws + OFF_TL)  + (t << 4);
            float2* rowB = (float2*)(ws + OFF_TWB) + (t << 4);
#pragma unroll
            for (int m = 0; m < 16; ++m) { rowL[m] = wf(2*t*m); rowB[m] = wf(32*t*m); }
        } else if (t < 34) {
            int c2 = t - 32;
            float2* rowC = (float2*)(ws + OFF_TWC) + (c2 << 4);
#pragma unroll
            for (int m = 0; m < 16; ++m) rowC[m] = wf(512*c2*m);
        }
    } else {
        const int j = ((blockIdx.x - 1) << 9) + t;
        const float z0 = z[j*3+0], z1 = z[j*3+1], z2 = z[j*3+2];
        float h[16], g[16];
#pragma unroll
        for (int m = 0; m < 16; ++m)
            h[m] = sinf(freq[m] * (z0*W0[m] + z1*W0[16+m] + z2*W0[32+m] + b0[m]));
#pragma unroll
        for (int m = 0; m < 16; ++m) {
            float a = b1[m];
#pragma unroll
            for (int p = 0; p < 16; ++p) a += h[p] * W1[p*16+m];
            g[m] = sinf(freq[m] * a);
        }
#pragma unroll
        for (int m = 0; m < 16; ++m) {
            float a = b2[m];
#pragma unroll
            for (int p = 0; p < 16; ++p) a += g[p] * W2[p*16+m];
            h[m] = sinf(freq[m] * a);
        }
        float4* hp = (float4*)(H + (j << 4));   // row-major [8192][16]
        hp[0] = make_float4(h[0],  h[1],  h[2],  h[3]);
        hp[1] = make_float4(h[4],  h[5],  h[6],  h[7]);
        hp[2] = make_float4(h[8],  h[9],  h[10], h[11]);
        hp[3] = make_float4(h[12], h[13], h[14], h[15]);
    }
}

// TWO channels per block (ping-pong buffers): H loads shared (channel-indep),
// filter -> pruned fwd FFT -> fused(r2+unpack) -> store (S~,D~) for both.
__global__ __launch_bounds__(NT) void k_filter(const float* __restrict__ H, const float* __restrict__ t,
        const float* __restrict__ deltas, const float* __restrict__ W3,
        const float* __restrict__ b3, const float* __restrict__ ws,
        float* __restrict__ KfF) {
    __shared__ float2 lds2[2][LSEQ];
    __shared__ float2 twT[16][68];
    const int c0 = blockIdx.x << 1, c1 = c0 + 1;
    const int tid = threadIdx.x;
    float2* l0 = lds2[0];
    float2* l1 = lds2[1];
    load_twT(twT, ws, tid);
    float w30[16], w31[16];
#pragma unroll
    for (int m = 0; m < 16; ++m) { w30[m] = W3[m*NCH + c0]; w31[m] = W3[m*NCH + c1]; }
    const float b30 = b3[c0], b31 = b3[c1];
    const float ad0 = fabsf(deltas[c0]), ad1 = fabsf(deltas[c1]);
    const int sbA = psb<0>(tid);
#pragma unroll 1
    for (int j = 0; j < 8; ++j) {
        int n = tid + (j << 9);
        const float4* hp = (const float4*)(H + (n << 5));
        float sA0 = b30, sB0 = b30, sA1 = b31, sB1 = b31;   // A/B = the 2 time pts
#pragma unroll
        for (int q = 0; q < 4; ++q) {
            float4 a = hp[q];       // elems of point 2n
            float4 b = hp[4+q];     // elems of point 2n+1
            sA0 += a.x*w30[4*q] + a.y*w30[4*q+1] + a.z*w30[4*q+2] + a.w*w30[4*q+3];
            sB0 += b.x*w30[4*q] + b.y*w30[4*q+1] + b.z*w30[4*q+2] + b.w*w30[4*q+3];
            sA1 += a.x*w31[4*q] + a.y*w31[4*q+1] + a.z*w31[4*q+2] + a.w*w31[4*q+3];
            sB1 += b.x*w31[4*q] + b.y*w31[4*q+1] + b.z*w31[4*q+2] + b.w*w31[4*q+3];
        }
        float2 tv = ((const float2*)t)[n];
        int a0 = (sbA ^ (2*j)) + (j<<9);
        l0[a0] = make_float2(sA0 * expf(-tv.x*ad0), sB0 * expf(-tv.y*ad0));
        l1[a0] = make_float2(sA1 * expf(-tv.x*ad1), sB1 * expf(-tv.y*ad1));
    }
    __syncthreads();
    r16p2<0,false,true >(l0, l1, twT, tid); __syncthreads();
    r16p2<1,false,false>(l0, l1, twT, tid); wave_sync();
    r16p2<2,false,false>(l0, l1, twT, tid); __syncthreads();

    float4* kf0 = (float4*)KfF + (size_t)c0 * 4096;
    float4* kf1 = (float4*)KfF + (size_t)c1 * 4096;
    const float2* tw16 = (const float2*)(ws + OFF_TW16);
    const float sc = 1.0f / 32768.0f;
#pragma unroll 1
    for (int it = 0; it < 4; ++it) {
        int k  = tid + 1 + (it << 9);   // 1..2048
        int jj = 4096 - k;              // (k=2048: idempotent dup)
        int pA = IDX(drev(k)), pB = IDX(drev(jj));
        float2 W  = tw16[k];
        float2 Wj = make_float2(-W.y, -W.x);
        filt_store(l0, kf0, k, jj, pA, pB, W, Wj, sc);
        filt_store(l1, kf1, k, jj, pA, pB, W, Wj, sc);
    }
    if (tid == 0) { filt_dc(l0, kf0); filt_dc(l1, kf1); }
}

// Block = (channel c, batch-half): 4 rows as 2 ping-pong pairs. Every pass runs
// on both buffers between barriers; kf4/tw16 loads shared across the pair.
__global__ __launch_bounds__(NT) void k_main(const float* __restrict__ x, const float* __restrict__ ws,
        const float* __restrict__ KfF, const float* __restrict__ bias,
        float* __restrict__ out) {
    __shared__ float2 lds2[2][LSEQ];
    __shared__ float2 twT[16][68];
    const int bid = blockIdx.x;                 // 0..1535
    const int c = bid >> 1, half = bid & 1;
    const int tt = threadIdx.x;
    float2* l0 = lds2[0];
    float2* l1 = lds2[1];
    const float4* kf4 = (const float4*)KfF + (size_t)c * 4096;
    const float2* tw16 = (const float2*)(ws + OFF_TW16);
    const size_t rowstride = (size_t)NCH * LSEQ;
    const float* xbase = x + (size_t)(half*4) * rowstride + (size_t)c * LSEQ;
    float* obase = out + (size_t)(half*4) * rowstride + (size_t)c * LSEQ;
    const float bc = bias[c];

    // staging addresses: IDX(2i) = (EB ^ (j<<2)) + (j<<10), IDX(2i+1) = that ^ 1
    const int EB = (tt << 1) ^ (((tt>>3) ^ (tt>>7)) & 15);

    load_twT(twT, ws, tt);

#pragma unroll 1
    for (int pp = 0; pp < 2; ++pp) {            // pair = rows (2pp, 2pp+1)
        const float4* xr0 = (const float4*)(xbase + (size_t)(2*pp)     * rowstride);
        const float4* xr1 = (const float4*)(xbase + (size_t)(2*pp + 1) * rowstride);
#pragma unroll
        for (int j = 0; j < 4; ++j) {
            float4 v0 = xr0[tt + (j<<9)];
            float4 v1 = xr1[tt + (j<<9)];
            int a0 = (EB ^ (j<<2)) + (j<<10);
            l0[a0]   = make_float2(v0.x, v0.y);
            l0[a0^1] = make_float2(v0.z, v0.w);
            l1[a0]   = make_float2(v1.x, v1.y);
            l1[a0^1] = make_float2(v1.z, v1.w);
        }
        __syncthreads();                              // also covers twT copy (pp==0)
        r16p2<0,false,true >(l0, l1, twT, tt); __syncthreads();
        r16p2<1,false,false>(l0, l1, twT, tt); wave_sync();
        r16p2<2,false,false>(l0, l1, twT, tt); __syncthreads();

        // fused fwd-r2 + spectral + inverse-r2 on both buffers; kf/tw shared
#pragma unroll 1
        for (int it = 0; it < 4; ++it) {
            int k  = tt + 1 + (it << 9);   // 1..2048
            int jj = 4096 - k;
            int pA = IDX(drev(k)), pB = IDX(drev(jj));
            float4 kvk = kf4[k], kvj = kf4[jj];
            float2 W  = tw16[k];
            float2 Wj = make_float2(-W.y, -W.x);
            spec_rows(l0, pA, pB, kvk, kvj, W, Wj);
            spec_rows(l1, pA, pB, kvk, kvj, W, Wj);
        }
        if (tt == 0) {
            float4 kv = kf4[0];
            spec_dc(l0, kv);
            spec_dc(l1, kv);
        }
        __syncthreads();

        r16p2<2,true,false>(l0, l1, twT, tt); wave_sync();
        r16p2<1,true,false>(l0, l1, twT, tt); __syncthreads();
        r16p2<0,true,false>(l0, l1, twT, tt); __syncthreads();

        float4* o0 = (float4*)(obase + (size_t)(2*pp)     * rowstride);
        float4* o1 = (float4*)(obase + (size_t)(2*pp + 1) * rowstride);
#pragma unroll
        for (int j = 0; j < 4; ++j) {
            int a0 = (EB ^ (j<<2)) + (j<<10);
            float2 wA0 = l0[a0], wB0 = l0[a0^1];
            float2 wA1 = l1[a0], wB1 = l1[a0^1];
            float4 xv0 = xr0[tt + (j<<9)];              // re-read (L2-resident)
            float4 xv1 = xr1[tt + (j<<9)];
            o0[tt + (j<<9)] = make_float4(wA0.y + xv0.x*bc, wA0.x + xv0.y*bc,
                                          wB0.y + xv0.z*bc, wB0.x + xv0.w*bc);
            o1[tt + (j<<9)] = make_float4(wA1.y + xv1.x*bc, wA1.x + xv1.y*bc,
                                          wB1.y + xv1.z*bc, wB1.x + xv1.w*bc);
        }
        if (pp == 0) __syncthreads();   // protect lds before next pair's staging
    }
}

extern "C" void kernel_launch(void* const* d_in, const int* in_sizes, int n_in,
                              void* d_out, int out_size, void* d_ws, size_t ws_size,
                              hipStream_t stream) {
    const float* x      = (const float*)d_in[0];
    const float* z      = (const float*)d_in[2];
    const float* t      = (const float*)d_in[3];
    const float* deltas = (const float*)d_in[4];
    const float* freq   = (const float*)d_in[5];
    const float* W0     = (const float*)d_in[6];
    const float* b0     = (const float*)d_in[7];
    const float* W1     = (const float*)d_in[8];
    const float* b1     = (const float*)d_in[9];
    const float* W2     = (const float*)d_in[10];
    const float* b2     = (const float*)d_in[11];
    const float* W3     = (const float*)d_in[12];
    const float* b3     = (const float*)d_in[13];
    const float* bias   = (const float*)d_in[14];
    float* out = (float*)d_out;
    float* ws  = (float*)d_ws;
    float* H   = ws + OFF_H;
    float* Kf  = ws + OFF_KF;

    hipLaunchKernelGGL(k_pre, dim3(17), dim3(512), 0, stream, z, freq, W0, b0, W1, b1, W2, b2, ws, H);
    hipLaunchKernelGGL(k_filter, dim3(NCH/2), dim3(NT), 0, stream, H, t, deltas, W3, b3, ws, Kf);
    hipLaunchKernelGGL(k_main, dim3(NBATCH * NCH / 4), dim3(NT), 0, stream, x, ws, Kf, bias, out);
}

// Round 10
// 659.139 us; speedup vs baseline: 1.5635x; 1.0196x over previous
//
#include <hip/hip_runtime.h>
#include <math.h>

// HyenaFilter: y = irfft(rfft(x,2L) * rfft(k,2L))[..., :L] + x*bias
// Register-blocked mixed-radix [16,16,16,2] FFT. Round-10 revision:
//  - R9 post-mortem: fused dual-buffer passes (q0[16]+q1[16] live together)
//    hit the 128-VGPR quantum and spilled (WRITE 196->310 MB), cancelling the
//    barrier-halving win. This round keeps R9's SCHEDULE (7 barriers per 2
//    rows, shared kv/W loads, paired staging/epilogue) but runs the two
//    buffers SEQUENTIALLY within each interval with a memory fence between:
//    register peak = single-pass (~104, R8-proven, no spill), barrier count
//    still halved. Clean test of barrier-convoy amortization.
//  - keeps: LDS twiddle tables, folded XOR-swizzle, wave-local B<->C sync,
//    fused r2+spectral quad, pruned first fwd pass, shared-H k_filter staging,
//    x re-read epilogue, merged k_pre.

#define LSEQ 8192
#define NCH 768
#define NBATCH 8
#define NT 512            // threads per block

// ws layout (float offsets)
#define OFF_TWB  0        // 32 rows x 16 float2 : W16384^{32*q*m}   (pass B; pass-A high = rows 2b)
#define OFF_TW16 1024     // 2049 float2         : W16384^k, k<=2048
#define OFF_TL   5124     // 32 rows x 16 float2 : W16384^{2*a*m}    (pass A low)
#define OFF_TWC  6660     // 2 rows x 16 float2  : W16384^{512*p*m}  (pass C)
#define OFF_H    10240    // 8192 x 16 floats (MLP features, row-major)
#define OFF_KF   141312   // 768 x 4096 float4 (S~, D~ per bin pair)

__device__ __forceinline__ float2 cadd(float2 a, float2 b){ return make_float2(a.x+b.x, a.y+b.y); }
__device__ __forceinline__ float2 csub(float2 a, float2 b){ return make_float2(a.x-b.x, a.y-b.y); }
__device__ __forceinline__ float2 cmul(float2 a, float2 b){ return make_float2(a.x*b.x - a.y*b.y, a.x*b.y + a.y*b.x); }
__device__ __forceinline__ float2 mni(float2 a){ return make_float2(a.y, -a.x); }  // * -i

// wave-local LDS producer->consumer sync (exchange confined to one wave)
__device__ __forceinline__ void wave_sync(){
    asm volatile("s_waitcnt lgkmcnt(0)" ::: "memory");
}
// scheduling fence: keeps the two sequential buffer-passes from being fused
// back into one fat register region (R9's spill mechanism)
__device__ __forceinline__ void fence(){
    asm volatile("" ::: "memory");
}

// generic swizzle (used only in the spectral stage)
__device__ __forceinline__ int IDX(int i){ return i ^ (((i>>4) ^ (i>>8)) & 15); }
// digit-reversal: bin k -> slot after DIF passes [16(512),16(32),16(2)] (pre-r2, slot even)
__device__ __forceinline__ int drev(int k){
    return ((k & 15) << 9) | (((k >> 4) & 15) << 5) | (((k >> 8) & 15) << 1) | (k >> 12);
}

#define C1 0.923879532511286756f
#define S1 0.382683432365089772f
#define R2 0.707106781186547524f

// natural-in DFT-16; output bin m in q[rv[m]]. FULL=false: inputs 8..15 are
// pre-duplicated copies of 0..7 (zero upper half), stage-1 add/sub skipped.
template<bool FULL>
__device__ __forceinline__ void dft16(float2 q[16]) {
    if constexpr (FULL) {
#pragma unroll
        for (int j = 0; j < 8; ++j) { float2 u=q[j], v=q[j+8]; q[j]=cadd(u,v); q[j+8]=csub(u,v); }
    }
    q[9]  = cmul(q[9],  make_float2( C1,-S1));
    q[10] = cmul(q[10], make_float2( R2,-R2));
    q[11] = cmul(q[11], make_float2( S1,-C1));
    q[12] = mni(q[12]);
    q[13] = cmul(q[13], make_float2(-S1,-C1));
    q[14] = cmul(q[14], make_float2(-R2,-R2));
    q[15] = cmul(q[15], make_float2(-C1,-S1));
#pragma unroll
    for (int b = 0; b < 16; b += 8) {
#pragma unroll
        for (int j = 0; j < 4; ++j) { float2 u=q[b+j], v=q[b+j+4]; q[b+j]=cadd(u,v); q[b+j+4]=csub(u,v); }
        q[b+5] = cmul(q[b+5], make_float2( R2,-R2));
        q[b+6] = mni(q[b+6]);
        q[b+7] = cmul(q[b+7], make_float2(-R2,-R2));
    }
#pragma unroll
    for (int b = 0; b < 16; b += 4) {
        float2 u0=q[b], v0=q[b+2], u1=q[b+1], v1=q[b+3];
        q[b]=cadd(u0,v0); q[b+2]=csub(u0,v0);
        q[b+1]=cadd(u1,v1); q[b+3]=mni(csub(u1,v1));
    }
#pragma unroll
    for (int b = 0; b < 16; b += 2) { float2 u=q[b], v=q[b+1]; q[b]=cadd(u,v); q[b+1]=csub(u,v); }
}

// Hand-folded swizzled addressing: IDX(base+p+r*L) == (sb ^ C_r) + (r*L).
template<int PASS>
__device__ __forceinline__ int psb(int t) {
    if constexpr (PASS == 0) {               // L=512, p=t
        return t ^ (((t>>4) ^ (t>>8)) & 15);
    } else if constexpr (PASS == 1) {        // L=32, base=(t>>5)<<9, p=t&31
        int p = t & 31, hb = t >> 5;
        return ((hb<<9) | p) ^ (((p>>4) ^ (hb<<1)) & 15);
    } else {                                 // L=2, base=(t>>1)<<5, p=t&1
        int h = t >> 1;
        return ((h<<5) | (t&1)) ^ (((h<<1) ^ (h>>3)) & 15);
    }
}
template<int PASS>
__device__ __forceinline__ int paddr(int sb, int r) {
    if constexpr (PASS == 0)      return (sb ^ (2*(r&7))) + (r<<9);
    else if constexpr (PASS == 1) return (sb ^ ((2*(r&7)) ^ (r>>3))) + (r<<5);
    else                          return sb ^ ((r<<1) ^ (r>>3));
}

// One radix-16 pass (single buffer — R8-proven register footprint ~104).
// twT[m][row]: row<32 TWB, 32+a TL, 64+c TWC.
// Pass A twiddle W8192^{pm} = TL[p&31][m] * TWB[2*(p>>5)][m].
template<int PASS, bool DIT, bool PRUNED>
__device__ __forceinline__ void r16p(float2* lds, const float2 (*twT)[68], int t) {
    static constexpr int RV[16] = {0,8,4,12,2,10,6,14,1,9,5,13,3,11,7,15};
    const int sb = psb<PASS>(t);
    int rL, rH = 0;
    if constexpr (PASS == 0) { rL = 32 + (t & 31); rH = (t >> 5) << 1; }
    else if constexpr (PASS == 1) { rL = t & 31; }
    else { rL = 64 + (t & 1); }
    float2 q[16];
    if constexpr (PRUNED) {
#pragma unroll
        for (int r = 0; r < 8; ++r) { q[r] = lds[paddr<PASS>(sb, r)]; q[r+8] = q[r]; }
    } else {
#pragma unroll
        for (int r = 0; r < 16; ++r) q[r] = lds[paddr<PASS>(sb, r)];
    }
    if constexpr (DIT) {
#pragma unroll
        for (int m = 1; m < 16; ++m) {
            float2 w = twT[m][rL];
            if constexpr (PASS == 0) w = cmul(w, twT[m][rH]);
            q[m] = cmul(q[m], w);
        }
        dft16<true>(q);
    } else {
        dft16<!PRUNED>(q);
#pragma unroll
        for (int m = 1; m < 16; ++m) {
            float2 w = twT[m][rL];
            if constexpr (PASS == 0) w = cmul(w, twT[m][rH]);
            q[RV[m]] = cmul(q[RV[m]], w);
        }
    }
#pragma unroll
    for (int m = 0; m < 16; ++m) lds[paddr<PASS>(sb, m)] = q[RV[m]];
}

// paired pass: two sequential single-buffer passes, one barrier interval
template<int PASS, bool DIT, bool PRUNED>
__device__ __forceinline__ void r16pp(float2* l0, float2* l1, const float2 (*twT)[68], int t) {
    r16p<PASS, DIT, PRUNED>(l0, twT, t);
    fence();
    r16p<PASS, DIT, PRUNED>(l1, twT, t);
}

// copy twiddle tables global -> LDS (transposed): 66 rows x 16 elems
__device__ __forceinline__ void load_twT(float2 (*twT)[68], const float* __restrict__ ws, int tid) {
    const float2* gTWB = (const float2*)(ws + OFF_TWB);
    const float2* gTL  = (const float2*)(ws + OFF_TL);
    const float2* gTWC = (const float2*)(ws + OFF_TWC);
    for (int idx = tid; idx < 16*66; idx += NT) {
        int r = idx >> 4, m = idx & 15;
        float2 v;
        if (r < 32)      v = gTWB[(r << 4) + m];
        else if (r < 64) v = gTL[((r - 32) << 4) + m];
        else             v = gTWC[((r - 64) << 4) + m];
        twT[m][r] = v;
    }
}

// spectral multiply for bin pair (k, 8192-k): o1/o2 are swapped v'[k], v'[8192-k]
__device__ __forceinline__ void specpair(float2 V1, float2 V2, float4 kv, float2 W,
                                         float2& o1, float2& o2) {
    float2 Eh = make_float2(V1.x + V2.x, V1.y - V2.y);
    float2 Oh = make_float2(V1.y + V2.y, V2.x - V1.x);
    float2 S = make_float2(kv.x, kv.y);
    float a = W.x*kv.z, b = W.y*kv.w, cc = W.x*kv.w, dd = W.y*kv.z;
    float2 T  = make_float2(a - b, cc + dd);
    float2 T2 = make_float2(a + b, cc - dd);
    float2 Ep = cadd(cmul(Eh, S), cmul(Oh, T));
    float2 Op = cadd(cmul(Eh, T2), cmul(Oh, S));
    o1 = make_float2(Ep.y + Op.x, Ep.x - Op.y);
    o2 = make_float2(Op.x - Ep.y, Ep.x + Op.y);
}

// fused fwd-r2 + spectral multiply + inverse-r2 for one buffer at quad (k,jj)
__device__ __forceinline__ void spec_rows(float2* l, int pA, int pB,
                                          float4 kvk, float4 kvj, float2 W, float2 Wj) {
    float2 uA = l[pA], vA = l[pA^1];
    float2 uB = l[pB], vB = l[pB^1];
    float2 Vk = cadd(uA, vA), Vk4 = csub(uA, vA);   // bins k, k+4096
    float2 Vj = cadd(uB, vB), Vj4 = csub(uB, vB);   // bins jj, 8192-k
    float2 r1, r2, r1j, r2j;
    specpair(Vk, Vj4, kvk, W,  r1,  r2);   // v'[k],  v'[8192-k]
    specpair(Vj, Vk4, kvj, Wj, r1j, r2j);  // v'[jj], v'[4096+k]
    l[pA]   = cadd(r1, r2j);  l[pA^1] = csub(r1, r2j);
    l[pB]   = cadd(r1j, r2);  l[pB^1] = csub(r1j, r2);
}

// bins 0 / 4096 special (tt==0)
__device__ __forceinline__ void spec_dc(float2* l, float4 kv) {
    float2 u = l[0], v = l[1];
    float2 V0 = cadd(u, v), VN = csub(u, v);
    float U0 = V0.x + V0.y, UL = V0.x - V0.y;
    float re = U0*kv.x + UL*kv.y;
    float im = U0*kv.x - UL*kv.y;
    float2 s0 = make_float2(im, re);
    float2 P = make_float2(VN.x*kv.z + VN.y*kv.w, VN.x*kv.w - VN.y*kv.z);
    float2 s1 = make_float2(-P.y, P.x);
    l[0] = cadd(s0, s1);
    l[1] = csub(s0, s1);
}

// filter spectral store for one channel at quad (k,jj)
__device__ __forceinline__ void filt_store(float2* l, float4* kf, int k, int jj,
                                           int pA, int pB, float2 W, float2 Wj, float sc) {
    float2 uA = l[pA], vA = l[pA^1];
    float2 uB = l[pB], vB = l[pB^1];
    float2 Vk = cadd(uA, vA), Vk4 = csub(uA, vA);
    float2 Vj = cadd(uB, vB), Vj4 = csub(uB, vB);
    {
        float2 E = make_float2(Vk.x + Vj4.x, Vk.y - Vj4.y);
        float2 O = make_float2(Vk.y + Vj4.y, Vj4.x - Vk.x);
        float2 D = cmul(W, O);
        kf[k] = make_float4(E.x*sc, E.y*sc, D.x*sc, D.y*sc);
    }
    {
        float2 E = make_float2(Vj.x + Vk4.x, Vj.y - Vk4.y);
        float2 O = make_float2(Vj.y + Vk4.y, Vk4.x - Vj.x);
        float2 D = cmul(Wj, O);
        kf[jj] = make_float4(E.x*sc, E.y*sc, D.x*sc, D.y*sc);
    }
}
__device__ __forceinline__ void filt_dc(float2* l, float4* kf) {
    float2 u = l[0], v = l[1];
    float2 V0 = cadd(u, v), VN = csub(u, v);
    kf[0] = make_float4((V0.x + V0.y)/16384.f, (V0.x - V0.y)/16384.f,
                        VN.x/8192.f, -VN.y/8192.f);
}

// merged init (block 0: twiddle tables via double-precision factor tables) + MLP (blocks 1..16)
__global__ __launch_bounds__(512) void k_pre(const float* __restrict__ z, const float* __restrict__ freq,
        const float* __restrict__ W0, const float* __restrict__ b0,
        const float* __restrict__ W1, const float* __restrict__ b1,
        const float* __restrict__ W2, const float* __restrict__ b2,
        float* __restrict__ ws, float* __restrict__ H) {
    __shared__ double2 lA[128], lB[128];
    const int t = threadIdx.x;
    if (blockIdx.x == 0) {
        const double K = -2.0 * 3.14159265358979323846 / 16384.0;
        if (t < 128)      { double a = K * (double)(t << 7); lA[t] = make_double2(cos(a), sin(a)); }
        else if (t < 256) { int b = t - 128; double a = K * (double)b; lB[b] = make_double2(cos(a), sin(a)); }
        __syncthreads();
        auto wf = [&](int e) -> float2 {
            e &= 16383;
            double2 A = lA[e >> 7], B = lB[e & 127];
            return make_float2((float)(A.x*B.x - A.y*B.y), (float)(A.x*B.y + A.y*B.x));
        };
        float2* tw16 = (float2*)(ws + OFF_TW16);
        for (int k = t; k <= 2048; k += 512) tw16[k] = wf(k);
        if (t < 32) {
            float2* rowL = (float2*)(ws + OFF_TL)  + (t << 4);
            float2* rowB = (float2*)(ws + OFF_TWB) + (t << 4);
#pragma unroll
            for (int m = 0; m < 16; ++m) { rowL[m] = wf(2*t*m); rowB[m] = wf(32*t*m); }
        } else if (t < 34) {
            int c2 = t - 32;
            float2* rowC = (float2*)(ws + OFF_TWC) + (c2 << 4);
#pragma unroll
            for (int m = 0; m < 16; ++m) rowC[m] = wf(512*c2*m);
        }
    } else {
        const int j = ((blockIdx.x - 1) << 9) + t;
        const float z0 = z[j*3+0], z1 = z[j*3+1], z2 = z[j*3+2];
        float h[16], g[16];
#pragma unroll
        for (int m = 0; m < 16; ++m)
            h[m] = sinf(freq[m] * (z0*W0[m] + z1*W0[16+m] + z2*W0[32+m] + b0[m]));
#pragma unroll
        for (int m = 0; m < 16; ++m) {
            float a = b1[m];
#pragma unroll
            for (int p = 0; p < 16; ++p) a += h[p] * W1[p*16+m];
            g[m] = sinf(freq[m] * a);
        }
#pragma unroll
        for (int m = 0; m < 16; ++m) {
            float a = b2[m];
#pragma unroll
            for (int p = 0; p < 16; ++p) a += g[p] * W2[p*16+m];
            h[m] = sinf(freq[m] * a);
        }
        float4* hp = (float4*)(H + (j << 4));   // row-major [8192][16]
        hp[0] = make_float4(h[0],  h[1],  h[2],  h[3]);
        hp[1] = make_float4(h[4],  h[5],  h[6],  h[7]);
        hp[2] = make_float4(h[8],  h[9],  h[10], h[11]);
        hp[3] = make_float4(h[12], h[13], h[14], h[15]);
    }
}

// TWO channels per block (shared H staging, sequential-paired passes):
// filter -> pruned fwd FFT -> fused(r2+unpack) -> store (S~,D~) for both.
__global__ __launch_bounds__(NT) void k_filter(const float* __restrict__ H, const float* __restrict__ t,
        const float* __restrict__ deltas, const float* __restrict__ W3,
        const float* __restrict__ b3, const float* __restrict__ ws,
        float* __restrict__ KfF) {
    __shared__ float2 lds2[2][LSEQ];
    __shared__ float2 twT[16][68];
    const int c0 = blockIdx.x << 1, c1 = c0 + 1;
    const int tid = threadIdx.x;
    float2* l0 = lds2[0];
    float2* l1 = lds2[1];
    load_twT(twT, ws, tid);
    float w30[16], w31[16];
#pragma unroll
    for (int m = 0; m < 16; ++m) { w30[m] = W3[m*NCH + c0]; w31[m] = W3[m*NCH + c1]; }
    const float b30 = b3[c0], b31 = b3[c1];
    const float ad0 = fabsf(deltas[c0]), ad1 = fabsf(deltas[c1]);
    const int sbA = psb<0>(tid);
#pragma unroll 1
    for (int j = 0; j < 8; ++j) {
        int n = tid + (j << 9);
        const float4* hp = (const float4*)(H + (n << 5));
        float sA0 = b30, sB0 = b30, sA1 = b31, sB1 = b31;   // A/B = the 2 time pts
#pragma unroll
        for (int q = 0; q < 4; ++q) {
            float4 a = hp[q];       // elems of point 2n
            float4 b = hp[4+q];     // elems of point 2n+1
            sA0 += a.x*w30[4*q] + a.y*w30[4*q+1] + a.z*w30[4*q+2] + a.w*w30[4*q+3];
            sB0 += b.x*w30[4*q] + b.y*w30[4*q+1] + b.z*w30[4*q+2] + b.w*w30[4*q+3];
            sA1 += a.x*w31[4*q] + a.y*w31[4*q+1] + a.z*w31[4*q+2] + a.w*w31[4*q+3];
            sB1 += b.x*w31[4*q] + b.y*w31[4*q+1] + b.z*w31[4*q+2] + b.w*w31[4*q+3];
        }
        float2 tv = ((const float2*)t)[n];
        int a0 = (sbA ^ (2*j)) + (j<<9);
        l0[a0] = make_float2(sA0 * expf(-tv.x*ad0), sB0 * expf(-tv.y*ad0));
        l1[a0] = make_float2(sA1 * expf(-tv.x*ad1), sB1 * expf(-tv.y*ad1));
    }
    __syncthreads();
    r16pp<0,false,true >(l0, l1, twT, tid); __syncthreads();
    r16pp<1,false,false>(l0, l1, twT, tid); wave_sync();
    r16pp<2,false,false>(l0, l1, twT, tid); __syncthreads();

    float4* kf0 = (float4*)KfF + (size_t)c0 * 4096;
    float4* kf1 = (float4*)KfF + (size_t)c1 * 4096;
    const float2* tw16 = (const float2*)(ws + OFF_TW16);
    const float sc = 1.0f / 32768.0f;
#pragma unroll 1
    for (int it = 0; it < 4; ++it) {
        int k  = tid + 1 + (it << 9);   // 1..2048
        int jj = 4096 - k;              // (k=2048: idempotent dup)
        int pA = IDX(drev(k)), pB = IDX(drev(jj));
        float2 W  = tw16[k];
        float2 Wj = make_float2(-W.y, -W.x);
        filt_store(l0, kf0, k, jj, pA, pB, W, Wj, sc);
        filt_store(l1, kf1, k, jj, pA, pB, W, Wj, sc);
    }
    if (tid == 0) { filt_dc(l0, kf0); filt_dc(l1, kf1); }
}

// Block = (channel c, batch-half): 4 rows as 2 pairs; sequential-paired passes
// (one barrier per pass-pair), kf4/tw16 loads shared across the pair.
__global__ __launch_bounds__(NT) void k_main(const float* __restrict__ x, const float* __restrict__ ws,
        const float* __restrict__ KfF, const float* __restrict__ bias,
        float* __restrict__ out) {
    __shared__ float2 lds2[2][LSEQ];
    __shared__ float2 twT[16][68];
    const int bid = blockIdx.x;                 // 0..1535
    const int c = bid >> 1, half = bid & 1;
    const int tt = threadIdx.x;
    float2* l0 = lds2[0];
    float2* l1 = lds2[1];
    const float4* kf4 = (const float4*)KfF + (size_t)c * 4096;
    const float2* tw16 = (const float2*)(ws + OFF_TW16);
    const size_t rowstride = (size_t)NCH * LSEQ;
    const float* xbase = x + (size_t)(half*4) * rowstride + (size_t)c * LSEQ;
    float* obase = out + (size_t)(half*4) * rowstride + (size_t)c * LSEQ;
    const float bc = bias[c];

    // staging addresses: IDX(2i) = (EB ^ (j<<2)) + (j<<10), IDX(2i+1) = that ^ 1
    const int EB = (tt << 1) ^ (((tt>>3) ^ (tt>>7)) & 15);

    load_twT(twT, ws, tt);

#pragma unroll 1
    for (int pp = 0; pp < 2; ++pp) {            // pair = rows (2pp, 2pp+1)
        const float4* xr0 = (const float4*)(xbase + (size_t)(2*pp)     * rowstride);
        const float4* xr1 = (const float4*)(xbase + (size_t)(2*pp + 1) * rowstride);
#pragma unroll
        for (int j = 0; j < 4; ++j) {
            float4 v0 = xr0[tt + (j<<9)];
            float4 v1 = xr1[tt + (j<<9)];
            int a0 = (EB ^ (j<<2)) + (j<<10);
            l0[a0]   = make_float2(v0.x, v0.y);
            l0[a0^1] = make_float2(v0.z, v0.w);
            l1[a0]   = make_float2(v1.x, v1.y);
            l1[a0^1] = make_float2(v1.z, v1.w);
        }
        __syncthreads();                              // also covers twT copy (pp==0)
        r16pp<0,false,true >(l0, l1, twT, tt); __syncthreads();
        r16pp<1,false,false>(l0, l1, twT, tt); wave_sync();
        r16pp<2,false,false>(l0, l1, twT, tt); __syncthreads();

        // fused fwd-r2 + spectral + inverse-r2 on both buffers; kf/tw shared
#pragma unroll 1
        for (int it = 0; it < 4; ++it) {
            int k  = tt + 1 + (it << 9);   // 1..2048
            int jj = 4096 - k;
            int pA = IDX(drev(k)), pB = IDX(drev(jj));
            float4 kvk = kf4[k], kvj = kf4[jj];
            float2 W  = tw16[k];
            float2 Wj = make_float2(-W.y, -W.x);
            spec_rows(l0, pA, pB, kvk, kvj, W, Wj);
            spec_rows(l1, pA, pB, kvk, kvj, W, Wj);
        }
        if (tt == 0) {
            float4 kv = kf4[0];
            spec_dc(l0, kv);
            spec_dc(l1, kv);
        }
        __syncthreads();

        r16pp<2,true,false>(l0, l1, twT, tt); wave_sync();
        r16pp<1,true,false>(l0, l1, twT, tt); __syncthreads();
        r16pp<0,true,false>(l0, l1, twT, tt); __syncthreads();

        float4* o0 = (float4*)(obase + (size_t)(2*pp)     * rowstride);
        float4* o1 = (float4*)(obase + (size_t)(2*pp + 1) * rowstride);
#pragma unroll
        for (int j = 0; j < 4; ++j) {
            int a0 = (EB ^ (j<<2)) + (j<<10);
            float2 wA0 = l0[a0], wB0 = l0[a0^1];
            float2 wA1 = l1[a0], wB1 = l1[a0^1];
            float4 xv0 = xr0[tt + (j<<9)];              // re-read (L2-resident)
            float4 xv1 = xr1[tt + (j<<9)];
            o0[tt + (j<<9)] = make_float4(wA0.y + xv0.x*bc, wA0.x + xv0.y*bc,
                                          wB0.y + xv0.z*bc, wB0.x + xv0.w*bc);
            o1[tt + (j<<9)] = make_float4(wA1.y + xv1.x*bc, wA1.x + xv1.y*bc,
                                          wB1.y + xv1.z*bc, wB1.x + xv1.w*bc);
        }
        if (pp == 0) __syncthreads();   // protect lds before next pair's staging
    }
}

extern "C" void kernel_launch(void* const* d_in, const int* in_sizes, int n_in,
                              void* d_out, int out_size, void* d_ws, size_t ws_size,
                              hipStream_t stream) {
    const float* x      = (const float*)d_in[0];
    const float* z      = (const float*)d_in[2];
    const float* t      = (const float*)d_in[3];
    const float* deltas = (const float*)d_in[4];
    const float* freq   = (const float*)d_in[5];
    const float* W0     = (const float*)d_in[6];
    const float* b0     = (const float*)d_in[7];
    const float* W1     = (const float*)d_in[8];
    const float* b1     = (const float*)d_in[9];
    const float* W2     = (const float*)d_in[10];
    const float* b2     = (const float*)d_in[11];
    const float* W3     = (const float*)d_in[12];
    const float* b3     = (const float*)d_in[13];
    const float* bias   = (const float*)d_in[14];
    float* out = (float*)d_out;
    float* ws  = (float*)d_ws;
    float* H   = ws + OFF_H;
    float* Kf  = ws + OFF_KF;

    hipLaunchKernelGGL(k_pre, dim3(17), dim3(512), 0, stream, z, freq, W0, b0, W1, b1, W2, b2, ws, H);
    hipLaunchKernelGGL(k_filter, dim3(NCH/2), dim3(NT), 0, stream, H, t, deltas, W3, b3, ws, Kf);
    hipLaunchKernelGGL(k_main, dim3(NBATCH * NCH / 4), dim3(NT), 0, stream, x, ws, Kf, bias, out);
}

// Round 11
// 646.676 us; speedup vs baseline: 1.5936x; 1.0193x over previous
//
#include <hip/hip_runtime.h>
#include <math.h>

// HyenaFilter: y = irfft(rfft(x,2L) * rfft(k,2L))[..., :L] + x*bias
// Register-blocked mixed-radix [16,16,16,2] FFT. Round-11 revision:
//  - BIAS FOLDED INTO THE FILTER SPECTRUM: y = irfft(X*(K + bc*delta0)) since
//    conv(x, delta0) = x exactly. delta0 lives in the even stream of the
//    packed-real representation: E += bc (O, D unchanged). Implemented as
//    kf.x += 2bc*sc in filt_store and +bc/16384, +bc/16384, +bc/8192 on the
//    (H[0], H[8192], H[4096]) components in filt_dc.
//    Deletes k_main's epilogue x re-read (-114 MB FETCH) + 16 FMA/thread/row,
//    and the epilogue's 4-float4 in-flight registers (R10's residual-spill margin).
//  - keeps R10 structure: sequential-paired passes (one barrier per pass-pair),
//    two-row LDS ping-pong, shared kv/W loads, LDS twiddle tables, folded
//    XOR-swizzle, wave-local B<->C sync, fused r2+spectral quad, pruned first
//    fwd pass, shared-H 2-channel k_filter, merged k_pre.

#define LSEQ 8192
#define NCH 768
#define NBATCH 8
#define NT 512            // threads per block

// ws layout (float offsets)
#define OFF_TWB  0        // 32 rows x 16 float2 : W16384^{32*q*m}   (pass B; pass-A high = rows 2b)
#define OFF_TW16 1024     // 2049 float2         : W16384^k, k<=2048
#define OFF_TL   5124     // 32 rows x 16 float2 : W16384^{2*a*m}    (pass A low)
#define OFF_TWC  6660     // 2 rows x 16 float2  : W16384^{512*p*m}  (pass C)
#define OFF_H    10240    // 8192 x 16 floats (MLP features, row-major)
#define OFF_KF   141312   // 768 x 4096 float4 (S~, D~ per bin pair)

__device__ __forceinline__ float2 cadd(float2 a, float2 b){ return make_float2(a.x+b.x, a.y+b.y); }
__device__ __forceinline__ float2 csub(float2 a, float2 b){ return make_float2(a.x-b.x, a.y-b.y); }
__device__ __forceinline__ float2 cmul(float2 a, float2 b){ return make_float2(a.x*b.x - a.y*b.y, a.x*b.y + a.y*b.x); }
__device__ __forceinline__ float2 mni(float2 a){ return make_float2(a.y, -a.x); }  // * -i

// wave-local LDS producer->consumer sync (exchange confined to one wave)
__device__ __forceinline__ void wave_sync(){
    asm volatile("s_waitcnt lgkmcnt(0)" ::: "memory");
}
// scheduling fence: keeps the two sequential buffer-passes from being fused
// back into one fat register region (R9's spill mechanism)
__device__ __forceinline__ void fence(){
    asm volatile("" ::: "memory");
}

// generic swizzle (used only in the spectral stage)
__device__ __forceinline__ int IDX(int i){ return i ^ (((i>>4) ^ (i>>8)) & 15); }
// digit-reversal: bin k -> slot after DIF passes [16(512),16(32),16(2)] (pre-r2, slot even)
__device__ __forceinline__ int drev(int k){
    return ((k & 15) << 9) | (((k >> 4) & 15) << 5) | (((k >> 8) & 15) << 1) | (k >> 12);
}

#define C1 0.923879532511286756f
#define S1 0.382683432365089772f
#define R2 0.707106781186547524f

// natural-in DFT-16; output bin m in q[rv[m]]. FULL=false: inputs 8..15 are
// pre-duplicated copies of 0..7 (zero upper half), stage-1 add/sub skipped.
template<bool FULL>
__device__ __forceinline__ void dft16(float2 q[16]) {
    if constexpr (FULL) {
#pragma unroll
        for (int j = 0; j < 8; ++j) { float2 u=q[j], v=q[j+8]; q[j]=cadd(u,v); q[j+8]=csub(u,v); }
    }
    q[9]  = cmul(q[9],  make_float2( C1,-S1));
    q[10] = cmul(q[10], make_float2( R2,-R2));
    q[11] = cmul(q[11], make_float2( S1,-C1));
    q[12] = mni(q[12]);
    q[13] = cmul(q[13], make_float2(-S1,-C1));
    q[14] = cmul(q[14], make_float2(-R2,-R2));
    q[15] = cmul(q[15], make_float2(-C1,-S1));
#pragma unroll
    for (int b = 0; b < 16; b += 8) {
#pragma unroll
        for (int j = 0; j < 4; ++j) { float2 u=q[b+j], v=q[b+j+4]; q[b+j]=cadd(u,v); q[b+j+4]=csub(u,v); }
        q[b+5] = cmul(q[b+5], make_float2( R2,-R2));
        q[b+6] = mni(q[b+6]);
        q[b+7] = cmul(q[b+7], make_float2(-R2,-R2));
    }
#pragma unroll
    for (int b = 0; b < 16; b += 4) {
        float2 u0=q[b], v0=q[b+2], u1=q[b+1], v1=q[b+3];
        q[b]=cadd(u0,v0); q[b+2]=csub(u0,v0);
        q[b+1]=cadd(u1,v1); q[b+3]=mni(csub(u1,v1));
    }
#pragma unroll
    for (int b = 0; b < 16; b += 2) { float2 u=q[b], v=q[b+1]; q[b]=cadd(u,v); q[b+1]=csub(u,v); }
}

// Hand-folded swizzled addressing: IDX(base+p+r*L) == (sb ^ C_r) + (r*L).
template<int PASS>
__device__ __forceinline__ int psb(int t) {
    if constexpr (PASS == 0) {               // L=512, p=t
        return t ^ (((t>>4) ^ (t>>8)) & 15);
    } else if constexpr (PASS == 1) {        // L=32, base=(t>>5)<<9, p=t&31
        int p = t & 31, hb = t >> 5;
        return ((hb<<9) | p) ^ (((p>>4) ^ (hb<<1)) & 15);
    } else {                                 // L=2, base=(t>>1)<<5, p=t&1
        int h = t >> 1;
        return ((h<<5) | (t&1)) ^ (((h<<1) ^ (h>>3)) & 15);
    }
}
template<int PASS>
__device__ __forceinline__ int paddr(int sb, int r) {
    if constexpr (PASS == 0)      return (sb ^ (2*(r&7))) + (r<<9);
    else if constexpr (PASS == 1) return (sb ^ ((2*(r&7)) ^ (r>>3))) + (r<<5);
    else                          return sb ^ ((r<<1) ^ (r>>3));
}

// One radix-16 pass (single buffer — R8-proven register footprint ~104).
// twT[m][row]: row<32 TWB, 32+a TL, 64+c TWC.
// Pass A twiddle W8192^{pm} = TL[p&31][m] * TWB[2*(p>>5)][m].
template<int PASS, bool DIT, bool PRUNED>
__device__ __forceinline__ void r16p(float2* lds, const float2 (*twT)[68], int t) {
    static constexpr int RV[16] = {0,8,4,12,2,10,6,14,1,9,5,13,3,11,7,15};
    const int sb = psb<PASS>(t);
    int rL, rH = 0;
    if constexpr (PASS == 0) { rL = 32 + (t & 31); rH = (t >> 5) << 1; }
    else if constexpr (PASS == 1) { rL = t & 31; }
    else { rL = 64 + (t & 1); }
    float2 q[16];
    if constexpr (PRUNED) {
#pragma unroll
        for (int r = 0; r < 8; ++r) { q[r] = lds[paddr<PASS>(sb, r)]; q[r+8] = q[r]; }
    } else {
#pragma unroll
        for (int r = 0; r < 16; ++r) q[r] = lds[paddr<PASS>(sb, r)];
    }
    if constexpr (DIT) {
#pragma unroll
        for (int m = 1; m < 16; ++m) {
            float2 w = twT[m][rL];
            if constexpr (PASS == 0) w = cmul(w, twT[m][rH]);
            q[m] = cmul(q[m], w);
        }
        dft16<true>(q);
    } else {
        dft16<!PRUNED>(q);
#pragma unroll
        for (int m = 1; m < 16; ++m) {
            float2 w = twT[m][rL];
            if constexpr (PASS == 0) w = cmul(w, twT[m][rH]);
            q[RV[m]] = cmul(q[RV[m]], w);
        }
    }
#pragma unroll
    for (int m = 0; m < 16; ++m) lds[paddr<PASS>(sb, m)] = q[RV[m]];
}

// paired pass: two sequential single-buffer passes, one barrier interval
template<int PASS, bool DIT, bool PRUNED>
__device__ __forceinline__ void r16pp(float2* l0, float2* l1, const float2 (*twT)[68], int t) {
    r16p<PASS, DIT, PRUNED>(l0, twT, t);
    fence();
    r16p<PASS, DIT, PRUNED>(l1, twT, t);
}

// copy twiddle tables global -> LDS (transposed): 66 rows x 16 elems
__device__ __forceinline__ void load_twT(float2 (*twT)[68], const float* __restrict__ ws, int tid) {
    const float2* gTWB = (const float2*)(ws + OFF_TWB);
    const float2* gTL  = (const float2*)(ws + OFF_TL);
    const float2* gTWC = (const float2*)(ws + OFF_TWC);
    for (int idx = tid; idx < 16*66; idx += NT) {
        int r = idx >> 4, m = idx & 15;
        float2 v;
        if (r < 32)      v = gTWB[(r << 4) + m];
        else if (r < 64) v = gTL[((r - 32) << 4) + m];
        else             v = gTWC[((r - 64) << 4) + m];
        twT[m][r] = v;
    }
}

// spectral multiply for bin pair (k, 8192-k): o1/o2 are swapped v'[k], v'[8192-k]
__device__ __forceinline__ void specpair(float2 V1, float2 V2, float4 kv, float2 W,
                                         float2& o1, float2& o2) {
    float2 Eh = make_float2(V1.x + V2.x, V1.y - V2.y);
    float2 Oh = make_float2(V1.y + V2.y, V2.x - V1.x);
    float2 S = make_float2(kv.x, kv.y);
    float a = W.x*kv.z, b = W.y*kv.w, cc = W.x*kv.w, dd = W.y*kv.z;
    float2 T  = make_float2(a - b, cc + dd);
    float2 T2 = make_float2(a + b, cc - dd);
    float2 Ep = cadd(cmul(Eh, S), cmul(Oh, T));
    float2 Op = cadd(cmul(Eh, T2), cmul(Oh, S));
    o1 = make_float2(Ep.y + Op.x, Ep.x - Op.y);
    o2 = make_float2(Op.x - Ep.y, Ep.x + Op.y);
}

// fused fwd-r2 + spectral multiply + inverse-r2 for one buffer at quad (k,jj)
__device__ __forceinline__ void spec_rows(float2* l, int pA, int pB,
                                          float4 kvk, float4 kvj, float2 W, float2 Wj) {
    float2 uA = l[pA], vA = l[pA^1];
    float2 uB = l[pB], vB = l[pB^1];
    float2 Vk = cadd(uA, vA), Vk4 = csub(uA, vA);   // bins k, k+4096
    float2 Vj = cadd(uB, vB), Vj4 = csub(uB, vB);   // bins jj, 8192-k
    float2 r1, r2, r1j, r2j;
    specpair(Vk, Vj4, kvk, W,  r1,  r2);   // v'[k],  v'[8192-k]
    specpair(Vj, Vk4, kvj, Wj, r1j, r2j);  // v'[jj], v'[4096+k]
    l[pA]   = cadd(r1, r2j);  l[pA^1] = csub(r1, r2j);
    l[pB]   = cadd(r1j, r2);  l[pB^1] = csub(r1j, r2);
}

// bins 0 / 4096 special (tt==0)
__device__ __forceinline__ void spec_dc(float2* l, float4 kv) {
    float2 u = l[0], v = l[1];
    float2 V0 = cadd(u, v), VN = csub(u, v);
    float U0 = V0.x + V0.y, UL = V0.x - V0.y;
    float re = U0*kv.x + UL*kv.y;
    float im = U0*kv.x - UL*kv.y;
    float2 s0 = make_float2(im, re);
    float2 P = make_float2(VN.x*kv.z + VN.y*kv.w, VN.x*kv.w - VN.y*kv.z);
    float2 s1 = make_float2(-P.y, P.x);
    l[0] = cadd(s0, s1);
    l[1] = csub(s0, s1);
}

// filter spectral store for one channel at quad (k,jj), bias folded:
// K += bc*delta0 => even-part E += bc (2bc on the doubled representation),
// odd part / D unchanged.
__device__ __forceinline__ void filt_store(float2* l, float4* kf, int k, int jj,
                                           int pA, int pB, float2 W, float2 Wj,
                                           float sc, float eb) {
    float2 uA = l[pA], vA = l[pA^1];
    float2 uB = l[pB], vB = l[pB^1];
    float2 Vk = cadd(uA, vA), Vk4 = csub(uA, vA);
    float2 Vj = cadd(uB, vB), Vj4 = csub(uB, vB);
    {
        float2 E = make_float2(Vk.x + Vj4.x + eb, Vk.y - Vj4.y);
        float2 O = make_float2(Vk.y + Vj4.y, Vj4.x - Vk.x);
        float2 D = cmul(W, O);
        kf[k] = make_float4(E.x*sc, E.y*sc, D.x*sc, D.y*sc);
    }
    {
        float2 E = make_float2(Vj.x + Vk4.x + eb, Vj.y - Vk4.y);
        float2 O = make_float2(Vj.y + Vk4.y, Vk4.x - Vj.x);
        float2 D = cmul(Wj, O);
        kf[jj] = make_float4(E.x*sc, E.y*sc, D.x*sc, D.y*sc);
    }
}
// DC store with bias fold: H[0]+=bc, H[8192]+=bc, H[4096]+=bc.
__device__ __forceinline__ void filt_dc(float2* l, float4* kf, float bc) {
    float2 u = l[0], v = l[1];
    float2 V0 = cadd(u, v), VN = csub(u, v);
    kf[0] = make_float4((V0.x + V0.y + bc)/16384.f, (V0.x - V0.y + bc)/16384.f,
                        (VN.x + bc)/8192.f, -VN.y/8192.f);
}

// merged init (block 0: twiddle tables via double-precision factor tables) + MLP (blocks 1..16)
__global__ __launch_bounds__(512) void k_pre(const float* __restrict__ z, const float* __restrict__ freq,
        const float* __restrict__ W0, const float* __restrict__ b0,
        const float* __restrict__ W1, const float* __restrict__ b1,
        const float* __restrict__ W2, const float* __restrict__ b2,
        float* __restrict__ ws, float* __restrict__ H) {
    __shared__ double2 lA[128], lB[128];
    const int t = threadIdx.x;
    if (blockIdx.x == 0) {
        const double K = -2.0 * 3.14159265358979323846 / 16384.0;
        if (t < 128)      { double a = K * (double)(t << 7); lA[t] = make_double2(cos(a), sin(a)); }
        else if (t < 256) { int b = t - 128; double a = K * (double)b; lB[b] = make_double2(cos(a), sin(a)); }
        __syncthreads();
        auto wf = [&](int e) -> float2 {
            e &= 16383;
            double2 A = lA[e >> 7], B = lB[e & 127];
            return make_float2((float)(A.x*B.x - A.y*B.y), (float)(A.x*B.y + A.y*B.x));
        };
        float2* tw16 = (float2*)(ws + OFF_TW16);
        for (int k = t; k <= 2048; k += 512) tw16[k] = wf(k);
        if (t < 32) {
            float2* rowL = (float2*)(ws + OFF_TL)  + (t << 4);
            float2* rowB = (float2*)(ws + OFF_TWB) + (t << 4);
#pragma unroll
            for (int m = 0; m < 16; ++m) { rowL[m] = wf(2*t*m); rowB[m] = wf(32*t*m); }
        } else if (t < 34) {
            int c2 = t - 32;
            float2* rowC = (float2*)(ws + OFF_TWC) + (c2 << 4);
#pragma unroll
            for (int m = 0; m < 16; ++m) rowC[m] = wf(512*c2*m);
        }
    } else {
        const int j = ((blockIdx.x - 1) << 9) + t;
        const float z0 = z[j*3+0], z1 = z[j*3+1], z2 = z[j*3+2];
        float h[16], g[16];
#pragma unroll
        for (int m = 0; m < 16; ++m)
            h[m] = sinf(freq[m] * (z0*W0[m] + z1*W0[16+m] + z2*W0[32+m] + b0[m]));
#pragma unroll
        for (int m = 0; m < 16; ++m) {
            float a = b1[m];
#pragma unroll
            for (int p = 0; p < 16; ++p) a += h[p] * W1[p*16+m];
            g[m] = sinf(freq[m] * a);
        }
#pragma unroll
        for (int m = 0; m < 16; ++m) {
            float a = b2[m];
#pragma unroll
            for (int p = 0; p < 16; ++p) a += g[p] * W2[p*16+m];
            h[m] = sinf(freq[m] * a);
        }
        float4* hp = (float4*)(H + (j << 4));   // row-major [8192][16]
        hp[0] = make_float4(h[0],  h[1],  h[2],  h[3]);
        hp[1] = make_float4(h[4],  h[5],  h[6],  h[7]);
        hp[2] = make_float4(h[8],  h[9],  h[10], h[11]);
        hp[3] = make_float4(h[12], h[13], h[14], h[15]);
    }
}

// TWO channels per block (shared H staging, sequential-paired passes):
// filter -> pruned fwd FFT -> fused(r2+unpack) -> store (S~,D~) with bias fold.
__global__ __launch_bounds__(NT) void k_filter(const float* __restrict__ H, const float* __restrict__ t,
        const float* __restrict__ deltas, const float* __restrict__ W3,
        const float* __restrict__ b3, const float* __restrict__ bias,
        const float* __restrict__ ws, float* __restrict__ KfF) {
    __shared__ float2 lds2[2][LSEQ];
    __shared__ float2 twT[16][68];
    const int c0 = blockIdx.x << 1, c1 = c0 + 1;
    const int tid = threadIdx.x;
    float2* l0 = lds2[0];
    float2* l1 = lds2[1];
    load_twT(twT, ws, tid);
    float w30[16], w31[16];
#pragma unroll
    for (int m = 0; m < 16; ++m) { w30[m] = W3[m*NCH + c0]; w31[m] = W3[m*NCH + c1]; }
    const float b30 = b3[c0], b31 = b3[c1];
    const float ad0 = fabsf(deltas[c0]), ad1 = fabsf(deltas[c1]);
    const float bc0 = bias[c0], bc1 = bias[c1];
    const int sbA = psb<0>(tid);
#pragma unroll 1
    for (int j = 0; j < 8; ++j) {
        int n = tid + (j << 9);
        const float4* hp = (const float4*)(H + (n << 5));
        float sA0 = b30, sB0 = b30, sA1 = b31, sB1 = b31;   // A/B = the 2 time pts
#pragma unroll
        for (int q = 0; q < 4; ++q) {
            float4 a = hp[q];       // elems of point 2n
            float4 b = hp[4+q];     // elems of point 2n+1
            sA0 += a.x*w30[4*q] + a.y*w30[4*q+1] + a.z*w30[4*q+2] + a.w*w30[4*q+3];
            sB0 += b.x*w30[4*q] + b.y*w30[4*q+1] + b.z*w30[4*q+2] + b.w*w30[4*q+3];
            sA1 += a.x*w31[4*q] + a.y*w31[4*q+1] + a.z*w31[4*q+2] + a.w*w31[4*q+3];
            sB1 += b.x*w31[4*q] + b.y*w31[4*q+1] + b.z*w31[4*q+2] + b.w*w31[4*q+3];
        }
        float2 tv = ((const float2*)t)[n];
        int a0 = (sbA ^ (2*j)) + (j<<9);
        l0[a0] = make_float2(sA0 * expf(-tv.x*ad0), sB0 * expf(-tv.y*ad0));
        l1[a0] = make_float2(sA1 * expf(-tv.x*ad1), sB1 * expf(-tv.y*ad1));
    }
    __syncthreads();
    r16pp<0,false,true >(l0, l1, twT, tid); __syncthreads();
    r16pp<1,false,false>(l0, l1, twT, tid); wave_sync();
    r16pp<2,false,false>(l0, l1, twT, tid); __syncthreads();

    float4* kf0 = (float4*)KfF + (size_t)c0 * 4096;
    float4* kf1 = (float4*)KfF + (size_t)c1 * 4096;
    const float2* tw16 = (const float2*)(ws + OFF_TW16);
    const float sc = 1.0f / 32768.0f;
#pragma unroll 1
    for (int it = 0; it < 4; ++it) {
        int k  = tid + 1 + (it << 9);   // 1..2048
        int jj = 4096 - k;              // (k=2048: idempotent dup)
        int pA = IDX(drev(k)), pB = IDX(drev(jj));
        float2 W  = tw16[k];
        float2 Wj = make_float2(-W.y, -W.x);
        filt_store(l0, kf0, k, jj, pA, pB, W, Wj, sc, 2.0f*bc0);
        filt_store(l1, kf1, k, jj, pA, pB, W, Wj, sc, 2.0f*bc1);
    }
    if (tid == 0) { filt_dc(l0, kf0, bc0); filt_dc(l1, kf1, bc1); }
}

// Block = (channel c, batch-half): 4 rows as 2 pairs; sequential-paired passes
// (one barrier per pass-pair), kf4/tw16 loads shared across the pair.
// Bias is folded into Kf, so no x re-read and no epilogue FMA.
__global__ __launch_bounds__(NT) void k_main(const float* __restrict__ x, const float* __restrict__ ws,
        const float* __restrict__ KfF, float* __restrict__ out) {
    __shared__ float2 lds2[2][LSEQ];
    __shared__ float2 twT[16][68];
    const int bid = blockIdx.x;                 // 0..1535
    const int c = bid >> 1, half = bid & 1;
    const int tt = threadIdx.x;
    float2* l0 = lds2[0];
    float2* l1 = lds2[1];
    const float4* kf4 = (const float4*)KfF + (size_t)c * 4096;
    const float2* tw16 = (const float2*)(ws + OFF_TW16);
    const size_t rowstride = (size_t)NCH * LSEQ;
    const float* xbase = x + (size_t)(half*4) * rowstride + (size_t)c * LSEQ;
    float* obase = out + (size_t)(half*4) * rowstride + (size_t)c * LSEQ;

    // staging addresses: IDX(2i) = (EB ^ (j<<2)) + (j<<10), IDX(2i+1) = that ^ 1
    const int EB = (tt << 1) ^ (((tt>>3) ^ (tt>>7)) & 15);

    load_twT(twT, ws, tt);

#pragma unroll 1
    for (int pp = 0; pp < 2; ++pp) {            // pair = rows (2pp, 2pp+1)
        const float4* xr0 = (const float4*)(xbase + (size_t)(2*pp)     * rowstride);
        const float4* xr1 = (const float4*)(xbase + (size_t)(2*pp + 1) * rowstride);
#pragma unroll
        for (int j = 0; j < 4; ++j) {
            float4 v0 = xr0[tt + (j<<9)];
            float4 v1 = xr1[tt + (j<<9)];
            int a0 = (EB ^ (j<<2)) + (j<<10);
            l0[a0]   = make_float2(v0.x, v0.y);
            l0[a0^1] = make_float2(v0.z, v0.w);
            l1[a0]   = make_float2(v1.x, v1.y);
            l1[a0^1] = make_float2(v1.z, v1.w);
        }
        __syncthreads();                              // also covers twT copy (pp==0)
        r16pp<0,false,true >(l0, l1, twT, tt); __syncthreads();
        r16pp<1,false,false>(l0, l1, twT, tt); wave_sync();
        r16pp<2,false,false>(l0, l1, twT, tt); __syncthreads();

        // fused fwd-r2 + spectral + inverse-r2 on both buffers; kf/tw shared
#pragma unroll 1
        for (int it = 0; it < 4; ++it) {
            int k  = tt + 1 + (it << 9);   // 1..2048
            int jj = 4096 - k;
            int pA = IDX(drev(k)), pB = IDX(drev(jj));
            float4 kvk = kf4[k], kvj = kf4[jj];
            float2 W  = tw16[k];
            float2 Wj = make_float2(-W.y, -W.x);
            spec_rows(l0, pA, pB, kvk, kvj, W, Wj);
            spec_rows(l1, pA, pB, kvk, kvj, W, Wj);
        }
        if (tt == 0) {
            float4 kv = kf4[0];
            spec_dc(l0, kv);
            spec_dc(l1, kv);
        }
        __syncthreads();

        r16pp<2,true,false>(l0, l1, twT, tt); wave_sync();
        r16pp<1,true,false>(l0, l1, twT, tt); __syncthreads();
        r16pp<0,true,false>(l0, l1, twT, tt); __syncthreads();

        float4* o0 = (float4*)(obase + (size_t)(2*pp)     * rowstride);
        float4* o1 = (float4*)(obase + (size_t)(2*pp + 1) * rowstride);
#pragma unroll
        for (int j = 0; j < 4; ++j) {
            int a0 = (EB ^ (j<<2)) + (j<<10);
            float2 wA0 = l0[a0], wB0 = l0[a0^1];
            float2 wA1 = l1[a0], wB1 = l1[a0^1];
            o0[tt + (j<<9)] = make_float4(wA0.y, wA0.x, wB0.y, wB0.x);
            o1[tt + (j<<9)] = make_float4(wA1.y, wA1.x, wB1.y, wB1.x);
        }
        if (pp == 0) __syncthreads();   // protect lds before next pair's staging
    }
}

extern "C" void kernel_launch(void* const* d_in, const int* in_sizes, int n_in,
                              void* d_out, int out_size, void* d_ws, size_t ws_size,
                              hipStream_t stream) {
    const float* x      = (const float*)d_in[0];
    const float* z      = (const float*)d_in[2];
    const float* t      = (const float*)d_in[3];
    const float* deltas = (const float*)d_in[4];
    const float* freq   = (const float*)d_in[5];
    const float* W0     = (const float*)d_in[6];
    const float* b0     = (const float*)d_in[7];
    const float* W1     = (const float*)d_in[8];
    const float* b1     = (const float*)d_in[9];
    const float* W2     = (const float*)d_in[10];
    const float* b2     = (const float*)d_in[11];
    const float* W3     = (const float*)d_in[12];
    const float* b3     = (const float*)d_in[13];
    const float* bias   = (const float*)d_in[14];
    float* out = (float*)d_out;
    float* ws  = (float*)d_ws;
    float* H   = ws + OFF_H;
    float* Kf  = ws + OFF_KF;

    hipLaunchKernelGGL(k_pre, dim3(17), dim3(512), 0, stream, z, freq, W0, b0, W1, b1, W2, b2, ws, H);
    hipLaunchKernelGGL(k_filter, dim3(NCH/2), dim3(NT), 0, stream, H, t, deltas, W3, b3, bias, ws, Kf);
    hipLaunchKernelGGL(k_main, dim3(NBATCH * NCH / 4), dim3(NT), 0, stream, x, ws, Kf, out);
}

// Round 12
// 607.913 us; speedup vs baseline: 1.6952x; 1.0638x over previous
//
#include <hip/hip_runtime.h>
#include <math.h>

// HyenaFilter: y = irfft(rfft(x,2L) * rfft(k,2L))[..., :L] + x*bias
// Register-blocked mixed-radix [16,16,16,2] FFT. Round-12 revision:
//  - PACKED F32 MATH: complex type is now ext_vector_type(2) float, so
//    cadd/csub compile to v_pk_add_f32 and cmul to pk_mul+pk_fma (gfx90a+
//    VOP3P). ~30-40% fewer VALU issues in the butterfly-dominated passes.
//  - SWIZZLE MASK &15 -> &14 (bit0 preserved): every r2/spectral/staging/
//    epilogue pair {2m,2m+1} is now an aligned, fixed-order float4 slot ->
//    ds_read/write_b128 in those stages (staging 2->1, spectral 8->4 per
//    quad/buffer, epilogue 2->1). Folded constants re-derived and verified:
//    psb* use &14; paddr<1> drops ^(r>>3); paddr<2> = sb^(r<<1).
//  - keeps R11 structure: bias folded into Kf, sequential-paired passes,
//    two-row LDS ping-pong, shared kv/W loads, LDS twiddle tables,
//    wave-local B<->C sync, pruned first fwd pass, merged k_pre.

#define LSEQ 8192
#define NCH 768
#define NBATCH 8
#define NT 512            // threads per block

// ws layout (float offsets)
#define OFF_TWB  0        // 32 rows x 16 cplx : W16384^{32*q*m}   (pass B; pass-A high = rows 2b)
#define OFF_TW16 1024     // 2049 cplx         : W16384^k, k<=2048
#define OFF_TL   5124     // 32 rows x 16 cplx : W16384^{2*a*m}    (pass A low)
#define OFF_TWC  6660     // 2 rows x 16 cplx  : W16384^{512*p*m}  (pass C)
#define OFF_H    10240    // 8192 x 16 floats (MLP features, row-major)
#define OFF_KF   141312   // 768 x 4096 float4 (S~, D~ per bin pair)

typedef float cplx __attribute__((ext_vector_type(2)));

__device__ __forceinline__ cplx cadd(cplx a, cplx b){ return a + b; }
__device__ __forceinline__ cplx csub(cplx a, cplx b){ return a - b; }
__device__ __forceinline__ cplx cmul(cplx a, cplx b){
    return cplx{a.x, a.x} * b + cplx{a.y, a.y} * cplx{-b.y, b.x};
}
__device__ __forceinline__ cplx mni(cplx a){ return cplx{a.y, -a.x}; }  // * -i

// wave-local LDS producer->consumer sync (exchange confined to one wave)
__device__ __forceinline__ void wave_sync(){
    asm volatile("s_waitcnt lgkmcnt(0)" ::: "memory");
}
// scheduling fence between the two sequential buffer-passes (R9 spill fix)
__device__ __forceinline__ void fence(){
    asm volatile("" ::: "memory");
}

// bit0-preserving swizzle (mask &14): pairs {2m,2m+1} stay adjacent, fixed order
__device__ __forceinline__ int IDX14(int i){ return i ^ (((i>>4) ^ (i>>8)) & 14); }
// digit-reversal: bin k -> slot after DIF passes [16(512),16(32),16(2)] (pre-r2, slot even)
__device__ __forceinline__ int drev(int k){
    return ((k & 15) << 9) | (((k >> 4) & 15) << 5) | (((k >> 8) & 15) << 1) | (k >> 12);
}

#define C1 0.923879532511286756f
#define S1 0.382683432365089772f
#define R2 0.707106781186547524f

// natural-in DFT-16; output bin m in q[rv[m]]. FULL=false: inputs 8..15 are
// pre-duplicated copies of 0..7 (zero upper half), stage-1 add/sub skipped.
template<bool FULL>
__device__ __forceinline__ void dft16(cplx q[16]) {
    if constexpr (FULL) {
#pragma unroll
        for (int j = 0; j < 8; ++j) { cplx u=q[j], v=q[j+8]; q[j]=u+v; q[j+8]=u-v; }
    }
    q[9]  = cmul(q[9],  cplx{ C1,-S1});
    q[10] = cmul(q[10], cplx{ R2,-R2});
    q[11] = cmul(q[11], cplx{ S1,-C1});
    q[12] = mni(q[12]);
    q[13] = cmul(q[13], cplx{-S1,-C1});
    q[14] = cmul(q[14], cplx{-R2,-R2});
    q[15] = cmul(q[15], cplx{-C1,-S1});
#pragma unroll
    for (int b = 0; b < 16; b += 8) {
#pragma unroll
        for (int j = 0; j < 4; ++j) { cplx u=q[b+j], v=q[b+j+4]; q[b+j]=u+v; q[b+j+4]=u-v; }
        q[b+5] = cmul(q[b+5], cplx{ R2,-R2});
        q[b+6] = mni(q[b+6]);
        q[b+7] = cmul(q[b+7], cplx{-R2,-R2});
    }
#pragma unroll
    for (int b = 0; b < 16; b += 4) {
        cplx u0=q[b], v0=q[b+2], u1=q[b+1], v1=q[b+3];
        q[b]=u0+v0; q[b+2]=u0-v0;
        q[b+1]=u1+v1; q[b+3]=mni(u1-v1);
    }
#pragma unroll
    for (int b = 0; b < 16; b += 2) { cplx u=q[b], v=q[b+1]; q[b]=u+v; q[b+1]=u-v; }
}

// Hand-folded swizzled addressing for mask &14: IDX14(base+p+r*L) == (sb ^ C_r) + (r*L).
// (Verified numerically against IDX14 for samples in each pass.)
template<int PASS>
__device__ __forceinline__ int psb(int t) {
    if constexpr (PASS == 0) {               // L=512, p=t
        return t ^ (((t>>4) ^ (t>>8)) & 14);
    } else if constexpr (PASS == 1) {        // L=32, base=(t>>5)<<9, p=t&31
        int p = t & 31, hb = t >> 5;
        return ((hb<<9) | p) ^ (((p>>4) ^ (hb<<1)) & 14);
    } else {                                 // L=2, base=(t>>1)<<5, p=t&1
        int h = t >> 1;
        return ((h<<5) | (t&1)) ^ (((h<<1) ^ (h>>3)) & 14);
    }
}
template<int PASS>
__device__ __forceinline__ int paddr(int sb, int r) {
    if constexpr (PASS == 0)      return (sb ^ (2*(r&7))) + (r<<9);
    else if constexpr (PASS == 1) return (sb ^ (2*(r&7))) + (r<<5);
    else                          return sb ^ (r<<1);
}

// One radix-16 pass (single buffer). twT[m][row]: row<32 TWB, 32+a TL, 64+c TWC.
// Pass A twiddle W8192^{pm} = TL[p&31][m] * TWB[2*(p>>5)][m].
template<int PASS, bool DIT, bool PRUNED>
__device__ __forceinline__ void r16p(cplx* lds, const cplx (*twT)[68], int t) {
    static constexpr int RV[16] = {0,8,4,12,2,10,6,14,1,9,5,13,3,11,7,15};
    const int sb = psb<PASS>(t);
    int rL, rH = 0;
    if constexpr (PASS == 0) { rL = 32 + (t & 31); rH = (t >> 5) << 1; }
    else if constexpr (PASS == 1) { rL = t & 31; }
    else { rL = 64 + (t & 1); }
    cplx q[16];
    if constexpr (PRUNED) {
#pragma unroll
        for (int r = 0; r < 8; ++r) { q[r] = lds[paddr<PASS>(sb, r)]; q[r+8] = q[r]; }
    } else {
#pragma unroll
        for (int r = 0; r < 16; ++r) q[r] = lds[paddr<PASS>(sb, r)];
    }
    if constexpr (DIT) {
#pragma unroll
        for (int m = 1; m < 16; ++m) {
            cplx w = twT[m][rL];
            if constexpr (PASS == 0) w = cmul(w, twT[m][rH]);
            q[m] = cmul(q[m], w);
        }
        dft16<true>(q);
    } else {
        dft16<!PRUNED>(q);
#pragma unroll
        for (int m = 1; m < 16; ++m) {
            cplx w = twT[m][rL];
            if constexpr (PASS == 0) w = cmul(w, twT[m][rH]);
            q[RV[m]] = cmul(q[RV[m]], w);
        }
    }
#pragma unroll
    for (int m = 0; m < 16; ++m) lds[paddr<PASS>(sb, m)] = q[RV[m]];
}

// paired pass: two sequential single-buffer passes, one barrier interval
template<int PASS, bool DIT, bool PRUNED>
__device__ __forceinline__ void r16pp(cplx* l0, cplx* l1, const cplx (*twT)[68], int t) {
    r16p<PASS, DIT, PRUNED>(l0, twT, t);
    fence();
    r16p<PASS, DIT, PRUNED>(l1, twT, t);
}

// copy twiddle tables global -> LDS (transposed): 66 rows x 16 elems
__device__ __forceinline__ void load_twT(cplx (*twT)[68], const float* __restrict__ ws, int tid) {
    const cplx* gTWB = (const cplx*)(ws + OFF_TWB);
    const cplx* gTL  = (const cplx*)(ws + OFF_TL);
    const cplx* gTWC = (const cplx*)(ws + OFF_TWC);
    for (int idx = tid; idx < 16*66; idx += NT) {
        int r = idx >> 4, m = idx & 15;
        cplx v;
        if (r < 32)      v = gTWB[(r << 4) + m];
        else if (r < 64) v = gTL[((r - 32) << 4) + m];
        else             v = gTWC[((r - 64) << 4) + m];
        twT[m][r] = v;
    }
}

// spectral multiply for bin pair (k, 8192-k): o1/o2 are swapped v'[k], v'[8192-k]
__device__ __forceinline__ void specpair(cplx V1, cplx V2, float4 kv, cplx W,
                                         cplx& o1, cplx& o2) {
    cplx Eh = V1 + cplx{V2.x, -V2.y};
    cplx Oh = cplx{V1.y + V2.y, V2.x - V1.x};
    cplx S = cplx{kv.x, kv.y};
    float a = W.x*kv.z, b = W.y*kv.w, cc = W.x*kv.w, dd = W.y*kv.z;
    cplx T  = cplx{a - b, cc + dd};
    cplx T2 = cplx{a + b, cc - dd};
    cplx Ep = cmul(Eh, S) + cmul(Oh, T);
    cplx Op = cmul(Eh, T2) + cmul(Oh, S);
    o1 = cplx{Ep.y + Op.x, Ep.x - Op.y};
    o2 = cplx{Op.x - Ep.y, Ep.x + Op.y};
}

// fused fwd-r2 + spectral multiply + inverse-r2 for one buffer at slot pair
// (sA = IDX14(drev(k))>>1, sB = IDX14(drev(jj))>>1) — b128 read/write per slot.
__device__ __forceinline__ void spec_rows(float4* l4, int sA, int sB,
                                          float4 kvk, float4 kvj, cplx W, cplx Wj) {
    float4 fA = l4[sA], fB = l4[sB];
    cplx uA = {fA.x, fA.y}, vA = {fA.z, fA.w};
    cplx uB = {fB.x, fB.y}, vB = {fB.z, fB.w};
    cplx Vk = uA + vA, Vk4 = uA - vA;   // bins k, k+4096
    cplx Vj = uB + vB, Vj4 = uB - vB;   // bins jj, 8192-k
    cplx r1, r2, r1j, r2j;
    specpair(Vk, Vj4, kvk, W,  r1,  r2);   // v'[k],  v'[8192-k]
    specpair(Vj, Vk4, kvj, Wj, r1j, r2j);  // v'[jj], v'[4096+k]
    cplx a0 = r1 + r2j, a1 = r1 - r2j;
    cplx b0 = r1j + r2, b1 = r1j - r2;
    l4[sA] = make_float4(a0.x, a0.y, a1.x, a1.y);
    l4[sB] = make_float4(b0.x, b0.y, b1.x, b1.y);
}

// bins 0 / 4096 special (tt==0); slots {0,1} = l4[0]
__device__ __forceinline__ void spec_dc(float4* l4, float4 kv) {
    float4 f = l4[0];
    cplx u = {f.x, f.y}, v = {f.z, f.w};
    cplx V0 = u + v, VN = u - v;
    float U0 = V0.x + V0.y, UL = V0.x - V0.y;
    float re = U0*kv.x + UL*kv.y;
    float im = U0*kv.x - UL*kv.y;
    cplx s0 = {im, re};
    cplx P = {VN.x*kv.z + VN.y*kv.w, VN.x*kv.w - VN.y*kv.z};
    cplx s1 = {-P.y, P.x};
    cplx a = s0 + s1, b = s0 - s1;
    l4[0] = make_float4(a.x, a.y, b.x, b.y);
}

// filter spectral store for one channel at quad (k,jj), bias folded (E += eb)
__device__ __forceinline__ void filt_store(const float4* l4, float4* kf, int k, int jj,
                                           int sA, int sB, cplx W, cplx Wj,
                                           float sc, float eb) {
    float4 fA = l4[sA], fB = l4[sB];
    cplx uA = {fA.x, fA.y}, vA = {fA.z, fA.w};
    cplx uB = {fB.x, fB.y}, vB = {fB.z, fB.w};
    cplx Vk = uA + vA, Vk4 = uA - vA;
    cplx Vj = uB + vB, Vj4 = uB - vB;
    {
        cplx E = {Vk.x + Vj4.x + eb, Vk.y - Vj4.y};
        cplx O = {Vk.y + Vj4.y, Vj4.x - Vk.x};
        cplx D = cmul(W, O);
        kf[k] = make_float4(E.x*sc, E.y*sc, D.x*sc, D.y*sc);
    }
    {
        cplx E = {Vj.x + Vk4.x + eb, Vj.y - Vk4.y};
        cplx O = {Vj.y + Vk4.y, Vk4.x - Vj.x};
        cplx D = cmul(Wj, O);
        kf[jj] = make_float4(E.x*sc, E.y*sc, D.x*sc, D.y*sc);
    }
}
// DC store with bias fold: H[0]+=bc, H[8192]+=bc, H[4096]+=bc.
__device__ __forceinline__ void filt_dc(const float4* l4, float4* kf, float bc) {
    float4 f = l4[0];
    cplx u = {f.x, f.y}, v = {f.z, f.w};
    cplx V0 = u + v, VN = u - v;
    kf[0] = make_float4((V0.x + V0.y + bc)/16384.f, (V0.x - V0.y + bc)/16384.f,
                        (VN.x + bc)/8192.f, -VN.y/8192.f);
}

// merged init (block 0: twiddle tables via double-precision factor tables) + MLP (blocks 1..16)
__global__ __launch_bounds__(512) void k_pre(const float* __restrict__ z, const float* __restrict__ freq,
        const float* __restrict__ W0, const float* __restrict__ b0,
        const float* __restrict__ W1, const float* __restrict__ b1,
        const float* __restrict__ W2, const float* __restrict__ b2,
        float* __restrict__ ws, float* __restrict__ H) {
    __shared__ double2 lA[128], lB[128];
    const int t = threadIdx.x;
    if (blockIdx.x == 0) {
        const double K = -2.0 * 3.14159265358979323846 / 16384.0;
        if (t < 128)      { double a = K * (double)(t << 7); lA[t] = make_double2(cos(a), sin(a)); }
        else if (t < 256) { int b = t - 128; double a = K * (double)b; lB[b] = make_double2(cos(a), sin(a)); }
        __syncthreads();
        auto wf = [&](int e) -> float2 {
            e &= 16383;
            double2 A = lA[e >> 7], B = lB[e & 127];
            return make_float2((float)(A.x*B.x - A.y*B.y), (float)(A.x*B.y + A.y*B.x));
        };
        float2* tw16 = (float2*)(ws + OFF_TW16);
        for (int k = t; k <= 2048; k += 512) tw16[k] = wf(k);
        if (t < 32) {
            float2* rowL = (float2*)(ws + OFF_TL)  + (t << 4);
            float2* rowB = (float2*)(ws + OFF_TWB) + (t << 4);
#pragma unroll
            for (int m = 0; m < 16; ++m) { rowL[m] = wf(2*t*m); rowB[m] = wf(32*t*m); }
        } else if (t < 34) {
            int c2 = t - 32;
            float2* rowC = (float2*)(ws + OFF_TWC) + (c2 << 4);
#pragma unroll
            for (int m = 0; m < 16; ++m) rowC[m] = wf(512*c2*m);
        }
    } else {
        const int j = ((blockIdx.x - 1) << 9) + t;
        const float z0 = z[j*3+0], z1 = z[j*3+1], z2 = z[j*3+2];
        float h[16], g[16];
#pragma unroll
        for (int m = 0; m < 16; ++m)
            h[m] = sinf(freq[m] * (z0*W0[m] + z1*W0[16+m] + z2*W0[32+m] + b0[m]));
#pragma unroll
        for (int m = 0; m < 16; ++m) {
            float a = b1[m];
#pragma unroll
            for (int p = 0; p < 16; ++p) a += h[p] * W1[p*16+m];
            g[m] = sinf(freq[m] * a);
        }
#pragma unroll
        for (int m = 0; m < 16; ++m) {
            float a = b2[m];
#pragma unroll
            for (int p = 0; p < 16; ++p) a += g[p] * W2[p*16+m];
            h[m] = sinf(freq[m] * a);
        }
        float4* hp = (float4*)(H + (j << 4));   // row-major [8192][16]
        hp[0] = make_float4(h[0],  h[1],  h[2],  h[3]);
        hp[1] = make_float4(h[4],  h[5],  h[6],  h[7]);
        hp[2] = make_float4(h[8],  h[9],  h[10], h[11]);
        hp[3] = make_float4(h[12], h[13], h[14], h[15]);
    }
}

// TWO channels per block (shared H staging, sequential-paired passes):
// filter -> pruned fwd FFT -> fused(r2+unpack) -> store (S~,D~) with bias fold.
__global__ __launch_bounds__(NT) void k_filter(const float* __restrict__ H, const float* __restrict__ t,
        const float* __restrict__ deltas, const float* __restrict__ W3,
        const float* __restrict__ b3, const float* __restrict__ bias,
        const float* __restrict__ ws, float* __restrict__ KfF) {
    __shared__ alignas(16) cplx lds2[2][LSEQ];
    __shared__ cplx twT[16][68];
    const int c0 = blockIdx.x << 1, c1 = c0 + 1;
    const int tid = threadIdx.x;
    cplx* l0 = lds2[0];
    cplx* l1 = lds2[1];
    float4* l04 = (float4*)l0;
    float4* l14 = (float4*)l1;
    load_twT(twT, ws, tid);
    float w30[16], w31[16];
#pragma unroll
    for (int m = 0; m < 16; ++m) { w30[m] = W3[m*NCH + c0]; w31[m] = W3[m*NCH + c1]; }
    const float b30 = b3[c0], b31 = b3[c1];
    const float ad0 = fabsf(deltas[c0]), ad1 = fabsf(deltas[c1]);
    const float bc0 = bias[c0], bc1 = bias[c1];
    const int sbA = psb<0>(tid);
#pragma unroll 1
    for (int j = 0; j < 8; ++j) {
        int n = tid + (j << 9);
        const float4* hp = (const float4*)(H + (n << 5));
        float sA0 = b30, sB0 = b30, sA1 = b31, sB1 = b31;   // A/B = the 2 time pts
#pragma unroll
        for (int q = 0; q < 4; ++q) {
            float4 a = hp[q];       // elems of point 2n
            float4 b = hp[4+q];     // elems of point 2n+1
            sA0 += a.x*w30[4*q] + a.y*w30[4*q+1] + a.z*w30[4*q+2] + a.w*w30[4*q+3];
            sB0 += b.x*w30[4*q] + b.y*w30[4*q+1] + b.z*w30[4*q+2] + b.w*w30[4*q+3];
            sA1 += a.x*w31[4*q] + a.y*w31[4*q+1] + a.z*w31[4*q+2] + a.w*w31[4*q+3];
            sB1 += b.x*w31[4*q] + b.y*w31[4*q+1] + b.z*w31[4*q+2] + b.w*w31[4*q+3];
        }
        float2 tv = ((const float2*)t)[n];
        int a0 = paddr<0>(sbA, j);          // = (sbA ^ 2*(j&7)) + (j<<9)
        float e0 = expf(-tv.x*ad0), e1 = expf(-tv.y*ad0);
        float e2 = expf(-tv.x*ad1), e3 = expf(-tv.y*ad1);
        l0[a0] = cplx{sA0 * e0, sB0 * e1};
        l1[a0] = cplx{sA1 * e2, sB1 * e3};
    }
    __syncthreads();
    r16pp<0,false,true >(l0, l1, twT, tid); __syncthreads();
    r16pp<1,false,false>(l0, l1, twT, tid); wave_sync();
    r16pp<2,false,false>(l0, l1, twT, tid); __syncthreads();

    float4* kf0 = (float4*)KfF + (size_t)c0 * 4096;
    float4* kf1 = (float4*)KfF + (size_t)c1 * 4096;
    const cplx* tw16 = (const cplx*)(ws + OFF_TW16);
    const float sc = 1.0f / 32768.0f;
#pragma unroll 1
    for (int it = 0; it < 4; ++it) {
        int k  = tid + 1 + (it << 9);   // 1..2048
        int jj = 4096 - k;              // (k=2048: idempotent dup)
        int sA = IDX14(drev(k)) >> 1, sB = IDX14(drev(jj)) >> 1;
        cplx W  = tw16[k];
        cplx Wj = cplx{-W.y, -W.x};
        filt_store(l04, kf0, k, jj, sA, sB, W, Wj, sc, 2.0f*bc0);
        filt_store(l14, kf1, k, jj, sA, sB, W, Wj, sc, 2.0f*bc1);
    }
    if (tid == 0) { filt_dc(l04, kf0, bc0); filt_dc(l14, kf1, bc1); }
}

// Block = (channel c, batch-half): 4 rows as 2 pairs; sequential-paired passes
// (one barrier per pass-pair), kf4/tw16 loads shared across the pair.
// Bias folded into Kf: no x re-read, no epilogue FMA. Staging/spectral/epilogue
// LDS traffic is b128 (mask14 keeps pairs adjacent, fixed order).
__global__ __launch_bounds__(NT) void k_main(const float* __restrict__ x, const float* __restrict__ ws,
        const float* __restrict__ KfF, float* __restrict__ out) {
    __shared__ alignas(16) cplx lds2[2][LSEQ];
    __shared__ cplx twT[16][68];
    const int bid = blockIdx.x;                 // 0..1535
    const int c = bid >> 1, half = bid & 1;
    const int tt = threadIdx.x;
    cplx* l0 = lds2[0];
    cplx* l1 = lds2[1];
    float4* l04 = (float4*)l0;
    float4* l14 = (float4*)l1;
    const float4* kf4 = (const float4*)KfF + (size_t)c * 4096;
    const cplx* tw16 = (const cplx*)(ws + OFF_TW16);
    const size_t rowstride = (size_t)NCH * LSEQ;
    const float* xbase = x + (size_t)(half*4) * rowstride + (size_t)c * LSEQ;
    float* obase = out + (size_t)(half*4) * rowstride + (size_t)c * LSEQ;

    // staging slot: IDX14(2i),IDX14(2i+1) = one float4 at ((EB^(j<<2))+(j<<10))>>1
    const int EB = (tt << 1) ^ (((tt>>3) ^ (tt>>7)) & 14);

    load_twT(twT, ws, tt);

#pragma unroll 1
    for (int pp = 0; pp < 2; ++pp) {            // pair = rows (2pp, 2pp+1)
        const float4* xr0 = (const float4*)(xbase + (size_t)(2*pp)     * rowstride);
        const float4* xr1 = (const float4*)(xbase + (size_t)(2*pp + 1) * rowstride);
#pragma unroll
        for (int j = 0; j < 4; ++j) {
            int si = ((EB ^ (j<<2)) + (j<<10)) >> 1;
            l04[si] = xr0[tt + (j<<9)];
            l14[si] = xr1[tt + (j<<9)];
        }
        __syncthreads();                              // also covers twT copy (pp==0)
        r16pp<0,false,true >(l0, l1, twT, tt); __syncthreads();
        r16pp<1,false,false>(l0, l1, twT, tt); wave_sync();
        r16pp<2,false,false>(l0, l1, twT, tt); __syncthreads();

        // fused fwd-r2 + spectral + inverse-r2 on both buffers; kf/tw shared
#pragma unroll 1
        for (int it = 0; it < 4; ++it) {
            int k  = tt + 1 + (it << 9);   // 1..2048
            int jj = 4096 - k;
            int sA = IDX14(drev(k)) >> 1, sB = IDX14(drev(jj)) >> 1;
            float4 kvk = kf4[k], kvj = kf4[jj];
            cplx W  = tw16[k];
            cplx Wj = cplx{-W.y, -W.x};
            spec_rows(l04, sA, sB, kvk, kvj, W, Wj);
            spec_rows(l14, sA, sB, kvk, kvj, W, Wj);
        }
        if (tt == 0) {
            float4 kv = kf4[0];
            spec_dc(l04, kv);
            spec_dc(l14, kv);
        }
        __syncthreads();

        r16pp<2,true,false>(l0, l1, twT, tt); wave_sync();
        r16pp<1,true,false>(l0, l1, twT, tt); __syncthreads();
        r16pp<0,true,false>(l0, l1, twT, tt); __syncthreads();

        float4* o0 = (float4*)(obase + (size_t)(2*pp)     * rowstride);
        float4* o1 = (float4*)(obase + (size_t)(2*pp + 1) * rowstride);
#pragma unroll
        for (int j = 0; j < 4; ++j) {
            int si = ((EB ^ (j<<2)) + (j<<10)) >> 1;
            float4 f0 = l04[si], f1 = l14[si];
            o0[tt + (j<<9)] = make_float4(f0.y, f0.x, f0.w, f0.z);
            o1[tt + (j<<9)] = make_float4(f1.y, f1.x, f1.w, f1.z);
        }
        if (pp == 0) __syncthreads();   // protect lds before next pair's staging
    }
}

extern "C" void kernel_launch(void* const* d_in, const int* in_sizes, int n_in,
                              void* d_out, int out_size, void* d_ws, size_t ws_size,
                              hipStream_t stream) {
    const float* x      = (const float*)d_in[0];
    const float* z      = (const float*)d_in[2];
    const float* t      = (const float*)d_in[3];
    const float* deltas = (const float*)d_in[4];
    const float* freq   = (const float*)d_in[5];
    const float* W0     = (const float*)d_in[6];
    const float* b0     = (const float*)d_in[7];
    const float* W1     = (const float*)d_in[8];
    const float* b1     = (const float*)d_in[9];
    const float* W2     = (const float*)d_in[10];
    const float* b2     = (const float*)d_in[11];
    const float* W3     = (const float*)d_in[12];
    const float* b3     = (const float*)d_in[13];
    const float* bias   = (const float*)d_in[14];
    float* out = (float*)d_out;
    float* ws  = (float*)d_ws;
    float* H   = ws + OFF_H;
    float* Kf  = ws + OFF_KF;

    hipLaunchKernelGGL(k_pre, dim3(17), dim3(512), 0, stream, z, freq, W0, b0, W1, b1, W2, b2, ws, H);
    hipLaunchKernelGGL(k_filter, dim3(NCH/2), dim3(NT), 0, stream, H, t, deltas, W3, b3, bias, ws, Kf);
    hipLaunchKernelGGL(k_main, dim3(NBATCH * NCH / 4), dim3(NT), 0, stream, x, ws, Kf, out);
}

// Round 13
// 595.591 us; speedup vs baseline: 1.7303x; 1.0207x over previous
//
#include <hip/hip_runtime.h>
#include <math.h>

// HyenaFilter: y = irfft(rfft(x,2L) * rfft(k,2L))[..., :L] + x*bias
// Register-blocked mixed-radix [16,16,16,2] FFT. Round-13 revision:
//  - PASS-A TWIDDLES HOISTED TO REGISTERS: rL/rH depend only on tid, so the
//    combined twiddle W8192^{pm} = TL[p&31][m]*TWB[2(p>>5)][m] is computed
//    ONCE into cplx twA[15] (30 VGPR, peak ~118 < 128 quantum). Deletes
//    240 LDS reads (8-way bank-conflicted: row stride 544B -> bank step 8)
//    and ~360 VALU per thread across the 8 A-calls. Same twA serves DIF and
//    DIT (both apply W^{pm}).
//  - keeps R12: packed f32 (ext_vector cplx -> v_pk_*), mask-14 swizzle with
//    b128 staging/spectral/epilogue, bias folded into Kf, sequential-paired
//    passes, two-row ping-pong, LDS twiddle tables (B/C still from LDS),
//    wave-local B<->C sync, pruned first fwd pass, merged k_pre.

#define LSEQ 8192
#define NCH 768
#define NBATCH 8
#define NT 512            // threads per block

// ws layout (float offsets)
#define OFF_TWB  0        // 32 rows x 16 cplx : W16384^{32*q*m}   (pass B; pass-A high = rows 2b)
#define OFF_TW16 1024     // 2049 cplx         : W16384^k, k<=2048
#define OFF_TL   5124     // 32 rows x 16 cplx : W16384^{2*a*m}    (pass A low)
#define OFF_TWC  6660     // 2 rows x 16 cplx  : W16384^{512*p*m}  (pass C)
#define OFF_H    10240    // 8192 x 16 floats (MLP features, row-major)
#define OFF_KF   141312   // 768 x 4096 float4 (S~, D~ per bin pair)

typedef float cplx __attribute__((ext_vector_type(2)));

__device__ __forceinline__ cplx cmul(cplx a, cplx b){
    return cplx{a.x, a.x} * b + cplx{a.y, a.y} * cplx{-b.y, b.x};
}
__device__ __forceinline__ cplx mni(cplx a){ return cplx{a.y, -a.x}; }  // * -i

// wave-local LDS producer->consumer sync (exchange confined to one wave)
__device__ __forceinline__ void wave_sync(){
    asm volatile("s_waitcnt lgkmcnt(0)" ::: "memory");
}
// scheduling fence between the two sequential buffer-passes (R9 spill fix)
__device__ __forceinline__ void fence(){
    asm volatile("" ::: "memory");
}

// bit0-preserving swizzle (mask &14): pairs {2m,2m+1} stay adjacent, fixed order
__device__ __forceinline__ int IDX14(int i){ return i ^ (((i>>4) ^ (i>>8)) & 14); }
// digit-reversal: bin k -> slot after DIF passes [16(512),16(32),16(2)] (pre-r2, slot even)
__device__ __forceinline__ int drev(int k){
    return ((k & 15) << 9) | (((k >> 4) & 15) << 5) | (((k >> 8) & 15) << 1) | (k >> 12);
}

#define C1 0.923879532511286756f
#define S1 0.382683432365089772f
#define R2 0.707106781186547524f

// natural-in DFT-16; output bin m in q[rv[m]]. FULL=false: inputs 8..15 are
// pre-duplicated copies of 0..7 (zero upper half), stage-1 add/sub skipped.
template<bool FULL>
__device__ __forceinline__ void dft16(cplx q[16]) {
    if constexpr (FULL) {
#pragma unroll
        for (int j = 0; j < 8; ++j) { cplx u=q[j], v=q[j+8]; q[j]=u+v; q[j+8]=u-v; }
    }
    q[9]  = cmul(q[9],  cplx{ C1,-S1});
    q[10] = cmul(q[10], cplx{ R2,-R2});
    q[11] = cmul(q[11], cplx{ S1,-C1});
    q[12] = mni(q[12]);
    q[13] = cmul(q[13], cplx{-S1,-C1});
    q[14] = cmul(q[14], cplx{-R2,-R2});
    q[15] = cmul(q[15], cplx{-C1,-S1});
#pragma unroll
    for (int b = 0; b < 16; b += 8) {
#pragma unroll
        for (int j = 0; j < 4; ++j) { cplx u=q[b+j], v=q[b+j+4]; q[b+j]=u+v; q[b+j+4]=u-v; }
        q[b+5] = cmul(q[b+5], cplx{ R2,-R2});
        q[b+6] = mni(q[b+6]);
        q[b+7] = cmul(q[b+7], cplx{-R2,-R2});
    }
#pragma unroll
    for (int b = 0; b < 16; b += 4) {
        cplx u0=q[b], v0=q[b+2], u1=q[b+1], v1=q[b+3];
        q[b]=u0+v0; q[b+2]=u0-v0;
        q[b+1]=u1+v1; q[b+3]=mni(u1-v1);
    }
#pragma unroll
    for (int b = 0; b < 16; b += 2) { cplx u=q[b], v=q[b+1]; q[b]=u+v; q[b+1]=u-v; }
}

// Hand-folded swizzled addressing for mask &14: IDX14(base+p+r*L) == (sb ^ C_r) + (r*L).
template<int PASS>
__device__ __forceinline__ int psb(int t) {
    if constexpr (PASS == 0) {               // L=512, p=t
        return t ^ (((t>>4) ^ (t>>8)) & 14);
    } else if constexpr (PASS == 1) {        // L=32, base=(t>>5)<<9, p=t&31
        int p = t & 31, hb = t >> 5;
        return ((hb<<9) | p) ^ (((p>>4) ^ (hb<<1)) & 14);
    } else {                                 // L=2, base=(t>>1)<<5, p=t&1
        int h = t >> 1;
        return ((h<<5) | (t&1)) ^ (((h<<1) ^ (h>>3)) & 14);
    }
}
template<int PASS>
__device__ __forceinline__ int paddr(int sb, int r) {
    if constexpr (PASS == 0)      return (sb ^ (2*(r&7))) + (r<<9);
    else if constexpr (PASS == 1) return (sb ^ (2*(r&7))) + (r<<5);
    else                          return sb ^ (r<<1);
}

// One radix-16 pass (single buffer). Pass A twiddles come from registers
// (twA[15], hoisted — thread-constant); B/C from LDS table twT[m][row].
template<int PASS, bool DIT, bool PRUNED>
__device__ __forceinline__ void r16p(cplx* lds, const cplx (*twT)[68],
                                     const cplx (&twA)[15], int t) {
    static constexpr int RV[16] = {0,8,4,12,2,10,6,14,1,9,5,13,3,11,7,15};
    const int sb = psb<PASS>(t);
    int rL = 0;
    if constexpr (PASS == 1) { rL = t & 31; }
    else if constexpr (PASS == 2) { rL = 64 + (t & 1); }
    cplx q[16];
    if constexpr (PRUNED) {
#pragma unroll
        for (int r = 0; r < 8; ++r) { q[r] = lds[paddr<PASS>(sb, r)]; q[r+8] = q[r]; }
    } else {
#pragma unroll
        for (int r = 0; r < 16; ++r) q[r] = lds[paddr<PASS>(sb, r)];
    }
    if constexpr (DIT) {
#pragma unroll
        for (int m = 1; m < 16; ++m) {
            cplx w = (PASS == 0) ? twA[m-1] : twT[m][rL];
            q[m] = cmul(q[m], w);
        }
        dft16<true>(q);
    } else {
        dft16<!PRUNED>(q);
#pragma unroll
        for (int m = 1; m < 16; ++m) {
            cplx w = (PASS == 0) ? twA[m-1] : twT[m][rL];
            q[RV[m]] = cmul(q[RV[m]], w);
        }
    }
#pragma unroll
    for (int m = 0; m < 16; ++m) lds[paddr<PASS>(sb, m)] = q[RV[m]];
}

// paired pass: two sequential single-buffer passes, one barrier interval
template<int PASS, bool DIT, bool PRUNED>
__device__ __forceinline__ void r16pp(cplx* l0, cplx* l1, const cplx (*twT)[68],
                                      const cplx (&twA)[15], int t) {
    r16p<PASS, DIT, PRUNED>(l0, twT, twA, t);
    fence();
    r16p<PASS, DIT, PRUNED>(l1, twT, twA, t);
}

// copy twiddle tables global -> LDS (transposed): 66 rows x 16 elems
__device__ __forceinline__ void load_twT(cplx (*twT)[68], const float* __restrict__ ws, int tid) {
    const cplx* gTWB = (const cplx*)(ws + OFF_TWB);
    const cplx* gTL  = (const cplx*)(ws + OFF_TL);
    const cplx* gTWC = (const cplx*)(ws + OFF_TWC);
    for (int idx = tid; idx < 16*66; idx += NT) {
        int r = idx >> 4, m = idx & 15;
        cplx v;
        if (r < 32)      v = gTWB[(r << 4) + m];
        else if (r < 64) v = gTL[((r - 32) << 4) + m];
        else             v = gTWC[((r - 64) << 4) + m];
        twT[m][r] = v;
    }
}

// hoist pass-A combined twiddles into registers (thread-constant; call after
// twT is barrier-visible). W8192^{pm} = TL[t&31][m] * TWB[2*(t>>5)][m].
__device__ __forceinline__ void make_twA(cplx (&twA)[15], const cplx (*twT)[68], int t) {
    const int rL = 32 + (t & 31);
    const int rH = (t >> 5) << 1;
#pragma unroll
    for (int m = 1; m < 16; ++m) twA[m-1] = cmul(twT[m][rL], twT[m][rH]);
}

// spectral multiply for bin pair (k, 8192-k): o1/o2 are swapped v'[k], v'[8192-k]
__device__ __forceinline__ void specpair(cplx V1, cplx V2, float4 kv, cplx W,
                                         cplx& o1, cplx& o2) {
    cplx Eh = V1 + cplx{V2.x, -V2.y};
    cplx Oh = cplx{V1.y + V2.y, V2.x - V1.x};
    cplx S = cplx{kv.x, kv.y};
    float a = W.x*kv.z, b = W.y*kv.w, cc = W.x*kv.w, dd = W.y*kv.z;
    cplx T  = cplx{a - b, cc + dd};
    cplx T2 = cplx{a + b, cc - dd};
    cplx Ep = cmul(Eh, S) + cmul(Oh, T);
    cplx Op = cmul(Eh, T2) + cmul(Oh, S);
    o1 = cplx{Ep.y + Op.x, Ep.x - Op.y};
    o2 = cplx{Op.x - Ep.y, Ep.x + Op.y};
}

// fused fwd-r2 + spectral multiply + inverse-r2 for one buffer at slot pair
__device__ __forceinline__ void spec_rows(float4* l4, int sA, int sB,
                                          float4 kvk, float4 kvj, cplx W, cplx Wj) {
    float4 fA = l4[sA], fB = l4[sB];
    cplx uA = {fA.x, fA.y}, vA = {fA.z, fA.w};
    cplx uB = {fB.x, fB.y}, vB = {fB.z, fB.w};
    cplx Vk = uA + vA, Vk4 = uA - vA;   // bins k, k+4096
    cplx Vj = uB + vB, Vj4 = uB - vB;   // bins jj, 8192-k
    cplx r1, r2, r1j, r2j;
    specpair(Vk, Vj4, kvk, W,  r1,  r2);   // v'[k],  v'[8192-k]
    specpair(Vj, Vk4, kvj, Wj, r1j, r2j);  // v'[jj], v'[4096+k]
    cplx a0 = r1 + r2j, a1 = r1 - r2j;
    cplx b0 = r1j + r2, b1 = r1j - r2;
    l4[sA] = make_float4(a0.x, a0.y, a1.x, a1.y);
    l4[sB] = make_float4(b0.x, b0.y, b1.x, b1.y);
}

// bins 0 / 4096 special (tt==0); slots {0,1} = l4[0]
__device__ __forceinline__ void spec_dc(float4* l4, float4 kv) {
    float4 f = l4[0];
    cplx u = {f.x, f.y}, v = {f.z, f.w};
    cplx V0 = u + v, VN = u - v;
    float U0 = V0.x + V0.y, UL = V0.x - V0.y;
    float re = U0*kv.x + UL*kv.y;
    float im = U0*kv.x - UL*kv.y;
    cplx s0 = {im, re};
    cplx P = {VN.x*kv.z + VN.y*kv.w, VN.x*kv.w - VN.y*kv.z};
    cplx s1 = {-P.y, P.x};
    cplx a = s0 + s1, b = s0 - s1;
    l4[0] = make_float4(a.x, a.y, b.x, b.y);
}

// filter spectral store for one channel at quad (k,jj), bias folded (E += eb)
__device__ __forceinline__ void filt_store(const float4* l4, float4* kf, int k, int jj,
                                           int sA, int sB, cplx W, cplx Wj,
                                           float sc, float eb) {
    float4 fA = l4[sA], fB = l4[sB];
    cplx uA = {fA.x, fA.y}, vA = {fA.z, fA.w};
    cplx uB = {fB.x, fB.y}, vB = {fB.z, fB.w};
    cplx Vk = uA + vA, Vk4 = uA - vA;
    cplx Vj = uB + vB, Vj4 = uB - vB;
    {
        cplx E = {Vk.x + Vj4.x + eb, Vk.y - Vj4.y};
        cplx O = {Vk.y + Vj4.y, Vj4.x - Vk.x};
        cplx D = cmul(W, O);
        kf[k] = make_float4(E.x*sc, E.y*sc, D.x*sc, D.y*sc);
    }
    {
        cplx E = {Vj.x + Vk4.x + eb, Vj.y - Vk4.y};
        cplx O = {Vj.y + Vk4.y, Vk4.x - Vj.x};
        cplx D = cmul(Wj, O);
        kf[jj] = make_float4(E.x*sc, E.y*sc, D.x*sc, D.y*sc);
    }
}
// DC store with bias fold: H[0]+=bc, H[8192]+=bc, H[4096]+=bc.
__device__ __forceinline__ void filt_dc(const float4* l4, float4* kf, float bc) {
    float4 f = l4[0];
    cplx u = {f.x, f.y}, v = {f.z, f.w};
    cplx V0 = u + v, VN = u - v;
    kf[0] = make_float4((V0.x + V0.y + bc)/16384.f, (V0.x - V0.y + bc)/16384.f,
                        (VN.x + bc)/8192.f, -VN.y/8192.f);
}

// merged init (block 0: twiddle tables via double-precision factor tables) + MLP (blocks 1..16)
__global__ __launch_bounds__(512) void k_pre(const float* __restrict__ z, const float* __restrict__ freq,
        const float* __restrict__ W0, const float* __restrict__ b0,
        const float* __restrict__ W1, const float* __restrict__ b1,
        const float* __restrict__ W2, const float* __restrict__ b2,
        float* __restrict__ ws, float* __restrict__ H) {
    __shared__ double2 lA[128], lB[128];
    const int t = threadIdx.x;
    if (blockIdx.x == 0) {
        const double K = -2.0 * 3.14159265358979323846 / 16384.0;
        if (t < 128)      { double a = K * (double)(t << 7); lA[t] = make_double2(cos(a), sin(a)); }
        else if (t < 256) { int b = t - 128; double a = K * (double)b; lB[b] = make_double2(cos(a), sin(a)); }
        __syncthreads();
        auto wf = [&](int e) -> float2 {
            e &= 16383;
            double2 A = lA[e >> 7], B = lB[e & 127];
            return make_float2((float)(A.x*B.x - A.y*B.y), (float)(A.x*B.y + A.y*B.x));
        };
        float2* tw16 = (float2*)(ws + OFF_TW16);
        for (int k = t; k <= 2048; k += 512) tw16[k] = wf(k);
        if (t < 32) {
            float2* rowL = (float2*)(ws + OFF_TL)  + (t << 4);
            float2* rowB = (float2*)(ws + OFF_TWB) + (t << 4);
#pragma unroll
            for (int m = 0; m < 16; ++m) { rowL[m] = wf(2*t*m); rowB[m] = wf(32*t*m); }
        } else if (t < 34) {
            int c2 = t - 32;
            float2* rowC = (float2*)(ws + OFF_TWC) + (c2 << 4);
#pragma unroll
            for (int m = 0; m < 16; ++m) rowC[m] = wf(512*c2*m);
        }
    } else {
        const int j = ((blockIdx.x - 1) << 9) + t;
        const float z0 = z[j*3+0], z1 = z[j*3+1], z2 = z[j*3+2];
        float h[16], g[16];
#pragma unroll
        for (int m = 0; m < 16; ++m)
            h[m] = sinf(freq[m] * (z0*W0[m] + z1*W0[16+m] + z2*W0[32+m] + b0[m]));
#pragma unroll
        for (int m = 0; m < 16; ++m) {
            float a = b1[m];
#pragma unroll
            for (int p = 0; p < 16; ++p) a += h[p] * W1[p*16+m];
            g[m] = sinf(freq[m] * a);
        }
#pragma unroll
        for (int m = 0; m < 16; ++m) {
            float a = b2[m];
#pragma unroll
            for (int p = 0; p < 16; ++p) a += g[p] * W2[p*16+m];
            h[m] = sinf(freq[m] * a);
        }
        float4* hp = (float4*)(H + (j << 4));   // row-major [8192][16]
        hp[0] = make_float4(h[0],  h[1],  h[2],  h[3]);
        hp[1] = make_float4(h[4],  h[5],  h[6],  h[7]);
        hp[2] = make_float4(h[8],  h[9],  h[10], h[11]);
        hp[3] = make_float4(h[12], h[13], h[14], h[15]);
    }
}

// TWO channels per block (shared H staging, sequential-paired passes):
// filter -> pruned fwd FFT -> fused(r2+unpack) -> store (S~,D~) with bias fold.
__global__ __launch_bounds__(NT) void k_filter(const float* __restrict__ H, const float* __restrict__ t,
        const float* __restrict__ deltas, const float* __restrict__ W3,
        const float* __restrict__ b3, const float* __restrict__ bias,
        const float* __restrict__ ws, float* __restrict__ KfF) {
    __shared__ alignas(16) cplx lds2[2][LSEQ];
    __shared__ cplx twT[16][68];
    const int c0 = blockIdx.x << 1, c1 = c0 + 1;
    const int tid = threadIdx.x;
    cplx* l0 = lds2[0];
    cplx* l1 = lds2[1];
    float4* l04 = (float4*)l0;
    float4* l14 = (float4*)l1;
    load_twT(twT, ws, tid);
    float w30[16], w31[16];
#pragma unroll
    for (int m = 0; m < 16; ++m) { w30[m] = W3[m*NCH + c0]; w31[m] = W3[m*NCH + c1]; }
    const float b30 = b3[c0], b31 = b3[c1];
    const float ad0 = fabsf(deltas[c0]), ad1 = fabsf(deltas[c1]);
    const float bc0 = bias[c0], bc1 = bias[c1];
    const int sbA = psb<0>(tid);
#pragma unroll 1
    for (int j = 0; j < 8; ++j) {
        int n = tid + (j << 9);
        const float4* hp = (const float4*)(H + (n << 5));
        float sA0 = b30, sB0 = b30, sA1 = b31, sB1 = b31;   // A/B = the 2 time pts
#pragma unroll
        for (int q = 0; q < 4; ++q) {
            float4 a = hp[q];       // elems of point 2n
            float4 b = hp[4+q];     // elems of point 2n+1
            sA0 += a.x*w30[4*q] + a.y*w30[4*q+1] + a.z*w30[4*q+2] + a.w*w30[4*q+3];
            sB0 += b.x*w30[4*q] + b.y*w30[4*q+1] + b.z*w30[4*q+2] + b.w*w30[4*q+3];
            sA1 += a.x*w31[4*q] + a.y*w31[4*q+1] + a.z*w31[4*q+2] + a.w*w31[4*q+3];
            sB1 += b.x*w31[4*q] + b.y*w31[4*q+1] + b.z*w31[4*q+2] + b.w*w31[4*q+3];
        }
        float2 tv = ((const float2*)t)[n];
        int a0 = paddr<0>(sbA, j);          // = (sbA ^ 2*(j&7)) + (j<<9)
        float e0 = expf(-tv.x*ad0), e1 = expf(-tv.y*ad0);
        float e2 = expf(-tv.x*ad1), e3 = expf(-tv.y*ad1);
        l0[a0] = cplx{sA0 * e0, sB0 * e1};
        l1[a0] = cplx{sA1 * e2, sB1 * e3};
    }
    __syncthreads();
    cplx twA[15];
    make_twA(twA, twT, tid);
    r16pp<0,false,true >(l0, l1, twT, twA, tid); __syncthreads();
    r16pp<1,false,false>(l0, l1, twT, twA, tid); wave_sync();
    r16pp<2,false,false>(l0, l1, twT, twA, tid); __syncthreads();

    float4* kf0 = (float4*)KfF + (size_t)c0 * 4096;
    float4* kf1 = (float4*)KfF + (size_t)c1 * 4096;
    const cplx* tw16 = (const cplx*)(ws + OFF_TW16);
    const float sc = 1.0f / 32768.0f;
#pragma unroll 1
    for (int it = 0; it < 4; ++it) {
        int k  = tid + 1 + (it << 9);   // 1..2048
        int jj = 4096 - k;              // (k=2048: idempotent dup)
        int sA = IDX14(drev(k)) >> 1, sB = IDX14(drev(jj)) >> 1;
        cplx W  = tw16[k];
        cplx Wj = cplx{-W.y, -W.x};
        filt_store(l04, kf0, k, jj, sA, sB, W, Wj, sc, 2.0f*bc0);
        filt_store(l14, kf1, k, jj, sA, sB, W, Wj, sc, 2.0f*bc1);
    }
    if (tid == 0) { filt_dc(l04, kf0, bc0); filt_dc(l14, kf1, bc1); }
}

// Block = (channel c, batch-half): 4 rows as 2 pairs; sequential-paired passes
// (one barrier per pass-pair), kf4/tw16 loads shared across the pair.
// Bias folded into Kf: no x re-read, no epilogue FMA. b128 LDS in
// staging/spectral/epilogue (mask14). Pass-A twiddles in registers.
__global__ __launch_bounds__(NT) void k_main(const float* __restrict__ x, const float* __restrict__ ws,
        const float* __restrict__ KfF, float* __restrict__ out) {
    __shared__ alignas(16) cplx lds2[2][LSEQ];
    __shared__ cplx twT[16][68];
    const int bid = blockIdx.x;                 // 0..1535
    const int c = bid >> 1, half = bid & 1;
    const int tt = threadIdx.x;
    cplx* l0 = lds2[0];
    cplx* l1 = lds2[1];
    float4* l04 = (float4*)l0;
    float4* l14 = (float4*)l1;
    const float4* kf4 = (const float4*)KfF + (size_t)c * 4096;
    const cplx* tw16 = (const cplx*)(ws + OFF_TW16);
    const size_t rowstride = (size_t)NCH * LSEQ;
    const float* xbase = x + (size_t)(half*4) * rowstride + (size_t)c * LSEQ;
    float* obase = out + (size_t)(half*4) * rowstride + (size_t)c * LSEQ;

    // staging slot: IDX14(2i),IDX14(2i+1) = one float4 at ((EB^(j<<2))+(j<<10))>>1
    const int EB = (tt << 1) ^ (((tt>>3) ^ (tt>>7)) & 14);

    load_twT(twT, ws, tt);
    __syncthreads();
    cplx twA[15];
    make_twA(twA, twT, tt);

#pragma unroll 1
    for (int pp = 0; pp < 2; ++pp) {            // pair = rows (2pp, 2pp+1)
        const float4* xr0 = (const float4*)(xbase + (size_t)(2*pp)     * rowstride);
        const float4* xr1 = (const float4*)(xbase + (size_t)(2*pp + 1) * rowstride);
#pragma unroll
        for (int j = 0; j < 4; ++j) {
            int si = ((EB ^ (j<<2)) + (j<<10)) >> 1;
            l04[si] = xr0[tt + (j<<9)];
            l14[si] = xr1[tt + (j<<9)];
        }
        __syncthreads();
        r16pp<0,false,true >(l0, l1, twT, twA, tt); __syncthreads();
        r16pp<1,false,false>(l0, l1, twT, twA, tt); wave_sync();
        r16pp<2,false,false>(l0, l1, twT, twA, tt); __syncthreads();

        // fused fwd-r2 + spectral + inverse-r2 on both buffers; kf/tw shared
#pragma unroll 1
        for (int it = 0; it < 4; ++it) {
            int k  = tt + 1 + (it << 9);   // 1..2048
            int jj = 4096 - k;
            int sA = IDX14(drev(k)) >> 1, sB = IDX14(drev(jj)) >> 1;
            float4 kvk = kf4[k], kvj = kf4[jj];
            cplx W  = tw16[k];
            cplx Wj = cplx{-W.y, -W.x};
            spec_rows(l04, sA, sB, kvk, kvj, W, Wj);
            spec_rows(l14, sA, sB, kvk, kvj, W, Wj);
        }
        if (tt == 0) {
            float4 kv = kf4[0];
            spec_dc(l04, kv);
            spec_dc(l14, kv);
        }
        __syncthreads();

        r16pp<2,true,false>(l0, l1, twT, twA, tt); wave_sync();
        r16pp<1,true,false>(l0, l1, twT, twA, tt); __syncthreads();
        r16pp<0,true,false>(l0, l1, twT, twA, tt); __syncthreads();

        float4* o0 = (float4*)(obase + (size_t)(2*pp)     * rowstride);
        float4* o1 = (float4*)(obase + (size_t)(2*pp + 1) * rowstride);
#pragma unroll
        for (int j = 0; j < 4; ++j) {
            int si = ((EB ^ (j<<2)) + (j<<10)) >> 1;
            float4 f0 = l04[si], f1 = l14[si];
            o0[tt + (j<<9)] = make_float4(f0.y, f0.x, f0.w, f0.z);
            o1[tt + (j<<9)] = make_float4(f1.y, f1.x, f1.w, f1.z);
        }
        if (pp == 0) __syncthreads();   // protect lds before next pair's staging
    }
}

extern "C" void kernel_launch(void* const* d_in, const int* in_sizes, int n_in,
                              void* d_out, int out_size, void* d_ws, size_t ws_size,
                              hipStream_t stream) {
    const float* x      = (const float*)d_in[0];
    const float* z      = (const float*)d_in[2];
    const float* t      = (const float*)d_in[3];
    const float* deltas = (const float*)d_in[4];
    const float* freq   = (const float*)d_in[5];
    const float* W0     = (const float*)d_in[6];
    const float* b0     = (const float*)d_in[7];
    const float* W1     = (const float*)d_in[8];
    const float* b1     = (const float*)d_in[9];
    const float* W2     = (const float*)d_in[10];
    const float* b2     = (const float*)d_in[11];
    const float* W3     = (const float*)d_in[12];
    const float* b3     = (const float*)d_in[13];
    const float* bias   = (const float*)d_in[14];
    float* out = (float*)d_out;
    float* ws  = (float*)d_ws;
    float* H   = ws + OFF_H;
    float* Kf  = ws + OFF_KF;

    hipLaunchKernelGGL(k_pre, dim3(17), dim3(512), 0, stream, z, freq, W0, b0, W1, b1, W2, b2, ws, H);
    hipLaunchKernelGGL(k_filter, dim3(NCH/2), dim3(NT), 0, stream, H, t, deltas, W3, b3, bias, ws, Kf);
    hipLaunchKernelGGL(k_main, dim3(NBATCH * NCH / 4), dim3(NT), 0, stream, x, ws, Kf, out);
}

// Round 14
// 574.765 us; speedup vs baseline: 1.7930x; 1.0362x over previous
//
#include <hip/hip_runtime.h>
#include <math.h>

// HyenaFilter: y = irfft(rfft(x,2L) * rfft(k,2L))[..., :L] + x*bias
// Register-blocked mixed-radix [16,16,16,2] FFT. Round-14 revision:
//  - K_FILTER MERGED INTO K_MAIN: 768 blocks (3 exact dispatch rounds), each
//    block = one channel x 8 batches. The block first computes its channel's
//    filter spectrum (MLP staging -> pruned fwd FFT in l0 -> filt_store to
//    global Kf[c]; single writer, no duplication), then __syncthreads (drains
//    vmcnt -> writes L2-visible) and processes 4 row-pairs reading kf4 L2-hot.
//    Kills the separate k_filter launch (384 blocks = 1.5 rounds, half-GPU
//    tail, 1 block/CU latency-bound) by absorbing its work into the full-GPU
//    schedule. L1-stale safe: first touch of Kf is the write; values constant.
//  - keeps R13: packed f32 cplx (v_pk_*), mask-14 swizzle + b128 LDS, pass-A
//    twiddles in registers (twA[15]), bias folded into Kf, sequential-paired
//    passes, two-row ping-pong, LDS twiddle tables, wave-local B<->C sync,
//    pruned first fwd pass, merged k_pre.

#define LSEQ 8192
#define NCH 768
#define NBATCH 8
#define NT 512            // threads per block

// ws layout (float offsets)
#define OFF_TWB  0        // 32 rows x 16 cplx : W16384^{32*q*m}   (pass B; pass-A high = rows 2b)
#define OFF_TW16 1024     // 2049 cplx         : W16384^k, k<=2048
#define OFF_TL   5124     // 32 rows x 16 cplx : W16384^{2*a*m}    (pass A low)
#define OFF_TWC  6660     // 2 rows x 16 cplx  : W16384^{512*p*m}  (pass C)
#define OFF_H    10240    // 8192 x 16 floats (MLP features, row-major)
#define OFF_KF   141312   // 768 x 4096 float4 (S~, D~ per bin pair)

typedef float cplx __attribute__((ext_vector_type(2)));

__device__ __forceinline__ cplx cmul(cplx a, cplx b){
    return cplx{a.x, a.x} * b + cplx{a.y, a.y} * cplx{-b.y, b.x};
}
__device__ __forceinline__ cplx mni(cplx a){ return cplx{a.y, -a.x}; }  // * -i

// wave-local LDS producer->consumer sync (exchange confined to one wave)
__device__ __forceinline__ void wave_sync(){
    asm volatile("s_waitcnt lgkmcnt(0)" ::: "memory");
}
// scheduling fence between the two sequential buffer-passes (R9 spill fix)
__device__ __forceinline__ void fence(){
    asm volatile("" ::: "memory");
}

// bit0-preserving swizzle (mask &14): pairs {2m,2m+1} stay adjacent, fixed order
__device__ __forceinline__ int IDX14(int i){ return i ^ (((i>>4) ^ (i>>8)) & 14); }
// digit-reversal: bin k -> slot after DIF passes [16(512),16(32),16(2)] (pre-r2, slot even)
__device__ __forceinline__ int drev(int k){
    return ((k & 15) << 9) | (((k >> 4) & 15) << 5) | (((k >> 8) & 15) << 1) | (k >> 12);
}

#define C1 0.923879532511286756f
#define S1 0.382683432365089772f
#define R2 0.707106781186547524f

// natural-in DFT-16; output bin m in q[rv[m]]. FULL=false: inputs 8..15 are
// pre-duplicated copies of 0..7 (zero upper half), stage-1 add/sub skipped.
template<bool FULL>
__device__ __forceinline__ void dft16(cplx q[16]) {
    if constexpr (FULL) {
#pragma unroll
        for (int j = 0; j < 8; ++j) { cplx u=q[j], v=q[j+8]; q[j]=u+v; q[j+8]=u-v; }
    }
    q[9]  = cmul(q[9],  cplx{ C1,-S1});
    q[10] = cmul(q[10], cplx{ R2,-R2});
    q[11] = cmul(q[11], cplx{ S1,-C1});
    q[12] = mni(q[12]);
    q[13] = cmul(q[13], cplx{-S1,-C1});
    q[14] = cmul(q[14], cplx{-R2,-R2});
    q[15] = cmul(q[15], cplx{-C1,-S1});
#pragma unroll
    for (int b = 0; b < 16; b += 8) {
#pragma unroll
        for (int j = 0; j < 4; ++j) { cplx u=q[b+j], v=q[b+j+4]; q[b+j]=u+v; q[b+j+4]=u-v; }
        q[b+5] = cmul(q[b+5], cplx{ R2,-R2});
        q[b+6] = mni(q[b+6]);
        q[b+7] = cmul(q[b+7], cplx{-R2,-R2});
    }
#pragma unroll
    for (int b = 0; b < 16; b += 4) {
        cplx u0=q[b], v0=q[b+2], u1=q[b+1], v1=q[b+3];
        q[b]=u0+v0; q[b+2]=u0-v0;
        q[b+1]=u1+v1; q[b+3]=mni(u1-v1);
    }
#pragma unroll
    for (int b = 0; b < 16; b += 2) { cplx u=q[b], v=q[b+1]; q[b]=u+v; q[b+1]=u-v; }
}

// Hand-folded swizzled addressing for mask &14: IDX14(base+p+r*L) == (sb ^ C_r) + (r*L).
template<int PASS>
__device__ __forceinline__ int psb(int t) {
    if constexpr (PASS == 0) {               // L=512, p=t
        return t ^ (((t>>4) ^ (t>>8)) & 14);
    } else if constexpr (PASS == 1) {        // L=32, base=(t>>5)<<9, p=t&31
        int p = t & 31, hb = t >> 5;
        return ((hb<<9) | p) ^ (((p>>4) ^ (hb<<1)) & 14);
    } else {                                 // L=2, base=(t>>1)<<5, p=t&1
        int h = t >> 1;
        return ((h<<5) | (t&1)) ^ (((h<<1) ^ (h>>3)) & 14);
    }
}
template<int PASS>
__device__ __forceinline__ int paddr(int sb, int r) {
    if constexpr (PASS == 0)      return (sb ^ (2*(r&7))) + (r<<9);
    else if constexpr (PASS == 1) return (sb ^ (2*(r&7))) + (r<<5);
    else                          return sb ^ (r<<1);
}

// One radix-16 pass (single buffer). Pass A twiddles come from registers
// (twA[15], hoisted — thread-constant); B/C from LDS table twT[m][row].
template<int PASS, bool DIT, bool PRUNED>
__device__ __forceinline__ void r16p(cplx* lds, const cplx (*twT)[68],
                                     const cplx (&twA)[15], int t) {
    static constexpr int RV[16] = {0,8,4,12,2,10,6,14,1,9,5,13,3,11,7,15};
    const int sb = psb<PASS>(t);
    int rL = 0;
    if constexpr (PASS == 1) { rL = t & 31; }
    else if constexpr (PASS == 2) { rL = 64 + (t & 1); }
    cplx q[16];
    if constexpr (PRUNED) {
#pragma unroll
        for (int r = 0; r < 8; ++r) { q[r] = lds[paddr<PASS>(sb, r)]; q[r+8] = q[r]; }
    } else {
#pragma unroll
        for (int r = 0; r < 16; ++r) q[r] = lds[paddr<PASS>(sb, r)];
    }
    if constexpr (DIT) {
#pragma unroll
        for (int m = 1; m < 16; ++m) {
            cplx w = (PASS == 0) ? twA[m-1] : twT[m][rL];
            q[m] = cmul(q[m], w);
        }
        dft16<true>(q);
    } else {
        dft16<!PRUNED>(q);
#pragma unroll
        for (int m = 1; m < 16; ++m) {
            cplx w = (PASS == 0) ? twA[m-1] : twT[m][rL];
            q[RV[m]] = cmul(q[RV[m]], w);
        }
    }
#pragma unroll
    for (int m = 0; m < 16; ++m) lds[paddr<PASS>(sb, m)] = q[RV[m]];
}

// paired pass: two sequential single-buffer passes, one barrier interval
template<int PASS, bool DIT, bool PRUNED>
__device__ __forceinline__ void r16pp(cplx* l0, cplx* l1, const cplx (*twT)[68],
                                      const cplx (&twA)[15], int t) {
    r16p<PASS, DIT, PRUNED>(l0, twT, twA, t);
    fence();
    r16p<PASS, DIT, PRUNED>(l1, twT, twA, t);
}

// copy twiddle tables global -> LDS (transposed): 66 rows x 16 elems
__device__ __forceinline__ void load_twT(cplx (*twT)[68], const float* __restrict__ ws, int tid) {
    const cplx* gTWB = (const cplx*)(ws + OFF_TWB);
    const cplx* gTL  = (const cplx*)(ws + OFF_TL);
    const cplx* gTWC = (const cplx*)(ws + OFF_TWC);
    for (int idx = tid; idx < 16*66; idx += NT) {
        int r = idx >> 4, m = idx & 15;
        cplx v;
        if (r < 32)      v = gTWB[(r << 4) + m];
        else if (r < 64) v = gTL[((r - 32) << 4) + m];
        else             v = gTWC[((r - 64) << 4) + m];
        twT[m][r] = v;
    }
}

// hoist pass-A combined twiddles into registers (thread-constant; call after
// twT is barrier-visible). W8192^{pm} = TL[t&31][m] * TWB[2*(t>>5)][m].
__device__ __forceinline__ void make_twA(cplx (&twA)[15], const cplx (*twT)[68], int t) {
    const int rL = 32 + (t & 31);
    const int rH = (t >> 5) << 1;
#pragma unroll
    for (int m = 1; m < 16; ++m) twA[m-1] = cmul(twT[m][rL], twT[m][rH]);
}

// spectral multiply for bin pair (k, 8192-k): o1/o2 are swapped v'[k], v'[8192-k]
__device__ __forceinline__ void specpair(cplx V1, cplx V2, float4 kv, cplx W,
                                         cplx& o1, cplx& o2) {
    cplx Eh = V1 + cplx{V2.x, -V2.y};
    cplx Oh = cplx{V1.y + V2.y, V2.x - V1.x};
    cplx S = cplx{kv.x, kv.y};
    float a = W.x*kv.z, b = W.y*kv.w, cc = W.x*kv.w, dd = W.y*kv.z;
    cplx T  = cplx{a - b, cc + dd};
    cplx T2 = cplx{a + b, cc - dd};
    cplx Ep = cmul(Eh, S) + cmul(Oh, T);
    cplx Op = cmul(Eh, T2) + cmul(Oh, S);
    o1 = cplx{Ep.y + Op.x, Ep.x - Op.y};
    o2 = cplx{Op.x - Ep.y, Ep.x + Op.y};
}

// fused fwd-r2 + spectral multiply + inverse-r2 for one buffer at slot pair
__device__ __forceinline__ void spec_rows(float4* l4, int sA, int sB,
                                          float4 kvk, float4 kvj, cplx W, cplx Wj) {
    float4 fA = l4[sA], fB = l4[sB];
    cplx uA = {fA.x, fA.y}, vA = {fA.z, fA.w};
    cplx uB = {fB.x, fB.y}, vB = {fB.z, fB.w};
    cplx Vk = uA + vA, Vk4 = uA - vA;   // bins k, k+4096
    cplx Vj = uB + vB, Vj4 = uB - vB;   // bins jj, 8192-k
    cplx r1, r2, r1j, r2j;
    specpair(Vk, Vj4, kvk, W,  r1,  r2);   // v'[k],  v'[8192-k]
    specpair(Vj, Vk4, kvj, Wj, r1j, r2j);  // v'[jj], v'[4096+k]
    cplx a0 = r1 + r2j, a1 = r1 - r2j;
    cplx b0 = r1j + r2, b1 = r1j - r2;
    l4[sA] = make_float4(a0.x, a0.y, a1.x, a1.y);
    l4[sB] = make_float4(b0.x, b0.y, b1.x, b1.y);
}

// bins 0 / 4096 special (tt==0); slots {0,1} = l4[0]
__device__ __forceinline__ void spec_dc(float4* l4, float4 kv) {
    float4 f = l4[0];
    cplx u = {f.x, f.y}, v = {f.z, f.w};
    cplx V0 = u + v, VN = u - v;
    float U0 = V0.x + V0.y, UL = V0.x - V0.y;
    float re = U0*kv.x + UL*kv.y;
    float im = U0*kv.x - UL*kv.y;
    cplx s0 = {im, re};
    cplx P = {VN.x*kv.z + VN.y*kv.w, VN.x*kv.w - VN.y*kv.z};
    cplx s1 = {-P.y, P.x};
    cplx a = s0 + s1, b = s0 - s1;
    l4[0] = make_float4(a.x, a.y, b.x, b.y);
}

// filter spectral store for one channel at quad (k,jj), bias folded (E += eb)
__device__ __forceinline__ void filt_store(const float4* l4, float4* kf, int k, int jj,
                                           int sA, int sB, cplx W, cplx Wj,
                                           float sc, float eb) {
    float4 fA = l4[sA], fB = l4[sB];
    cplx uA = {fA.x, fA.y}, vA = {fA.z, fA.w};
    cplx uB = {fB.x, fB.y}, vB = {fB.z, fB.w};
    cplx Vk = uA + vA, Vk4 = uA - vA;
    cplx Vj = uB + vB, Vj4 = uB - vB;
    {
        cplx E = {Vk.x + Vj4.x + eb, Vk.y - Vj4.y};
        cplx O = {Vk.y + Vj4.y, Vj4.x - Vk.x};
        cplx D = cmul(W, O);
        kf[k] = make_float4(E.x*sc, E.y*sc, D.x*sc, D.y*sc);
    }
    {
        cplx E = {Vj.x + Vk4.x + eb, Vj.y - Vk4.y};
        cplx O = {Vj.y + Vk4.y, Vk4.x - Vj.x};
        cplx D = cmul(Wj, O);
        kf[jj] = make_float4(E.x*sc, E.y*sc, D.x*sc, D.y*sc);
    }
}
// DC store with bias fold: H[0]+=bc, H[8192]+=bc, H[4096]+=bc.
__device__ __forceinline__ void filt_dc(const float4* l4, float4* kf, float bc) {
    float4 f = l4[0];
    cplx u = {f.x, f.y}, v = {f.z, f.w};
    cplx V0 = u + v, VN = u - v;
    kf[0] = make_float4((V0.x + V0.y + bc)/16384.f, (V0.x - V0.y + bc)/16384.f,
                        (VN.x + bc)/8192.f, -VN.y/8192.f);
}

// merged init (block 0: twiddle tables via double-precision factor tables) + MLP (blocks 1..16)
__global__ __launch_bounds__(512) void k_pre(const float* __restrict__ z, const float* __restrict__ freq,
        const float* __restrict__ W0, const float* __restrict__ b0,
        const float* __restrict__ W1, const float* __restrict__ b1,
        const float* __restrict__ W2, const float* __restrict__ b2,
        float* __restrict__ ws, float* __restrict__ H) {
    __shared__ double2 lA[128], lB[128];
    const int t = threadIdx.x;
    if (blockIdx.x == 0) {
        const double K = -2.0 * 3.14159265358979323846 / 16384.0;
        if (t < 128)      { double a = K * (double)(t << 7); lA[t] = make_double2(cos(a), sin(a)); }
        else if (t < 256) { int b = t - 128; double a = K * (double)b; lB[b] = make_double2(cos(a), sin(a)); }
        __syncthreads();
        auto wf = [&](int e) -> float2 {
            e &= 16383;
            double2 A = lA[e >> 7], B = lB[e & 127];
            return make_float2((float)(A.x*B.x - A.y*B.y), (float)(A.x*B.y + A.y*B.x));
        };
        float2* tw16 = (float2*)(ws + OFF_TW16);
        for (int k = t; k <= 2048; k += 512) tw16[k] = wf(k);
        if (t < 32) {
            float2* rowL = (float2*)(ws + OFF_TL)  + (t << 4);
            float2* rowB = (float2*)(ws + OFF_TWB) + (t << 4);
#pragma unroll
            for (int m = 0; m < 16; ++m) { rowL[m] = wf(2*t*m); rowB[m] = wf(32*t*m); }
        } else if (t < 34) {
            int c2 = t - 32;
            float2* rowC = (float2*)(ws + OFF_TWC) + (c2 << 4);
#pragma unroll
            for (int m = 0; m < 16; ++m) rowC[m] = wf(512*c2*m);
        }
    } else {
        const int j = ((blockIdx.x - 1) << 9) + t;
        const float z0 = z[j*3+0], z1 = z[j*3+1], z2 = z[j*3+2];
        float h[16], g[16];
#pragma unroll
        for (int m = 0; m < 16; ++m)
            h[m] = sinf(freq[m] * (z0*W0[m] + z1*W0[16+m] + z2*W0[32+m] + b0[m]));
#pragma unroll
        for (int m = 0; m < 16; ++m) {
            float a = b1[m];
#pragma unroll
            for (int p = 0; p < 16; ++p) a += h[p] * W1[p*16+m];
            g[m] = sinf(freq[m] * a);
        }
#pragma unroll
        for (int m = 0; m < 16; ++m) {
            float a = b2[m];
#pragma unroll
            for (int p = 0; p < 16; ++p) a += g[p] * W2[p*16+m];
            h[m] = sinf(freq[m] * a);
        }
        float4* hp = (float4*)(H + (j << 4));   // row-major [8192][16]
        hp[0] = make_float4(h[0],  h[1],  h[2],  h[3]);
        hp[1] = make_float4(h[4],  h[5],  h[6],  h[7]);
        hp[2] = make_float4(h[8],  h[9],  h[10], h[11]);
        hp[3] = make_float4(h[12], h[13], h[14], h[15]);
    }
}

// Block = channel c (768 blocks = 3 exact rounds). Phase 1: compute filter
// spectrum Kf[c] (MLP staging -> pruned fwd FFT in l0 -> filt_store to global;
// single writer). Phase 2: 8 batches as 4 ping-pong row-pairs reading kf4
// (L2-hot from own writes). Bias folded into Kf.
__global__ __launch_bounds__(NT) void k_main(const float* __restrict__ x, const float* __restrict__ H,
        const float* __restrict__ t, const float* __restrict__ deltas,
        const float* __restrict__ W3, const float* __restrict__ b3,
        const float* __restrict__ bias, const float* __restrict__ ws,
        float* __restrict__ KfF, float* __restrict__ out) {
    __shared__ alignas(16) cplx lds2[2][LSEQ];
    __shared__ cplx twT[16][68];
    const int c = blockIdx.x;                   // 0..767
    const int tt = threadIdx.x;
    cplx* l0 = lds2[0];
    cplx* l1 = lds2[1];
    float4* l04 = (float4*)l0;
    float4* l14 = (float4*)l1;
    float4* kf4 = (float4*)KfF + (size_t)c * 4096;
    const cplx* tw16 = (const cplx*)(ws + OFF_TW16);
    const size_t rowstride = (size_t)NCH * LSEQ;
    const float* xcol = x + (size_t)c * LSEQ;
    float* ocol = out + (size_t)c * LSEQ;
    const float sc = 1.0f / 32768.0f;

    // staging slot: IDX14(2i),IDX14(2i+1) = one float4 at ((EB^(j<<2))+(j<<10))>>1
    const int EB = (tt << 1) ^ (((tt>>3) ^ (tt>>7)) & 14);
    const int sbA = psb<0>(tt);

    load_twT(twT, ws, tt);

    // ---- Phase 1: filter for channel c -> l0 -> fwd FFT -> Kf[c] ----
    {
        float4 w3a = make_float4(W3[0*NCH+c],  W3[1*NCH+c],  W3[2*NCH+c],  W3[3*NCH+c]);
        float4 w3b = make_float4(W3[4*NCH+c],  W3[5*NCH+c],  W3[6*NCH+c],  W3[7*NCH+c]);
        float4 w3c = make_float4(W3[8*NCH+c],  W3[9*NCH+c],  W3[10*NCH+c], W3[11*NCH+c]);
        float4 w3d = make_float4(W3[12*NCH+c], W3[13*NCH+c], W3[14*NCH+c], W3[15*NCH+c]);
        const float b3c = b3[c];
        const float ad = fabsf(deltas[c]);
#pragma unroll 1
        for (int j = 0; j < 8; ++j) {
            int n = tt + (j << 9);
            const float4* hp = (const float4*)(H + (n << 5));
            float4 p0 = hp[0], p1 = hp[1], p2 = hp[2], p3 = hp[3];
            float4 q0 = hp[4], q1 = hp[5], q2 = hp[6], q3 = hp[7];
            float s0 = b3c + p0.x*w3a.x + p0.y*w3a.y + p0.z*w3a.z + p0.w*w3a.w
                           + p1.x*w3b.x + p1.y*w3b.y + p1.z*w3b.z + p1.w*w3b.w
                           + p2.x*w3c.x + p2.y*w3c.y + p2.z*w3c.z + p2.w*w3c.w
                           + p3.x*w3d.x + p3.y*w3d.y + p3.z*w3d.z + p3.w*w3d.w;
            float s1 = b3c + q0.x*w3a.x + q0.y*w3a.y + q0.z*w3a.z + q0.w*w3a.w
                           + q1.x*w3b.x + q1.y*w3b.y + q1.z*w3b.z + q1.w*w3b.w
                           + q2.x*w3c.x + q2.y*w3c.y + q2.z*w3c.z + q2.w*w3c.w
                           + q3.x*w3d.x + q3.y*w3d.y + q3.z*w3d.z + q3.w*w3d.w;
            float2 tv = ((const float2*)t)[n];
            l0[paddr<0>(sbA, j)] = cplx{s0 * expf(-tv.x*ad), s1 * expf(-tv.y*ad)};
        }
    }
    __syncthreads();                            // covers twT copy + filter staging
    cplx twA[15];
    make_twA(twA, twT, tt);

    r16p<0,false,true >(l0, twT, twA, tt); __syncthreads();
    r16p<1,false,false>(l0, twT, twA, tt); wave_sync();
    r16p<2,false,false>(l0, twT, twA, tt); __syncthreads();

    {
        const float bc = bias[c];
        const float eb = 2.0f * bc;
#pragma unroll 1
        for (int it = 0; it < 4; ++it) {
            int k  = tt + 1 + (it << 9);   // 1..2048
            int jj = 4096 - k;             // (k=2048: idempotent dup)
            int sA = IDX14(drev(k)) >> 1, sB = IDX14(drev(jj)) >> 1;
            cplx W  = tw16[k];
            cplx Wj = cplx{-W.y, -W.x};
            filt_store(l04, kf4, k, jj, sA, sB, W, Wj, sc, eb);
        }
        if (tt == 0) filt_dc(l04, kf4, bc);
    }
    __syncthreads();   // drains kf writes (vmcnt0 before barrier) -> L2-visible

    // ---- Phase 2: 8 batches as 4 ping-pong pairs ----
#pragma unroll 1
    for (int pp = 0; pp < 4; ++pp) {            // pair = batches (2pp, 2pp+1)
        const float4* xr0 = (const float4*)(xcol + (size_t)(2*pp)     * rowstride);
        const float4* xr1 = (const float4*)(xcol + (size_t)(2*pp + 1) * rowstride);
#pragma unroll
        for (int j = 0; j < 4; ++j) {
            int si = ((EB ^ (j<<2)) + (j<<10)) >> 1;
            l04[si] = xr0[tt + (j<<9)];
            l14[si] = xr1[tt + (j<<9)];
        }
        __syncthreads();
        r16pp<0,false,true >(l0, l1, twT, twA, tt); __syncthreads();
        r16pp<1,false,false>(l0, l1, twT, twA, tt); wave_sync();
        r16pp<2,false,false>(l0, l1, twT, twA, tt); __syncthreads();

        // fused fwd-r2 + spectral + inverse-r2 on both buffers; kf/tw shared
#pragma unroll 1
        for (int it = 0; it < 4; ++it) {
            int k  = tt + 1 + (it << 9);   // 1..2048
            int jj = 4096 - k;
            int sA = IDX14(drev(k)) >> 1, sB = IDX14(drev(jj)) >> 1;
            float4 kvk = kf4[k], kvj = kf4[jj];
            cplx W  = tw16[k];
            cplx Wj = cplx{-W.y, -W.x};
            spec_rows(l04, sA, sB, kvk, kvj, W, Wj);
            spec_rows(l14, sA, sB, kvk, kvj, W, Wj);
        }
        if (tt == 0) {
            float4 kv = kf4[0];
            spec_dc(l04, kv);
            spec_dc(l14, kv);
        }
        __syncthreads();

        r16pp<2,true,false>(l0, l1, twT, twA, tt); wave_sync();
        r16pp<1,true,false>(l0, l1, twT, twA, tt); __syncthreads();
        r16pp<0,true,false>(l0, l1, twT, twA, tt); __syncthreads();

        float4* o0 = (float4*)(ocol + (size_t)(2*pp)     * rowstride);
        float4* o1 = (float4*)(ocol + (size_t)(2*pp + 1) * rowstride);
#pragma unroll
        for (int j = 0; j < 4; ++j) {
            int si = ((EB ^ (j<<2)) + (j<<10)) >> 1;
            float4 f0 = l04[si], f1 = l14[si];
            o0[tt + (j<<9)] = make_float4(f0.y, f0.x, f0.w, f0.z);
            o1[tt + (j<<9)] = make_float4(f1.y, f1.x, f1.w, f1.z);
        }
        if (pp < 3) __syncthreads();   // protect lds before next pair's staging
    }
}

extern "C" void kernel_launch(void* const* d_in, const int* in_sizes, int n_in,
                              void* d_out, int out_size, void* d_ws, size_t ws_size,
                              hipStream_t stream) {
    const float* x      = (const float*)d_in[0];
    const float* z      = (const float*)d_in[2];
    const float* t      = (const float*)d_in[3];
    const float* deltas = (const float*)d_in[4];
    const float* freq   = (const float*)d_in[5];
    const float* W0     = (const float*)d_in[6];
    const float* b0     = (const float*)d_in[7];
    const float* W1     = (const float*)d_in[8];
    const float* b1     = (const float*)d_in[9];
    const float* W2     = (const float*)d_in[10];
    const float* b2     = (const float*)d_in[11];
    const float* W3     = (const float*)d_in[12];
    const float* b3     = (const float*)d_in[13];
    const float* bias   = (const float*)d_in[14];
    float* out = (float*)d_out;
    float* ws  = (float*)d_ws;
    float* H   = ws + OFF_H;
    float* Kf  = ws + OFF_KF;

    hipLaunchKernelGGL(k_pre, dim3(17), dim3(512), 0, stream, z, freq, W0, b0, W1, b1, W2, b2, ws, H);
    hipLaunchKernelGGL(k_main, dim3(NCH), dim3(NT), 0, stream, x, H, t, deltas, W3, b3, bias, ws, Kf, out);
}